// Round 1
// baseline (434.053 us; speedup 1.0000x reference)
//
#include <hip/hip_runtime.h>
#include <math.h>

// ---------------- problem constants (fixed by setup_inputs) ----------------
#define B_    4
#define QN    32
#define KN    8192
#define HDIM  1024
#define NHD   16
#define DH    64
#define LCH   128
#define JCH   64

typedef float f32x4 __attribute__((ext_vector_type(4)));
typedef short s16x8 __attribute__((ext_vector_type(8)));
typedef unsigned short u16;

__device__ __forceinline__ u16 f2bf(float f) {          // round-to-nearest-even f32->bf16
  unsigned u = __float_as_uint(f);
  u += 0x7fffu + ((u >> 16) & 1u);
  return (u16)(u >> 16);
}

__device__ __forceinline__ void llds16(const void* g, void* l) {   // 16B global->LDS DMA
  __builtin_amdgcn_global_load_lds((const __attribute__((address_space(1))) unsigned int*)g,
                                   (__attribute__((address_space(3))) unsigned int*)l,
                                   16, 0, 0);
}

// ---------------- context fp32 -> bf16 ----------------
__global__ __launch_bounds__(256) void k_ctx2bf16(const float* __restrict__ ctx, u16* __restrict__ out) {
  const int total4 = B_ * KN * HDIM / 4;
  int idx = blockIdx.x * 256 + threadIdx.x;
  for (int i = idx; i < total4; i += gridDim.x * 256) {
    float4 v = ((const float4*)ctx)[i];
    ushort4 o;
    o.x = f2bf(v.x); o.y = f2bf(v.y); o.z = f2bf(v.z); o.w = f2bf(v.w);
    ((ushort4*)out)[i] = o;
  }
}

// ---------------- generic fp32 tiled GEMM, C += A*B over one K-slice (atomic) ----------------
// grid: (M/64, N/64, K/kchunk), block 256. M,N mult of 64; kchunk mult of 16.
__global__ __launch_bounds__(256) void k_gemm_f32(const float* __restrict__ A, int lda,
                                                  const float* __restrict__ Bm, int ldb,
                                                  float* __restrict__ C, int ldc, int kchunk) {
  __shared__ float As[64][17];
  __shared__ float Bs[16][64];
  int t = threadIdx.x;
  int m0 = blockIdx.x * 64, n0 = blockIdx.y * 64, k0 = blockIdx.z * kchunk;
  int tm = t >> 4, tn = t & 15;
  float c[4][4];
#pragma unroll
  for (int i = 0; i < 4; ++i)
#pragma unroll
    for (int j = 0; j < 4; ++j) c[i][j] = 0.f;
  int ra = t >> 2, ka = (t & 3) * 4;
  int kb = t >> 4, nb = (t & 15) * 4;
  for (int kk = 0; kk < kchunk; kk += 16) {
    float4 va = *(const float4*)(A + (size_t)(m0 + ra) * lda + k0 + kk + ka);
    float4 vb = *(const float4*)(Bm + (size_t)(k0 + kk + kb) * ldb + n0 + nb);
    As[ra][ka] = va.x; As[ra][ka + 1] = va.y; As[ra][ka + 2] = va.z; As[ra][ka + 3] = va.w;
    *(float4*)&Bs[kb][nb] = vb;
    __syncthreads();
#pragma unroll
    for (int kq = 0; kq < 16; ++kq) {
      float a0 = As[tm * 4 + 0][kq], a1 = As[tm * 4 + 1][kq];
      float a2 = As[tm * 4 + 2][kq], a3 = As[tm * 4 + 3][kq];
      float b0 = Bs[kq][tn * 4 + 0], b1 = Bs[kq][tn * 4 + 1];
      float b2 = Bs[kq][tn * 4 + 2], b3 = Bs[kq][tn * 4 + 3];
      c[0][0] += a0 * b0; c[0][1] += a0 * b1; c[0][2] += a0 * b2; c[0][3] += a0 * b3;
      c[1][0] += a1 * b0; c[1][1] += a1 * b1; c[1][2] += a1 * b2; c[1][3] += a1 * b3;
      c[2][0] += a2 * b0; c[2][1] += a2 * b1; c[2][2] += a2 * b2; c[2][3] += a2 * b3;
      c[3][0] += a3 * b0; c[3][1] += a3 * b1; c[3][2] += a3 * b2; c[3][3] += a3 * b3;
    }
    __syncthreads();
  }
#pragma unroll
  for (int i = 0; i < 4; ++i)
#pragma unroll
    for (int j = 0; j < 4; ++j)
      atomicAdd(&C[(size_t)(m0 + tm * 4 + i) * ldc + n0 + tn * 4 + j], c[i][j]);
}

// ---------------- add bq to qh (both scorers) ----------------
__global__ __launch_bounds__(256) void k_qh_bias(float* __restrict__ qh, const float* __restrict__ bq_g,
                                                 const float* __restrict__ bq_l) {
  int i = blockIdx.x * 256 + threadIdx.x;   // 0..262143
  int s2 = i >> 17, n = i & (HDIM - 1);
  qh[i] += (s2 ? bq_l : bq_g)[n];
}

// ---------------- folded score matrix A[b][n][c] (bf16, scale 1/8 folded) ----------------
// n = s2*512 + h*32 + q ; A[b,n,c] = (1/8) sum_d qh[s2][b,q,h*64+d] * Wk_s2[c, h*64+d]
__global__ __launch_bounds__(256) void k_afold(const float* __restrict__ qh, const float* __restrict__ Wk_g,
                                               const float* __restrict__ Wk_l, u16* __restrict__ Ab) {
  int ct = blockIdx.x;          // 0..3  (c tile of 256)
  int slot = blockIdx.y;        // 0..31 (s2*16 + h)
  int b = blockIdx.z;
  int s2 = slot >> 4, h = slot & 15;
  const float* qhp = qh + (size_t)(s2 * 4 + b) * QN * HDIM;
  const float* Wk = s2 ? Wk_l : Wk_g;
  __shared__ float qs[QN][DH];
  int t = threadIdx.x;
  {
    int q = t >> 3, doff = (t & 7) * 8;
    const float4* src = (const float4*)(qhp + (size_t)q * HDIM + h * DH + doff);
    *(float4*)&qs[q][doff] = src[0];
    *(float4*)&qs[q][doff + 4] = src[1];
  }
  __syncthreads();
  int c = ct * 256 + t;
  float w[DH];
  const float* wr = Wk + (size_t)c * HDIM + h * DH;
#pragma unroll
  for (int d = 0; d < DH; d += 4) {
    float4 v = *(const float4*)(wr + d);
    w[d] = v.x; w[d + 1] = v.y; w[d + 2] = v.z; w[d + 3] = v.w;
  }
  u16* outp = Ab + ((size_t)b * HDIM + s2 * 512 + h * QN) * HDIM + c;
  for (int q = 0; q < QN; ++q) {
    float acc = 0.f;
#pragma unroll
    for (int d = 0; d < DH; ++d) acc += qs[q][d] * w[d];
    outp[(size_t)q * HDIM] = f2bf(acc * 0.125f);
  }
}

// ---------------- score bias sbias[b][n] = (1/8) qh . bk ----------------
__global__ __launch_bounds__(256) void k_sbias(const float* __restrict__ qh, const float* __restrict__ bk_g,
                                               const float* __restrict__ bk_l, float* __restrict__ sbias) {
  int i = blockIdx.x * 256 + threadIdx.x;   // 0..4095
  int b = i >> 10, n = i & (HDIM - 1);
  int s2 = n >> 9, hq = n & 511, h = hq >> 5, q = hq & 31;
  const float* qr = qh + ((size_t)(s2 * 4 + b) * QN + q) * HDIM + h * DH;
  const float* bk = (s2 ? bk_l : bk_g) + h * DH;
  float acc = 0.f;
#pragma unroll
  for (int d = 0; d < DH; ++d) acc += qr[d] * bk[d];
  sbias[i] = acc * 0.125f;
}

// ---------------- THE big fused kernel: S = ctx_bf16 @ A^T, column-wise (max,sumexp) per chunk ----
// grid (nt=8, jc=64, b=4), 256 thr (4 waves 2x2), 128x128 tile, K=1024 in 32-steps of 16x16x32 MFMA.
__global__ __launch_bounds__(256) void k_scores(const u16* __restrict__ ctxb, const u16* __restrict__ Ab,
                                                const float* __restrict__ sbias,
                                                float* __restrict__ mglob, float* __restrict__ zglob,
                                                float* __restrict__ locinv) {
  __shared__ u16 At[128 * 32];     // ctx tile  [row(l) 128][k 32]
  __shared__ u16 Bt[128 * 32];     // A-fold tile [n 128][k 32]
  __shared__ float red[2][128];
  int nt = blockIdx.x, jc = blockIdx.y, b = blockIdx.z;
  int t = threadIdx.x;
  int wid = t >> 6, lane = t & 63;
  int wr = wid >> 1, wc = wid & 1;
  int lrow = lane & 15, lkg = lane >> 4;

  const u16* ctx0 = ctxb + (size_t)(b * KN + jc * LCH) * HDIM;
  const u16* A0 = Ab + ((size_t)b * HDIM + nt * 128) * HDIM;

  f32x4 acc[4][4];
#pragma unroll
  for (int i = 0; i < 4; ++i)
#pragma unroll
    for (int j = 0; j < 4; ++j) acc[i][j] = 0.f;

  for (int kt = 0; kt < HDIM / 32; ++kt) {
    __syncthreads();
#pragma unroll
    for (int issue = 0; issue < 2; ++issue) {
      int seg = issue * 4 + wid;
      int chunk = seg * 64 + lane;
      int row = chunk >> 2;
      int ko = (chunk & 3) * 8;
      llds16(ctx0 + (size_t)row * HDIM + kt * 32 + ko, At + seg * 512);
      llds16(A0 + (size_t)row * HDIM + kt * 32 + ko, Bt + seg * 512);
    }
    __syncthreads();
    s16x8 af[4], bf[4];
#pragma unroll
    for (int i = 0; i < 4; ++i) af[i] = *(const s16x8*)(At + (wr * 64 + i * 16 + lrow) * 32 + lkg * 8);
#pragma unroll
    for (int j = 0; j < 4; ++j) bf[j] = *(const s16x8*)(Bt + (wc * 64 + j * 16 + lrow) * 32 + lkg * 8);
#pragma unroll
    for (int i = 0; i < 4; ++i)
#pragma unroll
      for (int j = 0; j < 4; ++j)
        acc[i][j] = __builtin_amdgcn_mfma_f32_16x16x32_bf16(af[i], bf[j], acc[i][j], 0, 0, 0);
  }

  // ---- epilogue: per output column (over 128 chunk rows): max, sumexp ----
  // D mapping (m89-verified): col = lane&15, row = (lane>>4)*4 + reg
  float sb[4], mv[4], Mc[4], zv[4];
#pragma unroll
  for (int fj = 0; fj < 4; ++fj)
    sb[fj] = sbias[b * HDIM + nt * 128 + wc * 64 + fj * 16 + lrow];
#pragma unroll
  for (int fj = 0; fj < 4; ++fj) {
    float m = -1e30f;
#pragma unroll
    for (int fi = 0; fi < 4; ++fi)
#pragma unroll
      for (int r = 0; r < 4; ++r) m = fmaxf(m, acc[fi][fj][r]);
    m += sb[fj];
    m = fmaxf(m, __shfl_xor(m, 16, 64));
    m = fmaxf(m, __shfl_xor(m, 32, 64));
    mv[fj] = m;
  }
  if (lane < 16) {
#pragma unroll
    for (int fj = 0; fj < 4; ++fj) red[wr][wc * 64 + fj * 16 + lane] = mv[fj];
  }
  __syncthreads();
#pragma unroll
  for (int fj = 0; fj < 4; ++fj) {
    int col = wc * 64 + fj * 16 + lrow;
    Mc[fj] = fmaxf(red[0][col], red[1][col]);
  }
  __syncthreads();
#pragma unroll
  for (int fj = 0; fj < 4; ++fj) {
    float s = 0.f;
#pragma unroll
    for (int fi = 0; fi < 4; ++fi)
#pragma unroll
      for (int r = 0; r < 4; ++r) s += __expf(acc[fi][fj][r] + sb[fj] - Mc[fj]);
    s += __shfl_xor(s, 16, 64);
    s += __shfl_xor(s, 32, 64);
    zv[fj] = s;
  }
  if (lane < 16) {
#pragma unroll
    for (int fj = 0; fj < 4; ++fj) red[wr][wc * 64 + fj * 16 + lane] = zv[fj];
  }
  __syncthreads();
  if (wr == 0 && lane < 16) {
    size_t base = (size_t)(b * JCH + jc) * 512;
#pragma unroll
    for (int fj = 0; fj < 4; ++fj) {
      int col = wc * 64 + fj * 16 + lane;
      float Z = red[0][col] + red[1][col];
      int n = nt * 128 + col;
      if (n < 512) { mglob[base + n] = Mc[fj]; zglob[base + n] = Z; }
      else         { locinv[base + n - 512] = 1.0f / Z; }
    }
  }
}

// ---------------- LN(mean over Q) of question -> qvec[b][1024] ----------------
__global__ __launch_bounds__(256) void k_qvec(const float* __restrict__ q, const float* __restrict__ g,
                                              const float* __restrict__ lb, float* __restrict__ qvec) {
  int b = blockIdx.x, t = threadIdx.x;
  const float* p = q + (size_t)b * QN * HDIM + t * 4;
  float a0 = 0, a1 = 0, a2 = 0, a3 = 0;
  for (int r = 0; r < QN; ++r) {
    float4 v = *(const float4*)(p + (size_t)r * HDIM);
    a0 += v.x; a1 += v.y; a2 += v.z; a3 += v.w;
  }
  const float sc = 1.0f / QN;
  a0 *= sc; a1 *= sc; a2 *= sc; a3 *= sc;
  float s = a0 + a1 + a2 + a3;
  float ss = a0 * a0 + a1 * a1 + a2 * a2 + a3 * a3;
#pragma unroll
  for (int o = 1; o < 64; o <<= 1) { s += __shfl_xor(s, o, 64); ss += __shfl_xor(ss, o, 64); }
  __shared__ float sm[4], sq[4];
  int wid = t >> 6, lane = t & 63;
  if (lane == 0) { sm[wid] = s; sq[wid] = ss; }
  __syncthreads();
  float S = sm[0] + sm[1] + sm[2] + sm[3], SS = sq[0] + sq[1] + sq[2] + sq[3];
  float mu = S / HDIM;
  float inv = rsqrtf(SS / HDIM - mu * mu + 1e-5f);
  int c = t * 4;
  float4 o;
  o.x = (a0 - mu) * inv * g[c + 0] + lb[c + 0];
  o.y = (a1 - mu) * inv * g[c + 1] + lb[c + 1];
  o.z = (a2 - mu) * inv * g[c + 2] + lb[c + 2];
  o.w = (a3 - mu) * inv * g[c + 3] + lb[c + 3];
  *(float4*)&qvec[(size_t)b * HDIM + c] = o;
}

// ---------------- LN(mean over L) of context chunks -> cvec[b*64+j][1024] ----------------
__global__ __launch_bounds__(256) void k_cvec(const float* __restrict__ ctx, const float* __restrict__ g,
                                              const float* __restrict__ lb, float* __restrict__ cvec) {
  int bj = blockIdx.x, t = threadIdx.x;
  int b = bj >> 6, jc = bj & 63;
  const float* p = ctx + ((size_t)b * KN + jc * LCH) * HDIM + t * 4;
  float a0 = 0, a1 = 0, a2 = 0, a3 = 0;
  for (int r = 0; r < LCH; ++r) {
    float4 v = *(const float4*)(p + (size_t)r * HDIM);
    a0 += v.x; a1 += v.y; a2 += v.z; a3 += v.w;
  }
  const float sc = 1.0f / LCH;
  a0 *= sc; a1 *= sc; a2 *= sc; a3 *= sc;
  float s = a0 + a1 + a2 + a3;
  float ss = a0 * a0 + a1 * a1 + a2 * a2 + a3 * a3;
#pragma unroll
  for (int o = 1; o < 64; o <<= 1) { s += __shfl_xor(s, o, 64); ss += __shfl_xor(ss, o, 64); }
  __shared__ float sm[4], sq[4];
  int wid = t >> 6, lane = t & 63;
  if (lane == 0) { sm[wid] = s; sq[wid] = ss; }
  __syncthreads();
  float S = sm[0] + sm[1] + sm[2] + sm[3], SS = sq[0] + sq[1] + sq[2] + sq[3];
  float mu = S / HDIM;
  float inv = rsqrtf(SS / HDIM - mu * mu + 1e-5f);
  int c = t * 4;
  float4 o;
  o.x = (a0 - mu) * inv * g[c + 0] + lb[c + 0];
  o.y = (a1 - mu) * inv * g[c + 1] + lb[c + 1];
  o.z = (a2 - mu) * inv * g[c + 2] + lb[c + 2];
  o.w = (a3 - mu) * inv * g[c + 3] + lb[c + 3];
  *(float4*)&cvec[(size_t)bj * HDIM + c] = o;
}

// ---------------- qpart[b][n] = qvec[b] . W1[0:1024, n] ----------------
__global__ __launch_bounds__(256) void k_qpart(const float* __restrict__ qvec, const float* __restrict__ W1,
                                               float* __restrict__ qpart) {
  int b = blockIdx.y;
  int n = blockIdx.x * 256 + threadIdx.x;
  __shared__ float qs[HDIM];
  for (int i = threadIdx.x; i < HDIM; i += 256) qs[i] = qvec[(size_t)b * HDIM + i];
  __syncthreads();
  float acc = 0.f;
  const float* wp = W1 + n;
#pragma unroll 4
  for (int c = 0; c < HDIM; ++c) acc += qs[c] * wp[(size_t)c * HDIM];
  qpart[(size_t)b * HDIM + n] = acc;
}

// ---------------- h1 = gelu(h1pre + qpart + b1), exact erf gelu, in-place ----------------
__global__ __launch_bounds__(256) void k_gelu(const float* __restrict__ h1in, const float* __restrict__ qpart,
                                              const float* __restrict__ b1, float* __restrict__ h1out) {
  int i = blockIdx.x * 256 + threadIdx.x;   // 0..262143
  int bj = i >> 10, n = i & (HDIM - 1);
  int b = bj >> 6;
  float x = h1in[i] + qpart[(size_t)b * HDIM + n] + b1[n];
  h1out[i] = x * 0.5f * (1.0f + erff(x * 0.70710678118654752f));
}

// ---------------- finalize: global/local pooling, gate, softmaxes, outputs ----------------
__global__ __launch_bounds__(256) void k_final(const float* __restrict__ mglob, const float* __restrict__ zglob,
                                               const float* __restrict__ locinv, const float* __restrict__ h1,
                                               const float* __restrict__ W2, const float* __restrict__ b2,
                                               float* __restrict__ out) {
  __shared__ float Mh[512], Zt[512];
  __shared__ float att4[64][4], loc4[64][4], gat4[64][4];
  int b = blockIdx.x, t = threadIdx.x;
  const float* mg = mglob + (size_t)b * JCH * 512;
  const float* zg = zglob + (size_t)b * JCH * 512;
  for (int hq = t; hq < 512; hq += 256) {
    float m = -1e30f;
    for (int j = 0; j < JCH; ++j) m = fmaxf(m, mg[j * 512 + hq]);
    float z = 0.f;
    for (int j = 0; j < JCH; ++j) z += zg[j * 512 + hq] * __expf(mg[j * 512 + hq] - m);
    Mh[hq] = m; Zt[hq] = z;
  }
  __syncthreads();
  {
    int j = t >> 2, p = t & 3;
    float s = 0.f;
    for (int hq = p * 128; hq < p * 128 + 128; ++hq)
      s += zg[j * 512 + hq] * __expf(mg[j * 512 + hq] - Mh[hq]) / Zt[hq];
    att4[j][p] = s;
    float sl = 0.f;
    const float* lp = locinv + (size_t)(b * JCH + j) * 512;
    for (int hq = p * 128; hq < p * 128 + 128; ++hq) sl += lp[hq];
    loc4[j][p] = sl;
    float sg = 0.f;
    const float* hp = h1 + (size_t)(b * JCH + j) * HDIM;
    for (int n = p * 256; n < p * 256 + 256; ++n) sg += hp[n] * W2[n];
    gat4[j][p] = sg;
  }
  __syncthreads();
  if (t < 64) {
    float a = (att4[t][0] + att4[t][1] + att4[t][2] + att4[t][3]) * (1.0f / 65536.0f);
    float l = (loc4[t][0] + loc4[t][1] + loc4[t][2] + loc4[t][3]) * (1.0f / 512.0f);
    float gt = gat4[t][0] + gat4[t][1] + gat4[t][2] + gat4[t][3] + b2[0];
    gt = 1.0f / (1.0f + __expf(-gt));
    float am = a, lm = l;
#pragma unroll
    for (int o = 1; o < 64; o <<= 1) { am = fmaxf(am, __shfl_xor(am, o, 64)); lm = fmaxf(lm, __shfl_xor(lm, o, 64)); }
    float ae = __expf(a - am), le = __expf(l - lm);
    float as_ = ae, ls_ = le;
#pragma unroll
    for (int o = 1; o < 64; o <<= 1) { as_ += __shfl_xor(as_, o, 64); ls_ += __shfl_xor(ls_, o, 64); }
    float gs = ae / as_, ls = le / ls_;
    float fu = gt * ls + (1.0f - gt) * gs;
    float fm = fu;
#pragma unroll
    for (int o = 1; o < 64; o <<= 1) fm = fmaxf(fm, __shfl_xor(fm, o, 64));
    float fe = __expf(fu - fm);
    float fs_ = fe;
#pragma unroll
    for (int o = 1; o < 64; o <<= 1) fs_ += __shfl_xor(fs_, o, 64);
    float fv = fe / fs_;
    out[b * 64 + t] = fv;
    out[256 + b * 64 + t] = ls;
    out[512 + b * 64 + t] = gs;
    float tot = fv;
#pragma unroll
    for (int o = 1; o < 64; o <<= 1) tot += __shfl_xor(tot, o, 64);
    if (t == 0) out[768 + b] = tot * (1.0f / 64.0f);
  }
}

// ---------------- launcher ----------------
extern "C" void kernel_launch(void* const* d_in, const int* in_sizes, int n_in,
                              void* d_out, int out_size, void* d_ws, size_t ws_size,
                              hipStream_t stream) {
  const float* question = (const float*)d_in[0];
  const float* context  = (const float*)d_in[1];
  const float* Wq_l = (const float*)d_in[2];
  const float* bq_l = (const float*)d_in[3];
  const float* Wk_l = (const float*)d_in[4];
  const float* bk_l = (const float*)d_in[5];
  const float* Wq_g = (const float*)d_in[6];
  const float* bq_g = (const float*)d_in[7];
  const float* Wk_g = (const float*)d_in[8];
  const float* bk_g = (const float*)d_in[9];
  const float* ln_g = (const float*)d_in[10];
  const float* ln_b = (const float*)d_in[11];
  const float* W1   = (const float*)d_in[12];
  const float* b1   = (const float*)d_in[13];
  const float* W2   = (const float*)d_in[14];
  const float* b2   = (const float*)d_in[15];

  char* ws = (char*)d_ws;
  u16*   ctxb   = (u16*)(ws + 0);            // 67108864 B
  u16*   Ab     = (u16*)(ws + 67108864);     //  8388608 B
  float* qh     = (float*)(ws + 75497472);   //  1048576 B  [2][4][32][1024]
  float* sbias  = (float*)(ws + 76546048);   //    16384 B
  float* mglob  = (float*)(ws + 76562432);   //   524288 B  [4][64][512]
  float* zglob  = (float*)(ws + 77086720);   //   524288 B
  float* locinv = (float*)(ws + 77611008);   //   524288 B
  float* qvec   = (float*)(ws + 78135296);   //    16384 B
  float* cvec   = (float*)(ws + 78151680);   //  1048576 B  [256][1024]
  float* qpart  = (float*)(ws + 79200256);   //    16384 B
  float* h1     = (float*)(ws + 79216640);   //  1048576 B  [256][1024]

  hipMemsetAsync(qh, 0, 1048576, stream);
  hipMemsetAsync(h1, 0, 1048576, stream);

  hipLaunchKernelGGL(k_ctx2bf16, dim3(2048), dim3(256), 0, stream, context, ctxb);
  // qh_g / qh_l : question[128x1024] @ Wq[1024x1024]
  hipLaunchKernelGGL(k_gemm_f32, dim3(2, 16, 8), dim3(256), 0, stream, question, HDIM, Wq_g, HDIM, qh, HDIM, 128);
  hipLaunchKernelGGL(k_gemm_f32, dim3(2, 16, 8), dim3(256), 0, stream, question, HDIM, Wq_l, HDIM, qh + 131072, HDIM, 128);
  hipLaunchKernelGGL(k_qh_bias, dim3(1024), dim3(256), 0, stream, qh, bq_g, bq_l);
  hipLaunchKernelGGL(k_afold, dim3(4, 32, 4), dim3(256), 0, stream, qh, Wk_g, Wk_l, Ab);
  hipLaunchKernelGGL(k_sbias, dim3(16), dim3(256), 0, stream, qh, bk_g, bk_l, sbias);
  hipLaunchKernelGGL(k_scores, dim3(8, 64, 4), dim3(256), 0, stream, ctxb, Ab, sbias, mglob, zglob, locinv);
  hipLaunchKernelGGL(k_qvec, dim3(4), dim3(256), 0, stream, question, ln_g, ln_b, qvec);
  hipLaunchKernelGGL(k_cvec, dim3(256), dim3(256), 0, stream, context, ln_g, ln_b, cvec);
  hipLaunchKernelGGL(k_qpart, dim3(4, 4), dim3(256), 0, stream, qvec, W1, qpart);
  // h1pre += cvec[256x1024] @ W1[1024:2048, :]
  hipLaunchKernelGGL(k_gemm_f32, dim3(4, 16, 8), dim3(256), 0, stream, cvec, HDIM, W1 + 1048576, HDIM, h1, HDIM, 128);
  hipLaunchKernelGGL(k_gelu, dim3(1024), dim3(256), 0, stream, h1, qpart, b1, h1);
  hipLaunchKernelGGL(k_final, dim3(4), dim3(256), 0, stream, mglob, zglob, locinv, h1, W2, b2, (float*)d_out);
}

// Round 2
// 356.892 us; speedup vs baseline: 1.2162x; 1.2162x over previous
//
#include <hip/hip_runtime.h>
#include <math.h>

// ---------------- problem constants (fixed by setup_inputs) ----------------
#define B_    4
#define QN    32
#define KN    8192
#define HDIM  1024
#define NHD   16
#define DH    64
#define LCH   128
#define JCH   64

typedef float f32x4 __attribute__((ext_vector_type(4)));
typedef short s16x8 __attribute__((ext_vector_type(8)));
typedef unsigned short u16;

__device__ __forceinline__ u16 f2bf(float f) {          // round-to-nearest-even f32->bf16
  unsigned u = __float_as_uint(f);
  u += 0x7fffu + ((u >> 16) & 1u);
  return (u16)(u >> 16);
}

__device__ __forceinline__ void llds16(const void* g, void* l) {   // 16B global->LDS DMA
  __builtin_amdgcn_global_load_lds((const __attribute__((address_space(1))) unsigned int*)g,
                                   (__attribute__((address_space(3))) unsigned int*)l,
                                   16, 0, 0);
}

// ---------------- context fp32 -> bf16 ----------------
__global__ __launch_bounds__(256) void k_ctx2bf16(const float* __restrict__ ctx, u16* __restrict__ out) {
  const int total4 = B_ * KN * HDIM / 4;
  int idx = blockIdx.x * 256 + threadIdx.x;
  for (int i = idx; i < total4; i += gridDim.x * 256) {
    float4 v = ((const float4*)ctx)[i];
    ushort4 o;
    o.x = f2bf(v.x); o.y = f2bf(v.y); o.z = f2bf(v.z); o.w = f2bf(v.w);
    ((ushort4*)out)[i] = o;
  }
}

// ---------------- generic fp32 tiled GEMM, C += A*B over one K-slice (atomic) ----------------
// grid: (M/64, N/64, K/kchunk), block 256. M,N mult of 64; kchunk mult of 16.
__global__ __launch_bounds__(256) void k_gemm_f32(const float* __restrict__ A, int lda,
                                                  const float* __restrict__ Bm, int ldb,
                                                  float* __restrict__ C, int ldc, int kchunk) {
  __shared__ float As[64][17];
  __shared__ float Bs[16][64];
  int t = threadIdx.x;
  int m0 = blockIdx.x * 64, n0 = blockIdx.y * 64, k0 = blockIdx.z * kchunk;
  int tm = t >> 4, tn = t & 15;
  float c[4][4];
#pragma unroll
  for (int i = 0; i < 4; ++i)
#pragma unroll
    for (int j = 0; j < 4; ++j) c[i][j] = 0.f;
  int ra = t >> 2, ka = (t & 3) * 4;
  int kb = t >> 4, nb = (t & 15) * 4;
  for (int kk = 0; kk < kchunk; kk += 16) {
    float4 va = *(const float4*)(A + (size_t)(m0 + ra) * lda + k0 + kk + ka);
    float4 vb = *(const float4*)(Bm + (size_t)(k0 + kk + kb) * ldb + n0 + nb);
    As[ra][ka] = va.x; As[ra][ka + 1] = va.y; As[ra][ka + 2] = va.z; As[ra][ka + 3] = va.w;
    *(float4*)&Bs[kb][nb] = vb;
    __syncthreads();
#pragma unroll
    for (int kq = 0; kq < 16; ++kq) {
      float a0 = As[tm * 4 + 0][kq], a1 = As[tm * 4 + 1][kq];
      float a2 = As[tm * 4 + 2][kq], a3 = As[tm * 4 + 3][kq];
      float b0 = Bs[kq][tn * 4 + 0], b1 = Bs[kq][tn * 4 + 1];
      float b2 = Bs[kq][tn * 4 + 2], b3 = Bs[kq][tn * 4 + 3];
      c[0][0] += a0 * b0; c[0][1] += a0 * b1; c[0][2] += a0 * b2; c[0][3] += a0 * b3;
      c[1][0] += a1 * b0; c[1][1] += a1 * b1; c[1][2] += a1 * b2; c[1][3] += a1 * b3;
      c[2][0] += a2 * b0; c[2][1] += a2 * b1; c[2][2] += a2 * b2; c[2][3] += a2 * b3;
      c[3][0] += a3 * b0; c[3][1] += a3 * b1; c[3][2] += a3 * b2; c[3][3] += a3 * b3;
    }
    __syncthreads();
  }
#pragma unroll
  for (int i = 0; i < 4; ++i)
#pragma unroll
    for (int j = 0; j < 4; ++j)
      atomicAdd(&C[(size_t)(m0 + tm * 4 + i) * ldc + n0 + tn * 4 + j], c[i][j]);
}

// ---------------- add bq to qh (both scorers) ----------------
__global__ __launch_bounds__(256) void k_qh_bias(float* __restrict__ qh, const float* __restrict__ bq_g,
                                                 const float* __restrict__ bq_l) {
  int i = blockIdx.x * 256 + threadIdx.x;   // 0..262143
  int s2 = i >> 17, n = i & (HDIM - 1);
  qh[i] += (s2 ? bq_l : bq_g)[n];
}

// ---------------- folded score matrix A[b][n][c] (bf16, scale 1/8 folded) ----------------
// n = s2*512 + h*32 + q ; A[b,n,c] = (1/8) sum_d qh[s2][b,q,h*64+d] * Wk_s2[c, h*64+d]
__global__ __launch_bounds__(256) void k_afold(const float* __restrict__ qh, const float* __restrict__ Wk_g,
                                               const float* __restrict__ Wk_l, u16* __restrict__ Ab) {
  int ct = blockIdx.x;          // 0..3  (c tile of 256)
  int slot = blockIdx.y;        // 0..31 (s2*16 + h)
  int b = blockIdx.z;
  int s2 = slot >> 4, h = slot & 15;
  const float* qhp = qh + (size_t)(s2 * 4 + b) * QN * HDIM;
  const float* Wk = s2 ? Wk_l : Wk_g;
  __shared__ float qs[QN][DH];
  int t = threadIdx.x;
  {
    int q = t >> 3, doff = (t & 7) * 8;
    const float4* src = (const float4*)(qhp + (size_t)q * HDIM + h * DH + doff);
    *(float4*)&qs[q][doff] = src[0];
    *(float4*)&qs[q][doff + 4] = src[1];
  }
  __syncthreads();
  int c = ct * 256 + t;
  float w[DH];
  const float* wr = Wk + (size_t)c * HDIM + h * DH;
#pragma unroll
  for (int d = 0; d < DH; d += 4) {
    float4 v = *(const float4*)(wr + d);
    w[d] = v.x; w[d + 1] = v.y; w[d + 2] = v.z; w[d + 3] = v.w;
  }
  u16* outp = Ab + ((size_t)b * HDIM + s2 * 512 + h * QN) * HDIM + c;
  for (int q = 0; q < QN; ++q) {
    float acc = 0.f;
#pragma unroll
    for (int d = 0; d < DH; ++d) acc += qs[q][d] * w[d];
    outp[(size_t)q * HDIM] = f2bf(acc * 0.125f);
  }
}

// ---------------- score bias sbias[b][n] = (1/8) qh . bk ----------------
__global__ __launch_bounds__(256) void k_sbias(const float* __restrict__ qh, const float* __restrict__ bk_g,
                                               const float* __restrict__ bk_l, float* __restrict__ sbias) {
  int i = blockIdx.x * 256 + threadIdx.x;   // 0..4095
  int b = i >> 10, n = i & (HDIM - 1);
  int s2 = n >> 9, hq = n & 511, h = hq >> 5, q = hq & 31;
  const float* qr = qh + ((size_t)(s2 * 4 + b) * QN + q) * HDIM + h * DH;
  const float* bk = (s2 ? bk_l : bk_g) + h * DH;
  float acc = 0.f;
#pragma unroll
  for (int d = 0; d < DH; ++d) acc += qr[d] * bk[d];
  sbias[i] = acc * 0.125f;
}

// ---------------- THE big fused kernel: S = ctx_bf16 @ A^T, column-wise (max,sumexp) per chunk ----
// grid (nt=8, jc=64, b=4), 256 thr (4 waves 2x2), 128x128 tile, K=1024 in 32-steps of 16x16x32 MFMA.
__global__ __launch_bounds__(256) void k_scores(const u16* __restrict__ ctxb, const u16* __restrict__ Ab,
                                                const float* __restrict__ sbias,
                                                float* __restrict__ mglob, float* __restrict__ zglob,
                                                float* __restrict__ locinv) {
  __shared__ u16 At[128 * 32];     // ctx tile  [row(l) 128][k 32]
  __shared__ u16 Bt[128 * 32];     // A-fold tile [n 128][k 32]
  __shared__ float red[2][128];
  int nt = blockIdx.x, jc = blockIdx.y, b = blockIdx.z;
  int t = threadIdx.x;
  int wid = t >> 6, lane = t & 63;
  int wr = wid >> 1, wc = wid & 1;
  int lrow = lane & 15, lkg = lane >> 4;

  const u16* ctx0 = ctxb + (size_t)(b * KN + jc * LCH) * HDIM;
  const u16* A0 = Ab + ((size_t)b * HDIM + nt * 128) * HDIM;

  f32x4 acc[4][4];
#pragma unroll
  for (int i = 0; i < 4; ++i)
#pragma unroll
    for (int j = 0; j < 4; ++j) acc[i][j] = 0.f;

  for (int kt = 0; kt < HDIM / 32; ++kt) {
    __syncthreads();
#pragma unroll
    for (int issue = 0; issue < 2; ++issue) {
      int seg = issue * 4 + wid;
      int chunk = seg * 64 + lane;
      int row = chunk >> 2;
      int ko = (chunk & 3) * 8;
      llds16(ctx0 + (size_t)row * HDIM + kt * 32 + ko, At + seg * 512);
      llds16(A0 + (size_t)row * HDIM + kt * 32 + ko, Bt + seg * 512);
    }
    __syncthreads();
    s16x8 af[4], bf[4];
#pragma unroll
    for (int i = 0; i < 4; ++i) af[i] = *(const s16x8*)(At + (wr * 64 + i * 16 + lrow) * 32 + lkg * 8);
#pragma unroll
    for (int j = 0; j < 4; ++j) bf[j] = *(const s16x8*)(Bt + (wc * 64 + j * 16 + lrow) * 32 + lkg * 8);
#pragma unroll
    for (int i = 0; i < 4; ++i)
#pragma unroll
      for (int j = 0; j < 4; ++j)
        acc[i][j] = __builtin_amdgcn_mfma_f32_16x16x32_bf16(af[i], bf[j], acc[i][j], 0, 0, 0);
  }

  // ---- epilogue: per output column (over 128 chunk rows): max, sumexp ----
  // D mapping (m89-verified): col = lane&15, row = (lane>>4)*4 + reg
  float sb[4], mv[4], Mc[4], zv[4];
#pragma unroll
  for (int fj = 0; fj < 4; ++fj)
    sb[fj] = sbias[b * HDIM + nt * 128 + wc * 64 + fj * 16 + lrow];
#pragma unroll
  for (int fj = 0; fj < 4; ++fj) {
    float m = -1e30f;
#pragma unroll
    for (int fi = 0; fi < 4; ++fi)
#pragma unroll
      for (int r = 0; r < 4; ++r) m = fmaxf(m, acc[fi][fj][r]);
    m += sb[fj];
    m = fmaxf(m, __shfl_xor(m, 16, 64));
    m = fmaxf(m, __shfl_xor(m, 32, 64));
    mv[fj] = m;
  }
  if (lane < 16) {
#pragma unroll
    for (int fj = 0; fj < 4; ++fj) red[wr][wc * 64 + fj * 16 + lane] = mv[fj];
  }
  __syncthreads();
#pragma unroll
  for (int fj = 0; fj < 4; ++fj) {
    int col = wc * 64 + fj * 16 + lrow;
    Mc[fj] = fmaxf(red[0][col], red[1][col]);
  }
  __syncthreads();
#pragma unroll
  for (int fj = 0; fj < 4; ++fj) {
    float s = 0.f;
#pragma unroll
    for (int fi = 0; fi < 4; ++fi)
#pragma unroll
      for (int r = 0; r < 4; ++r) s += __expf(acc[fi][fj][r] + sb[fj] - Mc[fj]);
    s += __shfl_xor(s, 16, 64);
    s += __shfl_xor(s, 32, 64);
    zv[fj] = s;
  }
  if (lane < 16) {
#pragma unroll
    for (int fj = 0; fj < 4; ++fj) red[wr][wc * 64 + fj * 16 + lane] = zv[fj];
  }
  __syncthreads();
  if (wr == 0 && lane < 16) {
    size_t base = (size_t)(b * JCH + jc) * 512;
#pragma unroll
    for (int fj = 0; fj < 4; ++fj) {
      int col = wc * 64 + fj * 16 + lane;
      float Z = red[0][col] + red[1][col];
      int n = nt * 128 + col;
      if (n < 512) { mglob[base + n] = Mc[fj]; zglob[base + n] = Z; }
      else         { locinv[base + n - 512] = 1.0f / Z; }
    }
  }
}

// ---------------- LN(mean over Q) of question -> qvec[b][1024] ----------------
__global__ __launch_bounds__(256) void k_qvec(const float* __restrict__ q, const float* __restrict__ g,
                                              const float* __restrict__ lb, float* __restrict__ qvec) {
  int b = blockIdx.x, t = threadIdx.x;
  const float* p = q + (size_t)b * QN * HDIM + t * 4;
  float a0 = 0, a1 = 0, a2 = 0, a3 = 0;
  for (int r = 0; r < QN; ++r) {
    float4 v = *(const float4*)(p + (size_t)r * HDIM);
    a0 += v.x; a1 += v.y; a2 += v.z; a3 += v.w;
  }
  const float sc = 1.0f / QN;
  a0 *= sc; a1 *= sc; a2 *= sc; a3 *= sc;
  float s = a0 + a1 + a2 + a3;
  float ss = a0 * a0 + a1 * a1 + a2 * a2 + a3 * a3;
#pragma unroll
  for (int o = 1; o < 64; o <<= 1) { s += __shfl_xor(s, o, 64); ss += __shfl_xor(ss, o, 64); }
  __shared__ float sm[4], sq[4];
  int wid = t >> 6, lane = t & 63;
  if (lane == 0) { sm[wid] = s; sq[wid] = ss; }
  __syncthreads();
  float S = sm[0] + sm[1] + sm[2] + sm[3], SS = sq[0] + sq[1] + sq[2] + sq[3];
  float mu = S / HDIM;
  float inv = rsqrtf(SS / HDIM - mu * mu + 1e-5f);
  int c = t * 4;
  float4 o;
  o.x = (a0 - mu) * inv * g[c + 0] + lb[c + 0];
  o.y = (a1 - mu) * inv * g[c + 1] + lb[c + 1];
  o.z = (a2 - mu) * inv * g[c + 2] + lb[c + 2];
  o.w = (a3 - mu) * inv * g[c + 3] + lb[c + 3];
  *(float4*)&qvec[(size_t)b * HDIM + c] = o;
}

// ---------------- LN(mean over L) of context chunks -> cvec[b*64+j][1024] ----------------
__global__ __launch_bounds__(256) void k_cvec(const float* __restrict__ ctx, const float* __restrict__ g,
                                              const float* __restrict__ lb, float* __restrict__ cvec) {
  int bj = blockIdx.x, t = threadIdx.x;
  int b = bj >> 6, jc = bj & 63;
  const float* p = ctx + ((size_t)b * KN + jc * LCH) * HDIM + t * 4;
  float a0 = 0, a1 = 0, a2 = 0, a3 = 0;
  for (int r = 0; r < LCH; ++r) {
    float4 v = *(const float4*)(p + (size_t)r * HDIM);
    a0 += v.x; a1 += v.y; a2 += v.z; a3 += v.w;
  }
  const float sc = 1.0f / LCH;
  a0 *= sc; a1 *= sc; a2 *= sc; a3 *= sc;
  float s = a0 + a1 + a2 + a3;
  float ss = a0 * a0 + a1 * a1 + a2 * a2 + a3 * a3;
#pragma unroll
  for (int o = 1; o < 64; o <<= 1) { s += __shfl_xor(s, o, 64); ss += __shfl_xor(ss, o, 64); }
  __shared__ float sm[4], sq[4];
  int wid = t >> 6, lane = t & 63;
  if (lane == 0) { sm[wid] = s; sq[wid] = ss; }
  __syncthreads();
  float S = sm[0] + sm[1] + sm[2] + sm[3], SS = sq[0] + sq[1] + sq[2] + sq[3];
  float mu = S / HDIM;
  float inv = rsqrtf(SS / HDIM - mu * mu + 1e-5f);
  int c = t * 4;
  float4 o;
  o.x = (a0 - mu) * inv * g[c + 0] + lb[c + 0];
  o.y = (a1 - mu) * inv * g[c + 1] + lb[c + 1];
  o.z = (a2 - mu) * inv * g[c + 2] + lb[c + 2];
  o.w = (a3 - mu) * inv * g[c + 3] + lb[c + 3];
  *(float4*)&cvec[(size_t)bj * HDIM + c] = o;
}

// ---------------- qpart[b][n] += qvec[b][c-slice] . W1[c-slice, n]  (split-K, 256 blocks) ------
// grid (4 ntiles, B, 16 kslices), block 256. Coalesced W1 row reads; atomicAdd partials.
__global__ __launch_bounds__(256) void k_qpart(const float* __restrict__ qvec, const float* __restrict__ W1,
                                               float* __restrict__ qpart) {
  int nt = blockIdx.x, b = blockIdx.y, ks = blockIdx.z;
  int n = nt * 256 + threadIdx.x;
  const float* qv = qvec + (size_t)b * HDIM + ks * 64;
  const float* wp = W1 + (size_t)ks * 64 * HDIM + n;
  float acc = 0.f;
#pragma unroll 8
  for (int c = 0; c < 64; ++c) acc += qv[c] * wp[(size_t)c * HDIM];
  atomicAdd(&qpart[(size_t)b * HDIM + n], acc);
}

// ---------------- h1 = gelu(h1pre + qpart + b1), exact erf gelu, in-place ----------------
__global__ __launch_bounds__(256) void k_gelu(const float* __restrict__ h1in, const float* __restrict__ qpart,
                                              const float* __restrict__ b1, float* __restrict__ h1out) {
  int i = blockIdx.x * 256 + threadIdx.x;   // 0..262143
  int bj = i >> 10, n = i & (HDIM - 1);
  int b = bj >> 6;
  float x = h1in[i] + qpart[(size_t)b * HDIM + n] + b1[n];
  h1out[i] = x * 0.5f * (1.0f + erff(x * 0.70710678118654752f));
}

// ---------------- finalize: global/local pooling, gate, softmaxes, outputs ----------------
__global__ __launch_bounds__(256) void k_final(const float* __restrict__ mglob, const float* __restrict__ zglob,
                                               const float* __restrict__ locinv, const float* __restrict__ h1,
                                               const float* __restrict__ W2, const float* __restrict__ b2,
                                               float* __restrict__ out) {
  __shared__ float Mh[512], Zt[512];
  __shared__ float att4[64][4], loc4[64][4], gat4[64][4];
  int b = blockIdx.x, t = threadIdx.x;
  const float* mg = mglob + (size_t)b * JCH * 512;
  const float* zg = zglob + (size_t)b * JCH * 512;
  for (int hq = t; hq < 512; hq += 256) {
    float m = -1e30f;
    for (int j = 0; j < JCH; ++j) m = fmaxf(m, mg[j * 512 + hq]);
    float z = 0.f;
    for (int j = 0; j < JCH; ++j) z += zg[j * 512 + hq] * __expf(mg[j * 512 + hq] - m);
    Mh[hq] = m; Zt[hq] = z;
  }
  __syncthreads();
  {
    int j = t >> 2, p = t & 3;
    float s = 0.f;
    for (int hq = p * 128; hq < p * 128 + 128; ++hq)
      s += zg[j * 512 + hq] * __expf(mg[j * 512 + hq] - Mh[hq]) / Zt[hq];
    att4[j][p] = s;
    float sl = 0.f;
    const float* lp = locinv + (size_t)(b * JCH + j) * 512;
    for (int hq = p * 128; hq < p * 128 + 128; ++hq) sl += lp[hq];
    loc4[j][p] = sl;
    float sg = 0.f;
    const float* hp = h1 + (size_t)(b * JCH + j) * HDIM;
    for (int n = p * 256; n < p * 256 + 256; ++n) sg += hp[n] * W2[n];
    gat4[j][p] = sg;
  }
  __syncthreads();
  if (t < 64) {
    float a = (att4[t][0] + att4[t][1] + att4[t][2] + att4[t][3]) * (1.0f / 65536.0f);
    float l = (loc4[t][0] + loc4[t][1] + loc4[t][2] + loc4[t][3]) * (1.0f / 512.0f);
    float gt = gat4[t][0] + gat4[t][1] + gat4[t][2] + gat4[t][3] + b2[0];
    gt = 1.0f / (1.0f + __expf(-gt));
    float am = a, lm = l;
#pragma unroll
    for (int o = 1; o < 64; o <<= 1) { am = fmaxf(am, __shfl_xor(am, o, 64)); lm = fmaxf(lm, __shfl_xor(lm, o, 64)); }
    float ae = __expf(a - am), le = __expf(l - lm);
    float as_ = ae, ls_ = le;
#pragma unroll
    for (int o = 1; o < 64; o <<= 1) { as_ += __shfl_xor(as_, o, 64); ls_ += __shfl_xor(ls_, o, 64); }
    float gs = ae / as_, ls = le / ls_;
    float fu = gt * ls + (1.0f - gt) * gs;
    float fm = fu;
#pragma unroll
    for (int o = 1; o < 64; o <<= 1) fm = fmaxf(fm, __shfl_xor(fm, o, 64));
    float fe = __expf(fu - fm);
    float fs_ = fe;
#pragma unroll
    for (int o = 1; o < 64; o <<= 1) fs_ += __shfl_xor(fs_, o, 64);
    float fv = fe / fs_;
    out[b * 64 + t] = fv;
    out[256 + b * 64 + t] = ls;
    out[512 + b * 64 + t] = gs;
    float tot = fv;
#pragma unroll
    for (int o = 1; o < 64; o <<= 1) tot += __shfl_xor(tot, o, 64);
    if (t == 0) out[768 + b] = tot * (1.0f / 64.0f);
  }
}

// ---------------- launcher ----------------
extern "C" void kernel_launch(void* const* d_in, const int* in_sizes, int n_in,
                              void* d_out, int out_size, void* d_ws, size_t ws_size,
                              hipStream_t stream) {
  const float* question = (const float*)d_in[0];
  const float* context  = (const float*)d_in[1];
  const float* Wq_l = (const float*)d_in[2];
  const float* bq_l = (const float*)d_in[3];
  const float* Wk_l = (const float*)d_in[4];
  const float* bk_l = (const float*)d_in[5];
  const float* Wq_g = (const float*)d_in[6];
  const float* bq_g = (const float*)d_in[7];
  const float* Wk_g = (const float*)d_in[8];
  const float* bk_g = (const float*)d_in[9];
  const float* ln_g = (const float*)d_in[10];
  const float* ln_b = (const float*)d_in[11];
  const float* W1   = (const float*)d_in[12];
  const float* b1   = (const float*)d_in[13];
  const float* W2   = (const float*)d_in[14];
  const float* b2   = (const float*)d_in[15];

  char* ws = (char*)d_ws;
  u16*   ctxb   = (u16*)(ws + 0);            // 67108864 B
  u16*   Ab     = (u16*)(ws + 67108864);     //  8388608 B
  float* qh     = (float*)(ws + 75497472);   //  1048576 B  [2][4][32][1024]
  float* sbias  = (float*)(ws + 76546048);   //    16384 B
  float* mglob  = (float*)(ws + 76562432);   //   524288 B  [4][64][512]
  float* zglob  = (float*)(ws + 77086720);   //   524288 B
  float* locinv = (float*)(ws + 77611008);   //   524288 B
  float* qvec   = (float*)(ws + 78135296);   //    16384 B
  float* cvec   = (float*)(ws + 78151680);   //  1048576 B  [256][1024]
  float* qpart  = (float*)(ws + 79200256);   //    16384 B
  float* h1     = (float*)(ws + 79216640);   //  1048576 B  [256][1024]

  hipMemsetAsync(qh, 0, 1048576, stream);
  hipMemsetAsync(h1, 0, 1048576, stream);
  hipMemsetAsync(qpart, 0, 16384, stream);

  hipLaunchKernelGGL(k_ctx2bf16, dim3(2048), dim3(256), 0, stream, context, ctxb);
  // qh_g / qh_l : question[128x1024] @ Wq[1024x1024]
  hipLaunchKernelGGL(k_gemm_f32, dim3(2, 16, 8), dim3(256), 0, stream, question, HDIM, Wq_g, HDIM, qh, HDIM, 128);
  hipLaunchKernelGGL(k_gemm_f32, dim3(2, 16, 8), dim3(256), 0, stream, question, HDIM, Wq_l, HDIM, qh + 131072, HDIM, 128);
  hipLaunchKernelGGL(k_qh_bias, dim3(1024), dim3(256), 0, stream, qh, bq_g, bq_l);
  hipLaunchKernelGGL(k_afold, dim3(4, 32, 4), dim3(256), 0, stream, qh, Wk_g, Wk_l, Ab);
  hipLaunchKernelGGL(k_sbias, dim3(16), dim3(256), 0, stream, qh, bk_g, bk_l, sbias);
  hipLaunchKernelGGL(k_scores, dim3(8, 64, 4), dim3(256), 0, stream, ctxb, Ab, sbias, mglob, zglob, locinv);
  hipLaunchKernelGGL(k_qvec, dim3(4), dim3(256), 0, stream, question, ln_g, ln_b, qvec);
  hipLaunchKernelGGL(k_cvec, dim3(256), dim3(256), 0, stream, context, ln_g, ln_b, cvec);
  hipLaunchKernelGGL(k_qpart, dim3(4, 4, 16), dim3(256), 0, stream, qvec, W1, qpart);
  // h1pre += cvec[256x1024] @ W1[1024:2048, :]
  hipLaunchKernelGGL(k_gemm_f32, dim3(4, 16, 8), dim3(256), 0, stream, cvec, HDIM, W1 + 1048576, HDIM, h1, HDIM, 128);
  hipLaunchKernelGGL(k_gelu, dim3(1024), dim3(256), 0, stream, h1, qpart, b1, h1);
  hipLaunchKernelGGL(k_final, dim3(4), dim3(256), 0, stream, mglob, zglob, locinv, h1, W2, b2, (float*)d_out);
}

// Round 4
// 310.438 us; speedup vs baseline: 1.3982x; 1.1496x over previous
//
#include <hip/hip_runtime.h>
#include <math.h>

// ---------------- problem constants (fixed by setup_inputs) ----------------
#define B_    4
#define QN    32
#define KN    8192
#define HDIM  1024
#define NHD   16
#define DH    64
#define LCH   128
#define JCH   64

typedef float f32x4 __attribute__((ext_vector_type(4)));
typedef short s16x8 __attribute__((ext_vector_type(8)));
typedef unsigned short u16;

__device__ __forceinline__ u16 f2bf(float f) {          // round-to-nearest-even f32->bf16
  unsigned u = __float_as_uint(f);
  u += 0x7fffu + ((u >> 16) & 1u);
  return (u16)(u >> 16);
}

__device__ __forceinline__ float bf2f(u16 v) {
  return __uint_as_float(((unsigned)v) << 16);
}

__device__ __forceinline__ void llds16(const void* g, void* l) {   // 16B global->LDS DMA
  __builtin_amdgcn_global_load_lds((const __attribute__((address_space(1))) unsigned int*)g,
                                   (__attribute__((address_space(3))) unsigned int*)l,
                                   16, 0, 0);
}

// ---------------- context fp32 -> bf16 ----------------
__global__ __launch_bounds__(256) void k_ctx2bf16(const float* __restrict__ ctx, u16* __restrict__ out) {
  const int total4 = B_ * KN * HDIM / 4;
  int idx = blockIdx.x * 256 + threadIdx.x;
  for (int i = idx; i < total4; i += gridDim.x * 256) {
    float4 v = ((const float4*)ctx)[i];
    ushort4 o;
    o.x = f2bf(v.x); o.y = f2bf(v.y); o.z = f2bf(v.z); o.w = f2bf(v.w);
    ((ushort4*)out)[i] = o;
  }
}

// ---------------- generic fp32 tiled GEMM, C += A*B over one K-slice (atomic) ----------------
__global__ __launch_bounds__(256) void k_gemm_f32(const float* __restrict__ A, int lda,
                                                  const float* __restrict__ Bm, int ldb,
                                                  float* __restrict__ C, int ldc, int kchunk) {
  __shared__ float As[64][17];
  __shared__ float Bs[16][64];
  int t = threadIdx.x;
  int m0 = blockIdx.x * 64, n0 = blockIdx.y * 64, k0 = blockIdx.z * kchunk;
  int tm = t >> 4, tn = t & 15;
  float c[4][4];
#pragma unroll
  for (int i = 0; i < 4; ++i)
#pragma unroll
    for (int j = 0; j < 4; ++j) c[i][j] = 0.f;
  int ra = t >> 2, ka = (t & 3) * 4;
  int kb = t >> 4, nb = (t & 15) * 4;
  for (int kk = 0; kk < kchunk; kk += 16) {
    float4 va = *(const float4*)(A + (size_t)(m0 + ra) * lda + k0 + kk + ka);
    float4 vb = *(const float4*)(Bm + (size_t)(k0 + kk + kb) * ldb + n0 + nb);
    As[ra][ka] = va.x; As[ra][ka + 1] = va.y; As[ra][ka + 2] = va.z; As[ra][ka + 3] = va.w;
    *(float4*)&Bs[kb][nb] = vb;
    __syncthreads();
#pragma unroll
    for (int kq = 0; kq < 16; ++kq) {
      float a0 = As[tm * 4 + 0][kq], a1 = As[tm * 4 + 1][kq];
      float a2 = As[tm * 4 + 2][kq], a3 = As[tm * 4 + 3][kq];
      float b0 = Bs[kq][tn * 4 + 0], b1 = Bs[kq][tn * 4 + 1];
      float b2 = Bs[kq][tn * 4 + 2], b3 = Bs[kq][tn * 4 + 3];
      c[0][0] += a0 * b0; c[0][1] += a0 * b1; c[0][2] += a0 * b2; c[0][3] += a0 * b3;
      c[1][0] += a1 * b0; c[1][1] += a1 * b1; c[1][2] += a1 * b2; c[1][3] += a1 * b3;
      c[2][0] += a2 * b0; c[2][1] += a2 * b1; c[2][2] += a2 * b2; c[2][3] += a2 * b3;
      c[3][0] += a3 * b0; c[3][1] += a3 * b1; c[3][2] += a3 * b2; c[3][3] += a3 * b3;
    }
    __syncthreads();
  }
#pragma unroll
  for (int i = 0; i < 4; ++i)
#pragma unroll
    for (int j = 0; j < 4; ++j)
      atomicAdd(&C[(size_t)(m0 + tm * 4 + i) * ldc + n0 + tn * 4 + j], c[i][j]);
}

// ---------------- add bq to qh (both scorers) ----------------
__global__ __launch_bounds__(256) void k_qh_bias(float* __restrict__ qh, const float* __restrict__ bq_g,
                                                 const float* __restrict__ bq_l) {
  int i = blockIdx.x * 256 + threadIdx.x;   // 0..262143
  int s2 = i >> 17, n = i & (HDIM - 1);
  qh[i] += (s2 ? bq_l : bq_g)[n];
}

// ---------------- folded score matrix A[b][n][c] (bf16, scale 1/8 folded) ----------------
__global__ __launch_bounds__(256) void k_afold(const float* __restrict__ qh, const float* __restrict__ Wk_g,
                                               const float* __restrict__ Wk_l, u16* __restrict__ Ab) {
  int ct = blockIdx.x;          // 0..3  (c tile of 256)
  int slot = blockIdx.y;        // 0..31 (s2*16 + h)
  int b = blockIdx.z;
  int s2 = slot >> 4, h = slot & 15;
  const float* qhp = qh + (size_t)(s2 * 4 + b) * QN * HDIM;
  const float* Wk = s2 ? Wk_l : Wk_g;
  __shared__ float qs[QN][DH];
  int t = threadIdx.x;
  {
    int q = t >> 3, doff = (t & 7) * 8;
    const float4* src = (const float4*)(qhp + (size_t)q * HDIM + h * DH + doff);
    *(float4*)&qs[q][doff] = src[0];
    *(float4*)&qs[q][doff + 4] = src[1];
  }
  __syncthreads();
  int c = ct * 256 + t;
  float w[DH];
  const float* wr = Wk + (size_t)c * HDIM + h * DH;
#pragma unroll
  for (int d = 0; d < DH; d += 4) {
    float4 v = *(const float4*)(wr + d);
    w[d] = v.x; w[d + 1] = v.y; w[d + 2] = v.z; w[d + 3] = v.w;
  }
  u16* outp = Ab + ((size_t)b * HDIM + s2 * 512 + h * QN) * HDIM + c;
  for (int q = 0; q < QN; ++q) {
    float acc = 0.f;
#pragma unroll
    for (int d = 0; d < DH; ++d) acc += qs[q][d] * w[d];
    outp[(size_t)q * HDIM] = f2bf(acc * 0.125f);
  }
}

// ---------------- score bias sbias[b][n] = (1/8) qh . bk ----------------
__global__ __launch_bounds__(256) void k_sbias(const float* __restrict__ qh, const float* __restrict__ bk_g,
                                               const float* __restrict__ bk_l, float* __restrict__ sbias) {
  int i = blockIdx.x * 256 + threadIdx.x;   // 0..4095
  int b = i >> 10, n = i & (HDIM - 1);
  int s2 = n >> 9, hq = n & 511, h = hq >> 5, q = hq & 31;
  const float* qr = qh + ((size_t)(s2 * 4 + b) * QN + q) * HDIM + h * DH;
  const float* bk = (s2 ? bk_l : bk_g) + h * DH;
  float acc = 0.f;
#pragma unroll
  for (int d = 0; d < DH; ++d) acc += qr[d] * bk[d];
  sbias[i] = acc * 0.125f;
}

// ---------------- THE big fused kernel: S = ctx_bf16 @ A^T, column-wise (max,sumexp) per chunk ----
// grid 2048 blocks (XCD-remapped), 256 thr (4 waves 2x2), 128x128 tile, dbuf BK=32, MFMA 16x16x32.
// LDS XOR swizzle (both-sides, rule #21): physical slot = logical_slot ^ ((row>>1)&3).
__global__ __launch_bounds__(256) void k_scores(const u16* __restrict__ ctxb, const u16* __restrict__ Ab,
                                                const float* __restrict__ sbias,
                                                float* __restrict__ mglob, float* __restrict__ zglob,
                                                float* __restrict__ locinv) {
  __shared__ u16 At[2][128 * 32];
  __shared__ u16 Bt[2][128 * 32];
  __shared__ float red[2][128];
  // XCD-bijective remap: 2048 blocks, 8 XCDs -> XCD x owns contiguous work [x*256, x*256+256)
  int bid = blockIdx.x;
  int work = (bid & 7) * 256 + (bid >> 3);
  int nt = work & 7, jc = (work >> 3) & 63, b = work >> 9;
  int t = threadIdx.x;
  int wid = t >> 6, lane = t & 63;
  int wr = wid >> 1, wc = wid & 1;
  int lrow = lane & 15, lkg = lane >> 4;

  const u16* ctx0 = ctxb + (size_t)(b * KN + jc * LCH) * HDIM;
  const u16* A0 = Ab + ((size_t)b * HDIM + nt * 128) * HDIM;

  // per-lane staging geometry (same for every kt): physical chunk = seg*64+lane
  int chunk0 = wid * 64 + lane, chunk1 = chunk0 + 256;
  int row0 = chunk0 >> 2, sp0 = chunk0 & 3, sg0 = sp0 ^ ((row0 >> 1) & 3);
  int row1 = chunk1 >> 2, sp1 = chunk1 & 3, sg1 = sp1 ^ ((row1 >> 1) & 3);
  size_t srcoff0 = (size_t)row0 * HDIM + sg0 * 8;
  size_t srcoff1 = (size_t)row1 * HDIM + sg1 * 8;

  f32x4 acc[4][4];
#pragma unroll
  for (int i = 0; i < 4; ++i)
#pragma unroll
    for (int j = 0; j < 4; ++j) acc[i][j] = 0.f;

  // prologue: stage kt=0 into buffer 0
  llds16(ctx0 + srcoff0, At[0] + wid * 512);
  llds16(ctx0 + srcoff1, At[0] + wid * 512 + 2048);
  llds16(A0 + srcoff0, Bt[0] + wid * 512);
  llds16(A0 + srcoff1, Bt[0] + wid * 512 + 2048);
  __syncthreads();

  for (int kt = 0; kt < HDIM / 32; ++kt) {
    int cur = kt & 1;
    if (kt < HDIM / 32 - 1) {        // prefetch next tile into other buffer (overlaps MFMA)
      int nxt = cur ^ 1;
      size_t ko = (size_t)(kt + 1) * 32;
      llds16(ctx0 + ko + srcoff0, At[nxt] + wid * 512);
      llds16(ctx0 + ko + srcoff1, At[nxt] + wid * 512 + 2048);
      llds16(A0 + ko + srcoff0, Bt[nxt] + wid * 512);
      llds16(A0 + ko + srcoff1, Bt[nxt] + wid * 512 + 2048);
    }
    s16x8 af[4], bf[4];
#pragma unroll
    for (int i = 0; i < 4; ++i) {
      int R = wr * 64 + i * 16 + lrow;
      af[i] = *(const s16x8*)(At[cur] + R * 32 + (lkg ^ ((R >> 1) & 3)) * 8);
    }
#pragma unroll
    for (int j = 0; j < 4; ++j) {
      int R = wc * 64 + j * 16 + lrow;
      bf[j] = *(const s16x8*)(Bt[cur] + R * 32 + (lkg ^ ((R >> 1) & 3)) * 8);
    }
#pragma unroll
    for (int i = 0; i < 4; ++i)
#pragma unroll
      for (int j = 0; j < 4; ++j)
        acc[i][j] = __builtin_amdgcn_mfma_f32_16x16x32_bf16(af[i], bf[j], acc[i][j], 0, 0, 0);
    __syncthreads();   // drains vmcnt (next buffer ready) + guards LDS reuse
  }

  // ---- epilogue: per output column (over 128 chunk rows): max, sumexp ----
  // D mapping (m89-verified): col = lane&15, row = (lane>>4)*4 + reg
  float sb[4], mv[4], Mc[4], zv[4];
#pragma unroll
  for (int fj = 0; fj < 4; ++fj)
    sb[fj] = sbias[b * HDIM + nt * 128 + wc * 64 + fj * 16 + lrow];
#pragma unroll
  for (int fj = 0; fj < 4; ++fj) {
    float m = -1e30f;
#pragma unroll
    for (int fi = 0; fi < 4; ++fi)
#pragma unroll
      for (int r = 0; r < 4; ++r) m = fmaxf(m, acc[fi][fj][r]);
    m += sb[fj];
    m = fmaxf(m, __shfl_xor(m, 16, 64));
    m = fmaxf(m, __shfl_xor(m, 32, 64));
    mv[fj] = m;
  }
  if (lane < 16) {
#pragma unroll
    for (int fj = 0; fj < 4; ++fj) red[wr][wc * 64 + fj * 16 + lane] = mv[fj];
  }
  __syncthreads();
#pragma unroll
  for (int fj = 0; fj < 4; ++fj) {
    int col = wc * 64 + fj * 16 + lrow;
    Mc[fj] = fmaxf(red[0][col], red[1][col]);
  }
  __syncthreads();
#pragma unroll
  for (int fj = 0; fj < 4; ++fj) {
    float s = 0.f;
#pragma unroll
    for (int fi = 0; fi < 4; ++fi)
#pragma unroll
      for (int r = 0; r < 4; ++r) s += __expf(acc[fi][fj][r] + sb[fj] - Mc[fj]);
    s += __shfl_xor(s, 16, 64);
    s += __shfl_xor(s, 32, 64);
    zv[fj] = s;
  }
  if (lane < 16) {
#pragma unroll
    for (int fj = 0; fj < 4; ++fj) red[wr][wc * 64 + fj * 16 + lane] = zv[fj];
  }
  __syncthreads();
  if (wr == 0 && lane < 16) {
    size_t base = (size_t)(b * JCH + jc) * 512;
#pragma unroll
    for (int fj = 0; fj < 4; ++fj) {
      int col = wc * 64 + fj * 16 + lane;
      float Z = red[0][col] + red[1][col];
      int n = nt * 128 + col;
      if (n < 512) { mglob[base + n] = Mc[fj]; zglob[base + n] = Z; }
      else         { locinv[base + n - 512] = 1.0f / Z; }
    }
  }
}

// ---------------- LN(mean over Q) of question -> qvec[b][1024] ----------------
__global__ __launch_bounds__(256) void k_qvec(const float* __restrict__ q, const float* __restrict__ g,
                                              const float* __restrict__ lb, float* __restrict__ qvec) {
  int b = blockIdx.x, t = threadIdx.x;
  const float* p = q + (size_t)b * QN * HDIM + t * 4;
  float a0 = 0, a1 = 0, a2 = 0, a3 = 0;
  for (int r = 0; r < QN; ++r) {
    float4 v = *(const float4*)(p + (size_t)r * HDIM);
    a0 += v.x; a1 += v.y; a2 += v.z; a3 += v.w;
  }
  const float sc = 1.0f / QN;
  a0 *= sc; a1 *= sc; a2 *= sc; a3 *= sc;
  float s = a0 + a1 + a2 + a3;
  float ss = a0 * a0 + a1 * a1 + a2 * a2 + a3 * a3;
#pragma unroll
  for (int o = 1; o < 64; o <<= 1) { s += __shfl_xor(s, o, 64); ss += __shfl_xor(ss, o, 64); }
  __shared__ float sm[4], sq[4];
  int wid = t >> 6, lane = t & 63;
  if (lane == 0) { sm[wid] = s; sq[wid] = ss; }
  __syncthreads();
  float S = sm[0] + sm[1] + sm[2] + sm[3], SS = sq[0] + sq[1] + sq[2] + sq[3];
  float mu = S / HDIM;
  float inv = rsqrtf(SS / HDIM - mu * mu + 1e-5f);
  int c = t * 4;
  float4 o;
  o.x = (a0 - mu) * inv * g[c + 0] + lb[c + 0];
  o.y = (a1 - mu) * inv * g[c + 1] + lb[c + 1];
  o.z = (a2 - mu) * inv * g[c + 2] + lb[c + 2];
  o.w = (a3 - mu) * inv * g[c + 3] + lb[c + 3];
  *(float4*)&qvec[(size_t)b * HDIM + c] = o;
}

// ---------------- LN(mean over L) of context chunks (bf16 src) -> cvec[b*64+j][1024] ----------------
__global__ __launch_bounds__(256) void k_cvec(const u16* __restrict__ ctxb, const float* __restrict__ g,
                                              const float* __restrict__ lb, float* __restrict__ cvec) {
  int bj = blockIdx.x, t = threadIdx.x;
  int b = bj >> 6, jc = bj & 63;
  const u16* p = ctxb + ((size_t)b * KN + jc * LCH) * HDIM + t * 4;
  float a0 = 0, a1 = 0, a2 = 0, a3 = 0;
  for (int r = 0; r < LCH; ++r) {
    ushort4 v = *(const ushort4*)(p + (size_t)r * HDIM);
    a0 += bf2f(v.x); a1 += bf2f(v.y); a2 += bf2f(v.z); a3 += bf2f(v.w);
  }
  const float sc = 1.0f / LCH;
  a0 *= sc; a1 *= sc; a2 *= sc; a3 *= sc;
  float s = a0 + a1 + a2 + a3;
  float ss = a0 * a0 + a1 * a1 + a2 * a2 + a3 * a3;
#pragma unroll
  for (int o = 1; o < 64; o <<= 1) { s += __shfl_xor(s, o, 64); ss += __shfl_xor(ss, o, 64); }
  __shared__ float sm[4], sq[4];
  int wid = t >> 6, lane = t & 63;
  if (lane == 0) { sm[wid] = s; sq[wid] = ss; }
  __syncthreads();
  float S = sm[0] + sm[1] + sm[2] + sm[3], SS = sq[0] + sq[1] + sq[2] + sq[3];
  float mu = S / HDIM;
  float inv = rsqrtf(SS / HDIM - mu * mu + 1e-5f);
  int c = t * 4;
  float4 o;
  o.x = (a0 - mu) * inv * g[c + 0] + lb[c + 0];
  o.y = (a1 - mu) * inv * g[c + 1] + lb[c + 1];
  o.z = (a2 - mu) * inv * g[c + 2] + lb[c + 2];
  o.w = (a3 - mu) * inv * g[c + 3] + lb[c + 3];
  *(float4*)&cvec[(size_t)bj * HDIM + c] = o;
}

// ---------------- qpart[b][n] += qvec[b][c-slice] . W1[c-slice, n]  (split-K, 256 blocks) ------
__global__ __launch_bounds__(256) void k_qpart(const float* __restrict__ qvec, const float* __restrict__ W1,
                                               float* __restrict__ qpart) {
  int nt = blockIdx.x, b = blockIdx.y, ks = blockIdx.z;
  int n = nt * 256 + threadIdx.x;
  const float* qv = qvec + (size_t)b * HDIM + ks * 64;
  const float* wp = W1 + (size_t)ks * 64 * HDIM + n;
  float acc = 0.f;
#pragma unroll 8
  for (int c = 0; c < 64; ++c) acc += qv[c] * wp[(size_t)c * HDIM];
  atomicAdd(&qpart[(size_t)b * HDIM + n], acc);
}

// ---------------- h1 = gelu(h1pre + qpart + b1), exact erf gelu, in-place ----------------
__global__ __launch_bounds__(256) void k_gelu(const float* __restrict__ h1in, const float* __restrict__ qpart,
                                              const float* __restrict__ b1, float* __restrict__ h1out) {
  int i = blockIdx.x * 256 + threadIdx.x;   // 0..262143
  int bj = i >> 10, n = i & (HDIM - 1);
  int b = bj >> 6;
  float x = h1in[i] + qpart[(size_t)b * HDIM + n] + b1[n];
  h1out[i] = x * 0.5f * (1.0f + erff(x * 0.70710678118654752f));
}

// ---------------- per-(b,hq) global max/denominator over chunks ----------------
__global__ __launch_bounds__(256) void k_hq(const float* __restrict__ mglob, const float* __restrict__ zglob,
                                            float* __restrict__ Mh, float* __restrict__ Zr) {
  int id = blockIdx.x * 256 + threadIdx.x;   // 0..2047
  int b = id >> 9, hq = id & 511;
  const float* mg = mglob + (size_t)b * JCH * 512 + hq;
  const float* zg = zglob + (size_t)b * JCH * 512 + hq;
  float m = -1e30f;
  for (int j = 0; j < JCH; ++j) m = fmaxf(m, mg[(size_t)j * 512]);
  float z = 0.f;
  for (int j = 0; j < JCH; ++j) z += zg[(size_t)j * 512] * __expf(mg[(size_t)j * 512] - m);
  Mh[id] = m;
  Zr[id] = 1.0f / z;
}

// ---------------- per-(b,j) pooled scalars: att, loc, gate-dot ----------------
__global__ __launch_bounds__(256) void k_chunk(const float* __restrict__ mglob, const float* __restrict__ zglob,
                                               const float* __restrict__ locinv,
                                               const float* __restrict__ Mh, const float* __restrict__ Zr,
                                               const float* __restrict__ h1, const float* __restrict__ W2,
                                               float* __restrict__ abuf, float* __restrict__ lbuf,
                                               float* __restrict__ gbuf) {
  int bj = blockIdx.x, t = threadIdx.x;
  int b = bj >> 6;
  const float* mg = mglob + (size_t)bj * 512;
  const float* zg = zglob + (size_t)bj * 512;
  const float* lp = locinv + (size_t)bj * 512;
  const float* Mb = Mh + (size_t)b * 512;
  const float* Zb = Zr + (size_t)b * 512;
  float a = 0.f, l = 0.f, gsum = 0.f;
  for (int hq = t; hq < 512; hq += 256) {
    a += zg[hq] * __expf(mg[hq] - Mb[hq]) * Zb[hq];
    l += lp[hq];
  }
  const float* hp = h1 + (size_t)bj * HDIM;
  for (int n = t; n < HDIM; n += 256) gsum += hp[n] * W2[n];
#pragma unroll
  for (int o = 1; o < 64; o <<= 1) {
    a += __shfl_xor(a, o, 64); l += __shfl_xor(l, o, 64); gsum += __shfl_xor(gsum, o, 64);
  }
  __shared__ float ra[4], rl[4], rg[4];
  int wid = t >> 6, lane = t & 63;
  if (lane == 0) { ra[wid] = a; rl[wid] = l; rg[wid] = gsum; }
  __syncthreads();
  if (t == 0) {
    abuf[bj] = (ra[0] + ra[1] + ra[2] + ra[3]) * (1.0f / 65536.0f);
    lbuf[bj] = (rl[0] + rl[1] + rl[2] + rl[3]) * (1.0f / 512.0f);
    gbuf[bj] = rg[0] + rg[1] + rg[2] + rg[3];
  }
}

// ---------------- final: softmaxes over J, fuse, outputs ----------------
__global__ __launch_bounds__(64) void k_final(const float* __restrict__ abuf, const float* __restrict__ lbuf,
                                              const float* __restrict__ gbuf, const float* __restrict__ b2,
                                              float* __restrict__ out) {
  int b = blockIdx.x, t = threadIdx.x;   // 64 threads
  float a = abuf[b * 64 + t];
  float l = lbuf[b * 64 + t];
  float gt = gbuf[b * 64 + t] + b2[0];
  gt = 1.0f / (1.0f + __expf(-gt));
  float am = a, lm = l;
#pragma unroll
  for (int o = 1; o < 64; o <<= 1) { am = fmaxf(am, __shfl_xor(am, o, 64)); lm = fmaxf(lm, __shfl_xor(lm, o, 64)); }
  float ae = __expf(a - am), le = __expf(l - lm);
  float as_ = ae, ls_ = le;
#pragma unroll
  for (int o = 1; o < 64; o <<= 1) { as_ += __shfl_xor(as_, o, 64); ls_ += __shfl_xor(ls_, o, 64); }
  float gs = ae / as_, ls = le / ls_;
  float fu = gt * ls + (1.0f - gt) * gs;
  float fm = fu;
#pragma unroll
  for (int o = 1; o < 64; o <<= 1) fm = fmaxf(fm, __shfl_xor(fm, o, 64));
  float fe = __expf(fu - fm);
  float fs_ = fe;
#pragma unroll
  for (int o = 1; o < 64; o <<= 1) fs_ += __shfl_xor(fs_, o, 64);
  float fv = fe / fs_;
  out[b * 64 + t] = fv;
  out[256 + b * 64 + t] = ls;
  out[512 + b * 64 + t] = gs;
  float tot = fv;
#pragma unroll
  for (int o = 1; o < 64; o <<= 1) tot += __shfl_xor(tot, o, 64);
  if (t == 0) out[768 + b] = tot * (1.0f / 64.0f);
}

// ---------------- launcher ----------------
extern "C" void kernel_launch(void* const* d_in, const int* in_sizes, int n_in,
                              void* d_out, int out_size, void* d_ws, size_t ws_size,
                              hipStream_t stream) {
  const float* question = (const float*)d_in[0];
  const float* context  = (const float*)d_in[1];
  const float* Wq_l = (const float*)d_in[2];
  const float* bq_l = (const float*)d_in[3];
  const float* Wk_l = (const float*)d_in[4];
  const float* bk_l = (const float*)d_in[5];
  const float* Wq_g = (const float*)d_in[6];
  const float* bq_g = (const float*)d_in[7];
  const float* Wk_g = (const float*)d_in[8];
  const float* bk_g = (const float*)d_in[9];
  const float* ln_g = (const float*)d_in[10];
  const float* ln_b = (const float*)d_in[11];
  const float* W1   = (const float*)d_in[12];
  const float* b1   = (const float*)d_in[13];
  const float* W2   = (const float*)d_in[14];
  const float* b2   = (const float*)d_in[15];

  char* ws = (char*)d_ws;
  u16*   ctxb   = (u16*)(ws + 0);            // 67108864 B
  u16*   Ab     = (u16*)(ws + 67108864);     //  8388608 B
  float* qh     = (float*)(ws + 75497472);   //  1048576 B  [2][4][32][1024]
  float* sbias  = (float*)(ws + 76546048);   //    16384 B
  float* mglob  = (float*)(ws + 76562432);   //   524288 B  [4][64][512]
  float* zglob  = (float*)(ws + 77086720);   //   524288 B
  float* locinv = (float*)(ws + 77611008);   //   524288 B
  float* qvec   = (float*)(ws + 78135296);   //    16384 B
  float* cvec   = (float*)(ws + 78151680);   //  1048576 B  [256][1024]
  float* qpart  = (float*)(ws + 79200256);   //    16384 B
  float* h1     = (float*)(ws + 79216640);   //  1048576 B  [256][1024]
  float* Mh     = (float*)(ws + 80265216);   //     8192 B  [4][512]
  float* Zr     = (float*)(ws + 80273408);   //     8192 B
  float* abuf   = (float*)(ws + 80281600);   //     1024 B  [4][64]
  float* lbuf   = (float*)(ws + 80282624);   //     1024 B
  float* gbuf   = (float*)(ws + 80283648);   //     1024 B

  hipMemsetAsync(qh, 0, 1048576, stream);
  hipMemsetAsync(h1, 0, 1048576, stream);
  hipMemsetAsync(qpart, 0, 16384, stream);

  hipLaunchKernelGGL(k_ctx2bf16, dim3(2048), dim3(256), 0, stream, context, ctxb);
  // qh_g / qh_l : question[128x1024] @ Wq[1024x1024]
  hipLaunchKernelGGL(k_gemm_f32, dim3(2, 16, 8), dim3(256), 0, stream, question, HDIM, Wq_g, HDIM, qh, HDIM, 128);
  hipLaunchKernelGGL(k_gemm_f32, dim3(2, 16, 8), dim3(256), 0, stream, question, HDIM, Wq_l, HDIM, qh + 131072, HDIM, 128);
  hipLaunchKernelGGL(k_qh_bias, dim3(1024), dim3(256), 0, stream, qh, bq_g, bq_l);
  hipLaunchKernelGGL(k_afold, dim3(4, 32, 4), dim3(256), 0, stream, qh, Wk_g, Wk_l, Ab);
  hipLaunchKernelGGL(k_sbias, dim3(16), dim3(256), 0, stream, qh, bk_g, bk_l, sbias);
  hipLaunchKernelGGL(k_scores, dim3(2048), dim3(256), 0, stream, ctxb, Ab, sbias, mglob, zglob, locinv);
  hipLaunchKernelGGL(k_qvec, dim3(4), dim3(256), 0, stream, question, ln_g, ln_b, qvec);
  hipLaunchKernelGGL(k_cvec, dim3(256), dim3(256), 0, stream, ctxb, ln_g, ln_b, cvec);
  hipLaunchKernelGGL(k_qpart, dim3(4, 4, 16), dim3(256), 0, stream, qvec, W1, qpart);
  // h1pre += cvec[256x1024] @ W1[1024:2048, :]
  hipLaunchKernelGGL(k_gemm_f32, dim3(4, 16, 8), dim3(256), 0, stream, cvec, HDIM, W1 + 1048576, HDIM, h1, HDIM, 128);
  hipLaunchKernelGGL(k_gelu, dim3(1024), dim3(256), 0, stream, h1, qpart, b1, h1);
  hipLaunchKernelGGL(k_hq, dim3(8), dim3(256), 0, stream, mglob, zglob, Mh, Zr);
  hipLaunchKernelGGL(k_chunk, dim3(256), dim3(256), 0, stream, mglob, zglob, locinv, Mh, Zr, h1, W2, abuf, lbuf, gbuf);
  hipLaunchKernelGGL(k_final, dim3(4), dim3(64), 0, stream, abuf, lbuf, gbuf, b2, (float*)d_out);
}

// Round 5
// 297.168 us; speedup vs baseline: 1.4606x; 1.0447x over previous
//
#include <hip/hip_runtime.h>
#include <math.h>

// ---------------- problem constants (fixed by setup_inputs) ----------------
#define B_    4
#define QN    32
#define KN    8192
#define HDIM  1024
#define NHD   16
#define DH    64
#define LCH   128
#define JCH   64

typedef float f32x4 __attribute__((ext_vector_type(4)));
typedef short s16x8 __attribute__((ext_vector_type(8)));
typedef unsigned short u16;

__device__ __forceinline__ u16 f2bf(float f) {          // round-to-nearest-even f32->bf16
  unsigned u = __float_as_uint(f);
  u += 0x7fffu + ((u >> 16) & 1u);
  return (u16)(u >> 16);
}

__device__ __forceinline__ float bf2f(u16 v) {
  return __uint_as_float(((unsigned)v) << 16);
}

__device__ __forceinline__ void llds16(const void* g, void* l) {   // 16B global->LDS DMA
  __builtin_amdgcn_global_load_lds((const __attribute__((address_space(1))) unsigned int*)g,
                                   (__attribute__((address_space(3))) unsigned int*)l,
                                   16, 0, 0);
}

// ---------------- context fp32 -> bf16 ----------------
__global__ __launch_bounds__(256) void k_ctx2bf16(const float* __restrict__ ctx, u16* __restrict__ out) {
  const int total4 = B_ * KN * HDIM / 4;
  int idx = blockIdx.x * 256 + threadIdx.x;
  for (int i = idx; i < total4; i += gridDim.x * 256) {
    float4 v = ((const float4*)ctx)[i];
    ushort4 o;
    o.x = f2bf(v.x); o.y = f2bf(v.y); o.z = f2bf(v.z); o.w = f2bf(v.w);
    ((ushort4*)out)[i] = o;
  }
}

// ---------------- generic fp32 tiled GEMM, C += A*B over one K-slice (atomic) ----------------
__global__ __launch_bounds__(256) void k_gemm_f32(const float* __restrict__ A, int lda,
                                                  const float* __restrict__ Bm, int ldb,
                                                  float* __restrict__ C, int ldc, int kchunk) {
  __shared__ float As[64][17];
  __shared__ float Bs[16][64];
  int t = threadIdx.x;
  int m0 = blockIdx.x * 64, n0 = blockIdx.y * 64, k0 = blockIdx.z * kchunk;
  int tm = t >> 4, tn = t & 15;
  float c[4][4];
#pragma unroll
  for (int i = 0; i < 4; ++i)
#pragma unroll
    for (int j = 0; j < 4; ++j) c[i][j] = 0.f;
  int ra = t >> 2, ka = (t & 3) * 4;
  int kb = t >> 4, nb = (t & 15) * 4;
  for (int kk = 0; kk < kchunk; kk += 16) {
    float4 va = *(const float4*)(A + (size_t)(m0 + ra) * lda + k0 + kk + ka);
    float4 vb = *(const float4*)(Bm + (size_t)(k0 + kk + kb) * ldb + n0 + nb);
    As[ra][ka] = va.x; As[ra][ka + 1] = va.y; As[ra][ka + 2] = va.z; As[ra][ka + 3] = va.w;
    *(float4*)&Bs[kb][nb] = vb;
    __syncthreads();
#pragma unroll
    for (int kq = 0; kq < 16; ++kq) {
      float a0 = As[tm * 4 + 0][kq], a1 = As[tm * 4 + 1][kq];
      float a2 = As[tm * 4 + 2][kq], a3 = As[tm * 4 + 3][kq];
      float b0 = Bs[kq][tn * 4 + 0], b1 = Bs[kq][tn * 4 + 1];
      float b2 = Bs[kq][tn * 4 + 2], b3 = Bs[kq][tn * 4 + 3];
      c[0][0] += a0 * b0; c[0][1] += a0 * b1; c[0][2] += a0 * b2; c[0][3] += a0 * b3;
      c[1][0] += a1 * b0; c[1][1] += a1 * b1; c[1][2] += a1 * b2; c[1][3] += a1 * b3;
      c[2][0] += a2 * b0; c[2][1] += a2 * b1; c[2][2] += a2 * b2; c[2][3] += a2 * b3;
      c[3][0] += a3 * b0; c[3][1] += a3 * b1; c[3][2] += a3 * b2; c[3][3] += a3 * b3;
    }
    __syncthreads();
  }
#pragma unroll
  for (int i = 0; i < 4; ++i)
#pragma unroll
    for (int j = 0; j < 4; ++j)
      atomicAdd(&C[(size_t)(m0 + tm * 4 + i) * ldc + n0 + tn * 4 + j], c[i][j]);
}

// ---------------- folded score matrix A[b][n][c] (bf16, scale 1/8, bq folded in) ----------------
__global__ __launch_bounds__(256) void k_afold(const float* __restrict__ qh, const float* __restrict__ Wk_g,
                                               const float* __restrict__ Wk_l, const float* __restrict__ bq_g,
                                               const float* __restrict__ bq_l, u16* __restrict__ Ab) {
  int ct = blockIdx.x;          // 0..3  (c tile of 256)
  int slot = blockIdx.y;        // 0..31 (s2*16 + h)
  int b = blockIdx.z;
  int s2 = slot >> 4, h = slot & 15;
  const float* qhp = qh + (size_t)(s2 * 4 + b) * QN * HDIM;
  const float* Wk = s2 ? Wk_l : Wk_g;
  const float* bq = s2 ? bq_l : bq_g;
  __shared__ float qs[QN][DH];
  int t = threadIdx.x;
  {
    int q = t >> 3, doff = (t & 7) * 8;
    const float4* src = (const float4*)(qhp + (size_t)q * HDIM + h * DH + doff);
    float4 b0 = *(const float4*)(bq + h * DH + doff);
    float4 b1 = *(const float4*)(bq + h * DH + doff + 4);
    float4 v0 = src[0], v1 = src[1];
    qs[q][doff + 0] = v0.x + b0.x; qs[q][doff + 1] = v0.y + b0.y;
    qs[q][doff + 2] = v0.z + b0.z; qs[q][doff + 3] = v0.w + b0.w;
    qs[q][doff + 4] = v1.x + b1.x; qs[q][doff + 5] = v1.y + b1.y;
    qs[q][doff + 6] = v1.z + b1.z; qs[q][doff + 7] = v1.w + b1.w;
  }
  __syncthreads();
  int c = ct * 256 + t;
  float w[DH];
  const float* wr = Wk + (size_t)c * HDIM + h * DH;
#pragma unroll
  for (int d = 0; d < DH; d += 4) {
    float4 v = *(const float4*)(wr + d);
    w[d] = v.x; w[d + 1] = v.y; w[d + 2] = v.z; w[d + 3] = v.w;
  }
  u16* outp = Ab + ((size_t)b * HDIM + s2 * 512 + h * QN) * HDIM + c;
  for (int q = 0; q < QN; ++q) {
    float acc = 0.f;
#pragma unroll
    for (int d = 0; d < DH; ++d) acc += qs[q][d] * w[d];
    outp[(size_t)q * HDIM] = f2bf(acc * 0.125f);
  }
}

// ---------------- score bias sbias[b][n] = (1/8) (qh+bq) . bk ----------------
__global__ __launch_bounds__(256) void k_sbias(const float* __restrict__ qh, const float* __restrict__ bk_g,
                                               const float* __restrict__ bk_l, const float* __restrict__ bq_g,
                                               const float* __restrict__ bq_l, float* __restrict__ sbias) {
  int i = blockIdx.x * 256 + threadIdx.x;   // 0..4095
  int b = i >> 10, n = i & (HDIM - 1);
  int s2 = n >> 9, hq = n & 511, h = hq >> 5, q = hq & 31;
  const float* qr = qh + ((size_t)(s2 * 4 + b) * QN + q) * HDIM + h * DH;
  const float* bk = (s2 ? bk_l : bk_g) + h * DH;
  const float* bq = (s2 ? bq_l : bq_g) + h * DH;
  float acc = 0.f;
#pragma unroll
  for (int d = 0; d < DH; ++d) acc += (qr[d] + bq[d]) * bk[d];
  sbias[i] = acc * 0.125f;
}

// ---------------- THE big fused kernel: S = ctx_bf16 @ A^T, column-wise (max,sumexp) per chunk ----
// grid 2048 blocks (XCD-remapped), 256 thr (4 waves 2x2), 128x128 tile, MFMA 16x16x32.
// Compile-time ping-pong dbuf (no runtime LDS base index -> all addresses loop-invariant).
// LDS XOR swizzle both-sides (rule #21): physical slot = logical_slot ^ ((row>>1)&3).
__global__ __launch_bounds__(256) void k_scores(const u16* __restrict__ ctxb, const u16* __restrict__ Ab,
                                                const float* __restrict__ sbias,
                                                float* __restrict__ mglob, float* __restrict__ zglob,
                                                float* __restrict__ locinv) {
  __shared__ u16 lds[16384];     // At0 | Bt0 | At1 | Bt1 (4096 u16 each)
  __shared__ float red[2][128];
  u16* At0 = lds;          u16* Bt0 = lds + 4096;
  u16* At1 = lds + 8192;   u16* Bt1 = lds + 12288;
  // XCD-bijective remap: 2048 blocks, 8 XCDs -> XCD x owns contiguous work [x*256, x*256+256)
  int bid = blockIdx.x;
  int work = (bid & 7) * 256 + (bid >> 3);
  int nt = work & 7, jc = (work >> 3) & 63, b = work >> 9;
  int t = threadIdx.x;
  int wid = t >> 6, lane = t & 63;
  int wr = wid >> 1, wc = wid & 1;
  int lrow = lane & 15, lkg = lane >> 4;

  const u16* ctx0 = ctxb + (size_t)(b * KN + jc * LCH) * HDIM;
  const u16* A0 = Ab + ((size_t)b * HDIM + nt * 128) * HDIM;

  // staging geometry: chunk = seg*64 + lane, row = chunk>>2, slot = chunk&3,
  // global source pre-swizzled so linear LDS write == swizzled layout
  int chunk0 = wid * 64 + lane, chunk1 = chunk0 + 256;
  int row0 = chunk0 >> 2, sg0 = (chunk0 & 3) ^ ((row0 >> 1) & 3);
  int row1 = chunk1 >> 2, sg1 = (chunk1 & 3) ^ ((row1 >> 1) & 3);
  const u16* pa0 = ctx0 + (size_t)row0 * HDIM + sg0 * 8;
  const u16* pa1 = ctx0 + (size_t)row1 * HDIM + sg1 * 8;
  const u16* pb0 = A0 + (size_t)row0 * HDIM + sg0 * 8;
  const u16* pb1 = A0 + (size_t)row1 * HDIM + sg1 * 8;
  int dst0 = wid * 512, dst1 = wid * 512 + 2048;   // u16 index (wave-uniform)

  // ds_read offsets (u16 idx), loop-invariant; (R>>1)&3 == (lrow>>1)&3 (i-independent)
  int swz = (lkg ^ ((lrow >> 1) & 3)) * 8;
  int aoff[4], boff[4];
#pragma unroll
  for (int i = 0; i < 4; ++i) aoff[i] = (wr * 64 + i * 16 + lrow) * 32 + swz;
#pragma unroll
  for (int j = 0; j < 4; ++j) boff[j] = (wc * 64 + j * 16 + lrow) * 32 + swz;

  f32x4 acc[4][4];
#pragma unroll
  for (int i = 0; i < 4; ++i)
#pragma unroll
    for (int j = 0; j < 4; ++j) acc[i][j] = 0.f;

#define STAGE(AT, BT, KOFF) \
  { llds16(pa0 + (KOFF), AT + dst0); llds16(pa1 + (KOFF), AT + dst1); \
    llds16(pb0 + (KOFF), BT + dst0); llds16(pb1 + (KOFF), BT + dst1); }

#define COMPUTE(AT, BT) \
  { s16x8 af[4], bf[4]; \
    _Pragma("unroll") for (int i = 0; i < 4; ++i) af[i] = *(const s16x8*)((AT) + aoff[i]); \
    _Pragma("unroll") for (int j = 0; j < 4; ++j) bf[j] = *(const s16x8*)((BT) + boff[j]); \
    _Pragma("unroll") for (int i = 0; i < 4; ++i) \
    _Pragma("unroll") for (int j = 0; j < 4; ++j) \
      acc[i][j] = __builtin_amdgcn_mfma_f32_16x16x32_bf16(af[i], bf[j], acc[i][j], 0, 0, 0); }

  STAGE(At0, Bt0, 0);
  __syncthreads();
#pragma unroll
  for (int kt = 0; kt < 32; kt += 2) {
    STAGE(At1, Bt1, (kt + 1) * 32);     // prefetch kt+1 while computing kt
    COMPUTE(At0, Bt0);
    __syncthreads();
    if (kt + 2 < 32) STAGE(At0, Bt0, (kt + 2) * 32);
    COMPUTE(At1, Bt1);
    __syncthreads();
  }
#undef STAGE
#undef COMPUTE

  // ---- epilogue: per output column (over 128 chunk rows): max, sumexp ----
  // D mapping (m89-verified): col = lane&15, row = (lane>>4)*4 + reg
  float sb[4], mv[4], Mc[4], zv[4];
#pragma unroll
  for (int fj = 0; fj < 4; ++fj)
    sb[fj] = sbias[b * HDIM + nt * 128 + wc * 64 + fj * 16 + lrow];
#pragma unroll
  for (int fj = 0; fj < 4; ++fj) {
    float m = -1e30f;
#pragma unroll
    for (int fi = 0; fi < 4; ++fi)
#pragma unroll
      for (int r = 0; r < 4; ++r) m = fmaxf(m, acc[fi][fj][r]);
    m += sb[fj];
    m = fmaxf(m, __shfl_xor(m, 16, 64));
    m = fmaxf(m, __shfl_xor(m, 32, 64));
    mv[fj] = m;
  }
  if (lane < 16) {
#pragma unroll
    for (int fj = 0; fj < 4; ++fj) red[wr][wc * 64 + fj * 16 + lane] = mv[fj];
  }
  __syncthreads();
#pragma unroll
  for (int fj = 0; fj < 4; ++fj) {
    int col = wc * 64 + fj * 16 + lrow;
    Mc[fj] = fmaxf(red[0][col], red[1][col]);
  }
  __syncthreads();
#pragma unroll
  for (int fj = 0; fj < 4; ++fj) {
    float s = 0.f;
#pragma unroll
    for (int fi = 0; fi < 4; ++fi)
#pragma unroll
      for (int r = 0; r < 4; ++r) s += __expf(acc[fi][fj][r] + sb[fj] - Mc[fj]);
    s += __shfl_xor(s, 16, 64);
    s += __shfl_xor(s, 32, 64);
    zv[fj] = s;
  }
  if (lane < 16) {
#pragma unroll
    for (int fj = 0; fj < 4; ++fj) red[wr][wc * 64 + fj * 16 + lane] = zv[fj];
  }
  __syncthreads();
  if (wr == 0 && lane < 16) {
    size_t base = (size_t)(b * JCH + jc) * 512;
#pragma unroll
    for (int fj = 0; fj < 4; ++fj) {
      int col = wc * 64 + fj * 16 + lane;
      float Z = red[0][col] + red[1][col];
      int n = nt * 128 + col;
      if (n < 512) { mglob[base + n] = Mc[fj]; zglob[base + n] = Z; }
      else         { locinv[base + n - 512] = 1.0f / Z; }
    }
  }
}

// ---------------- LN(mean over Q) of question -> qvec[b][1024] ----------------
__global__ __launch_bounds__(256) void k_qvec(const float* __restrict__ q, const float* __restrict__ g,
                                              const float* __restrict__ lb, float* __restrict__ qvec) {
  int b = blockIdx.x, t = threadIdx.x;
  const float* p = q + (size_t)b * QN * HDIM + t * 4;
  float a0 = 0, a1 = 0, a2 = 0, a3 = 0;
  for (int r = 0; r < QN; ++r) {
    float4 v = *(const float4*)(p + (size_t)r * HDIM);
    a0 += v.x; a1 += v.y; a2 += v.z; a3 += v.w;
  }
  const float sc = 1.0f / QN;
  a0 *= sc; a1 *= sc; a2 *= sc; a3 *= sc;
  float s = a0 + a1 + a2 + a3;
  float ss = a0 * a0 + a1 * a1 + a2 * a2 + a3 * a3;
#pragma unroll
  for (int o = 1; o < 64; o <<= 1) { s += __shfl_xor(s, o, 64); ss += __shfl_xor(ss, o, 64); }
  __shared__ float sm[4], sq[4];
  int wid = t >> 6, lane = t & 63;
  if (lane == 0) { sm[wid] = s; sq[wid] = ss; }
  __syncthreads();
  float S = sm[0] + sm[1] + sm[2] + sm[3], SS = sq[0] + sq[1] + sq[2] + sq[3];
  float mu = S / HDIM;
  float inv = rsqrtf(SS / HDIM - mu * mu + 1e-5f);
  int c = t * 4;
  float4 o;
  o.x = (a0 - mu) * inv * g[c + 0] + lb[c + 0];
  o.y = (a1 - mu) * inv * g[c + 1] + lb[c + 1];
  o.z = (a2 - mu) * inv * g[c + 2] + lb[c + 2];
  o.w = (a3 - mu) * inv * g[c + 3] + lb[c + 3];
  *(float4*)&qvec[(size_t)b * HDIM + c] = o;
}

// ---------------- LN(mean over L) of context chunks (bf16 src) -> cvec[b*64+j][1024] ----------------
__global__ __launch_bounds__(256) void k_cvec(const u16* __restrict__ ctxb, const float* __restrict__ g,
                                              const float* __restrict__ lb, float* __restrict__ cvec) {
  int bj = blockIdx.x, t = threadIdx.x;
  int b = bj >> 6, jc = bj & 63;
  const u16* p = ctxb + ((size_t)b * KN + jc * LCH) * HDIM + t * 4;
  float a0 = 0, a1 = 0, a2 = 0, a3 = 0;
  for (int r = 0; r < LCH; ++r) {
    ushort4 v = *(const ushort4*)(p + (size_t)r * HDIM);
    a0 += bf2f(v.x); a1 += bf2f(v.y); a2 += bf2f(v.z); a3 += bf2f(v.w);
  }
  const float sc = 1.0f / LCH;
  a0 *= sc; a1 *= sc; a2 *= sc; a3 *= sc;
  float s = a0 + a1 + a2 + a3;
  float ss = a0 * a0 + a1 * a1 + a2 * a2 + a3 * a3;
#pragma unroll
  for (int o = 1; o < 64; o <<= 1) { s += __shfl_xor(s, o, 64); ss += __shfl_xor(ss, o, 64); }
  __shared__ float sm[4], sq[4];
  int wid = t >> 6, lane = t & 63;
  if (lane == 0) { sm[wid] = s; sq[wid] = ss; }
  __syncthreads();
  float S = sm[0] + sm[1] + sm[2] + sm[3], SS = sq[0] + sq[1] + sq[2] + sq[3];
  float mu = S / HDIM;
  float inv = rsqrtf(SS / HDIM - mu * mu + 1e-5f);
  int c = t * 4;
  float4 o;
  o.x = (a0 - mu) * inv * g[c + 0] + lb[c + 0];
  o.y = (a1 - mu) * inv * g[c + 1] + lb[c + 1];
  o.z = (a2 - mu) * inv * g[c + 2] + lb[c + 2];
  o.w = (a3 - mu) * inv * g[c + 3] + lb[c + 3];
  *(float4*)&cvec[(size_t)bj * HDIM + c] = o;
}

// ---------------- qpart[b][n] += qvec[b][c-slice] . W1[c-slice, n]  (split-K, 256 blocks) ------
__global__ __launch_bounds__(256) void k_qpart(const float* __restrict__ qvec, const float* __restrict__ W1,
                                               float* __restrict__ qpart) {
  int nt = blockIdx.x, b = blockIdx.y, ks = blockIdx.z;
  int n = nt * 256 + threadIdx.x;
  const float* qv = qvec + (size_t)b * HDIM + ks * 64;
  const float* wp = W1 + (size_t)ks * 64 * HDIM + n;
  float acc = 0.f;
#pragma unroll 8
  for (int c = 0; c < 64; ++c) acc += qv[c] * wp[(size_t)c * HDIM];
  atomicAdd(&qpart[(size_t)b * HDIM + n], acc);
}

// ---------------- per-(b,hq) global max/denominator over chunks ----------------
__global__ __launch_bounds__(64) void k_hq(const float* __restrict__ mglob, const float* __restrict__ zglob,
                                           float* __restrict__ Mh, float* __restrict__ Zr) {
  int id = blockIdx.x * 64 + threadIdx.x;   // grid 32 -> 0..2047
  int b = id >> 9, hq = id & 511;
  const float* mg = mglob + (size_t)b * JCH * 512 + hq;
  const float* zg = zglob + (size_t)b * JCH * 512 + hq;
  float m = -1e30f;
  for (int j = 0; j < JCH; ++j) m = fmaxf(m, mg[(size_t)j * 512]);
  float z = 0.f;
  for (int j = 0; j < JCH; ++j) z += zg[(size_t)j * 512] * __expf(mg[(size_t)j * 512] - m);
  Mh[id] = m;
  Zr[id] = 1.0f / z;
}

// ---------------- per-(b,j) pooled scalars: att, loc, gate-dot (gelu fused) ----------------
__global__ __launch_bounds__(256) void k_chunk(const float* __restrict__ mglob, const float* __restrict__ zglob,
                                               const float* __restrict__ locinv,
                                               const float* __restrict__ Mh, const float* __restrict__ Zr,
                                               const float* __restrict__ h1, const float* __restrict__ qpart,
                                               const float* __restrict__ b1, const float* __restrict__ W2,
                                               float* __restrict__ abuf, float* __restrict__ lbuf,
                                               float* __restrict__ gbuf) {
  int bj = blockIdx.x, t = threadIdx.x;
  int b = bj >> 6;
  const float* mg = mglob + (size_t)bj * 512;
  const float* zg = zglob + (size_t)bj * 512;
  const float* lp = locinv + (size_t)bj * 512;
  const float* Mb = Mh + (size_t)b * 512;
  const float* Zb = Zr + (size_t)b * 512;
  float a = 0.f, l = 0.f, gsum = 0.f;
  for (int hq = t; hq < 512; hq += 256) {
    a += zg[hq] * __expf(mg[hq] - Mb[hq]) * Zb[hq];
    l += lp[hq];
  }
  const float* hp = h1 + (size_t)bj * HDIM;
  const float* qp = qpart + (size_t)b * HDIM;
  for (int n = t; n < HDIM; n += 256) {
    float x = hp[n] + qp[n] + b1[n];
    x = x * 0.5f * (1.0f + erff(x * 0.70710678118654752f));
    gsum += x * W2[n];
  }
#pragma unroll
  for (int o = 1; o < 64; o <<= 1) {
    a += __shfl_xor(a, o, 64); l += __shfl_xor(l, o, 64); gsum += __shfl_xor(gsum, o, 64);
  }
  __shared__ float ra[4], rl[4], rg[4];
  int wid = t >> 6, lane = t & 63;
  if (lane == 0) { ra[wid] = a; rl[wid] = l; rg[wid] = gsum; }
  __syncthreads();
  if (t == 0) {
    abuf[bj] = (ra[0] + ra[1] + ra[2] + ra[3]) * (1.0f / 65536.0f);
    lbuf[bj] = (rl[0] + rl[1] + rl[2] + rl[3]) * (1.0f / 512.0f);
    gbuf[bj] = rg[0] + rg[1] + rg[2] + rg[3];
  }
}

// ---------------- final: softmaxes over J, fuse, outputs ----------------
__global__ __launch_bounds__(64) void k_final(const float* __restrict__ abuf, const float* __restrict__ lbuf,
                                              const float* __restrict__ gbuf, const float* __restrict__ b2,
                                              float* __restrict__ out) {
  int b = blockIdx.x, t = threadIdx.x;   // 64 threads
  float a = abuf[b * 64 + t];
  float l = lbuf[b * 64 + t];
  float gt = gbuf[b * 64 + t] + b2[0];
  gt = 1.0f / (1.0f + __expf(-gt));
  float am = a, lm = l;
#pragma unroll
  for (int o = 1; o < 64; o <<= 1) { am = fmaxf(am, __shfl_xor(am, o, 64)); lm = fmaxf(lm, __shfl_xor(lm, o, 64)); }
  float ae = __expf(a - am), le = __expf(l - lm);
  float as_ = ae, ls_ = le;
#pragma unroll
  for (int o = 1; o < 64; o <<= 1) { as_ += __shfl_xor(as_, o, 64); ls_ += __shfl_xor(ls_, o, 64); }
  float gs = ae / as_, ls = le / ls_;
  float fu = gt * ls + (1.0f - gt) * gs;
  float fm = fu;
#pragma unroll
  for (int o = 1; o < 64; o <<= 1) fm = fmaxf(fm, __shfl_xor(fm, o, 64));
  float fe = __expf(fu - fm);
  float fs_ = fe;
#pragma unroll
  for (int o = 1; o < 64; o <<= 1) fs_ += __shfl_xor(fs_, o, 64);
  float fv = fe / fs_;
  out[b * 64 + t] = fv;
  out[256 + b * 64 + t] = ls;
  out[512 + b * 64 + t] = gs;
  float tot = fv;
#pragma unroll
  for (int o = 1; o < 64; o <<= 1) tot += __shfl_xor(tot, o, 64);
  if (t == 0) out[768 + b] = tot * (1.0f / 64.0f);
}

// ---------------- launcher ----------------
extern "C" void kernel_launch(void* const* d_in, const int* in_sizes, int n_in,
                              void* d_out, int out_size, void* d_ws, size_t ws_size,
                              hipStream_t stream) {
  const float* question = (const float*)d_in[0];
  const float* context  = (const float*)d_in[1];
  const float* Wq_l = (const float*)d_in[2];
  const float* bq_l = (const float*)d_in[3];
  const float* Wk_l = (const float*)d_in[4];
  const float* bk_l = (const float*)d_in[5];
  const float* Wq_g = (const float*)d_in[6];
  const float* bq_g = (const float*)d_in[7];
  const float* Wk_g = (const float*)d_in[8];
  const float* bk_g = (const float*)d_in[9];
  const float* ln_g = (const float*)d_in[10];
  const float* ln_b = (const float*)d_in[11];
  const float* W1   = (const float*)d_in[12];
  const float* b1   = (const float*)d_in[13];
  const float* W2   = (const float*)d_in[14];
  const float* b2   = (const float*)d_in[15];

  char* ws = (char*)d_ws;
  u16*   ctxb   = (u16*)(ws + 0);            // 67108864 B
  u16*   Ab     = (u16*)(ws + 67108864);     //  8388608 B
  float* qh     = (float*)(ws + 75497472);   //  1048576 B  [2][4][32][1024]
  float* sbias  = (float*)(ws + 76546048);   //    16384 B
  float* mglob  = (float*)(ws + 76562432);   //   524288 B  [4][64][512]
  float* zglob  = (float*)(ws + 77086720);   //   524288 B
  float* locinv = (float*)(ws + 77611008);   //   524288 B
  float* qvec   = (float*)(ws + 78135296);   //    16384 B
  float* cvec   = (float*)(ws + 78151680);   //  1048576 B  [256][1024]
  float* qpart  = (float*)(ws + 79200256);   //    16384 B
  float* h1     = (float*)(ws + 79216640);   //  1048576 B  [256][1024]
  float* Mh     = (float*)(ws + 80265216);   //     8192 B  [4][512]
  float* Zr     = (float*)(ws + 80273408);   //     8192 B
  float* abuf   = (float*)(ws + 80281600);   //     1024 B  [4][64]
  float* lbuf   = (float*)(ws + 80282624);   //     1024 B
  float* gbuf   = (float*)(ws + 80283648);   //     1024 B

  hipMemsetAsync(qh, 0, 1048576, stream);
  hipMemsetAsync(h1, 0, 1048576, stream);
  hipMemsetAsync(qpart, 0, 16384, stream);

  hipLaunchKernelGGL(k_ctx2bf16, dim3(2048), dim3(256), 0, stream, context, ctxb);
  // qh_g / qh_l : question[128x1024] @ Wq[1024x1024]  (bias folded downstream)
  hipLaunchKernelGGL(k_gemm_f32, dim3(2, 16, 8), dim3(256), 0, stream, question, HDIM, Wq_g, HDIM, qh, HDIM, 128);
  hipLaunchKernelGGL(k_gemm_f32, dim3(2, 16, 8), dim3(256), 0, stream, question, HDIM, Wq_l, HDIM, qh + 131072, HDIM, 128);
  hipLaunchKernelGGL(k_afold, dim3(4, 32, 4), dim3(256), 0, stream, qh, Wk_g, Wk_l, bq_g, bq_l, Ab);
  hipLaunchKernelGGL(k_sbias, dim3(16), dim3(256), 0, stream, qh, bk_g, bk_l, bq_g, bq_l, sbias);
  hipLaunchKernelGGL(k_scores, dim3(2048), dim3(256), 0, stream, ctxb, Ab, sbias, mglob, zglob, locinv);
  hipLaunchKernelGGL(k_qvec, dim3(4), dim3(256), 0, stream, question, ln_g, ln_b, qvec);
  hipLaunchKernelGGL(k_cvec, dim3(256), dim3(256), 0, stream, ctxb, ln_g, ln_b, cvec);
  hipLaunchKernelGGL(k_qpart, dim3(4, 4, 16), dim3(256), 0, stream, qvec, W1, qpart);
  // h1pre += cvec[256x1024] @ W1[1024:2048, :]
  hipLaunchKernelGGL(k_gemm_f32, dim3(4, 16, 8), dim3(256), 0, stream, cvec, HDIM, W1 + 1048576, HDIM, h1, HDIM, 128);
  hipLaunchKernelGGL(k_hq, dim3(32), dim3(64), 0, stream, mglob, zglob, Mh, Zr);
  hipLaunchKernelGGL(k_chunk, dim3(256), dim3(256), 0, stream, mglob, zglob, locinv, Mh, Zr, h1, qpart, b1, W2, abuf, lbuf, gbuf);
  hipLaunchKernelGGL(k_final, dim3(4), dim3(64), 0, stream, abuf, lbuf, gbuf, b2, (float*)d_out);
}

// Round 6
// 249.164 us; speedup vs baseline: 1.7420x; 1.1927x over previous
//
#include <hip/hip_runtime.h>
#include <math.h>

// ---------------- problem constants (fixed by setup_inputs) ----------------
#define B_    4
#define QN    32
#define KN    8192
#define HDIM  1024
#define NHD   16
#define DH    64
#define LCH   128
#define JCH   64

typedef float f32x4 __attribute__((ext_vector_type(4)));
typedef short s16x8 __attribute__((ext_vector_type(8)));
typedef unsigned short u16;

__device__ __forceinline__ u16 f2bf(float f) {          // round-to-nearest-even f32->bf16
  unsigned u = __float_as_uint(f);
  u += 0x7fffu + ((u >> 16) & 1u);
  return (u16)(u >> 16);
}

__device__ __forceinline__ float bf2f(u16 v) {
  return __uint_as_float(((unsigned)v) << 16);
}

__device__ __forceinline__ void llds16(const void* g, void* l) {   // 16B global->LDS DMA
  __builtin_amdgcn_global_load_lds((const __attribute__((address_space(1))) unsigned int*)g,
                                   (__attribute__((address_space(3))) unsigned int*)l,
                                   16, 0, 0);
}

// ---------------- context fp32 -> bf16 ----------------
__global__ __launch_bounds__(256) void k_ctx2bf16(const float* __restrict__ ctx, u16* __restrict__ out) {
  const int total4 = B_ * KN * HDIM / 4;
  int idx = blockIdx.x * 256 + threadIdx.x;
  for (int i = idx; i < total4; i += gridDim.x * 256) {
    float4 v = ((const float4*)ctx)[i];
    ushort4 o;
    o.x = f2bf(v.x); o.y = f2bf(v.y); o.z = f2bf(v.z); o.w = f2bf(v.w);
    ((ushort4*)out)[i] = o;
  }
}

// ---------------- generic fp32 tiled GEMM, C += A*B over one K-slice (atomic) ----------------
__global__ __launch_bounds__(256) void k_gemm_f32(const float* __restrict__ A, int lda,
                                                  const float* __restrict__ Bm, int ldb,
                                                  float* __restrict__ C, int ldc, int kchunk) {
  __shared__ float As[64][17];
  __shared__ float Bs[16][64];
  int t = threadIdx.x;
  int m0 = blockIdx.x * 64, n0 = blockIdx.y * 64, k0 = blockIdx.z * kchunk;
  int tm = t >> 4, tn = t & 15;
  float c[4][4];
#pragma unroll
  for (int i = 0; i < 4; ++i)
#pragma unroll
    for (int j = 0; j < 4; ++j) c[i][j] = 0.f;
  int ra = t >> 2, ka = (t & 3) * 4;
  int kb = t >> 4, nb = (t & 15) * 4;
  for (int kk = 0; kk < kchunk; kk += 16) {
    float4 va = *(const float4*)(A + (size_t)(m0 + ra) * lda + k0 + kk + ka);
    float4 vb = *(const float4*)(Bm + (size_t)(k0 + kk + kb) * ldb + n0 + nb);
    As[ra][ka] = va.x; As[ra][ka + 1] = va.y; As[ra][ka + 2] = va.z; As[ra][ka + 3] = va.w;
    *(float4*)&Bs[kb][nb] = vb;
    __syncthreads();
#pragma unroll
    for (int kq = 0; kq < 16; ++kq) {
      float a0 = As[tm * 4 + 0][kq], a1 = As[tm * 4 + 1][kq];
      float a2 = As[tm * 4 + 2][kq], a3 = As[tm * 4 + 3][kq];
      float b0 = Bs[kq][tn * 4 + 0], b1 = Bs[kq][tn * 4 + 1];
      float b2 = Bs[kq][tn * 4 + 2], b3 = Bs[kq][tn * 4 + 3];
      c[0][0] += a0 * b0; c[0][1] += a0 * b1; c[0][2] += a0 * b2; c[0][3] += a0 * b3;
      c[1][0] += a1 * b0; c[1][1] += a1 * b1; c[1][2] += a1 * b2; c[1][3] += a1 * b3;
      c[2][0] += a2 * b0; c[2][1] += a2 * b1; c[2][2] += a2 * b2; c[2][3] += a2 * b3;
      c[3][0] += a3 * b0; c[3][1] += a3 * b1; c[3][2] += a3 * b2; c[3][3] += a3 * b3;
    }
    __syncthreads();
  }
#pragma unroll
  for (int i = 0; i < 4; ++i)
#pragma unroll
    for (int j = 0; j < 4; ++j)
      atomicAdd(&C[(size_t)(m0 + tm * 4 + i) * ldc + n0 + tn * 4 + j], c[i][j]);
}

// ---------------- merged qh GEMM: both Wq_g and Wq_l in one launch ----------------
// grid (2, 32, 8): y<16 -> global scorer, y>=16 -> local scorer
__global__ __launch_bounds__(256) void k_gemm_qh(const float* __restrict__ A,
                                                 const float* __restrict__ Bg, const float* __restrict__ Bl,
                                                 float* __restrict__ C) {
  __shared__ float As[64][17];
  __shared__ float Bs[16][64];
  int t = threadIdx.x;
  int ny = blockIdx.y;
  const float* Bm = (ny < 16) ? Bg : Bl;
  float* Cp = (ny < 16) ? C : (C + 131072);
  int m0 = blockIdx.x * 64, n0 = (ny & 15) * 64, k0 = blockIdx.z * 128;
  int tm = t >> 4, tn = t & 15;
  float c[4][4];
#pragma unroll
  for (int i = 0; i < 4; ++i)
#pragma unroll
    for (int j = 0; j < 4; ++j) c[i][j] = 0.f;
  int ra = t >> 2, ka = (t & 3) * 4;
  int kb = t >> 4, nb = (t & 15) * 4;
  for (int kk = 0; kk < 128; kk += 16) {
    float4 va = *(const float4*)(A + (size_t)(m0 + ra) * HDIM + k0 + kk + ka);
    float4 vb = *(const float4*)(Bm + (size_t)(k0 + kk + kb) * HDIM + n0 + nb);
    As[ra][ka] = va.x; As[ra][ka + 1] = va.y; As[ra][ka + 2] = va.z; As[ra][ka + 3] = va.w;
    *(float4*)&Bs[kb][nb] = vb;
    __syncthreads();
#pragma unroll
    for (int kq = 0; kq < 16; ++kq) {
      float a0 = As[tm * 4 + 0][kq], a1 = As[tm * 4 + 1][kq];
      float a2 = As[tm * 4 + 2][kq], a3 = As[tm * 4 + 3][kq];
      float b0 = Bs[kq][tn * 4 + 0], b1 = Bs[kq][tn * 4 + 1];
      float b2 = Bs[kq][tn * 4 + 2], b3 = Bs[kq][tn * 4 + 3];
      c[0][0] += a0 * b0; c[0][1] += a0 * b1; c[0][2] += a0 * b2; c[0][3] += a0 * b3;
      c[1][0] += a1 * b0; c[1][1] += a1 * b1; c[1][2] += a1 * b2; c[1][3] += a1 * b3;
      c[2][0] += a2 * b0; c[2][1] += a2 * b1; c[2][2] += a2 * b2; c[2][3] += a2 * b3;
      c[3][0] += a3 * b0; c[3][1] += a3 * b1; c[3][2] += a3 * b2; c[3][3] += a3 * b3;
    }
    __syncthreads();
  }
#pragma unroll
  for (int i = 0; i < 4; ++i)
#pragma unroll
    for (int j = 0; j < 4; ++j)
      atomicAdd(&Cp[(size_t)(m0 + tm * 4 + i) * HDIM + n0 + tn * 4 + j], c[i][j]);
}

// ---------------- folded score matrix A[b][n][c] (bf16, scale 1/8, bq folded in) ----------------
__global__ __launch_bounds__(256) void k_afold(const float* __restrict__ qh, const float* __restrict__ Wk_g,
                                               const float* __restrict__ Wk_l, const float* __restrict__ bq_g,
                                               const float* __restrict__ bq_l, u16* __restrict__ Ab) {
  int ct = blockIdx.x;          // 0..3  (c tile of 256)
  int slot = blockIdx.y;        // 0..31 (s2*16 + h)
  int b = blockIdx.z;
  int s2 = slot >> 4, h = slot & 15;
  const float* qhp = qh + (size_t)(s2 * 4 + b) * QN * HDIM;
  const float* Wk = s2 ? Wk_l : Wk_g;
  const float* bq = s2 ? bq_l : bq_g;
  __shared__ float qs[QN][DH];
  int t = threadIdx.x;
  {
    int q = t >> 3, doff = (t & 7) * 8;
    const float4* src = (const float4*)(qhp + (size_t)q * HDIM + h * DH + doff);
    float4 b0 = *(const float4*)(bq + h * DH + doff);
    float4 b1 = *(const float4*)(bq + h * DH + doff + 4);
    float4 v0 = src[0], v1 = src[1];
    qs[q][doff + 0] = v0.x + b0.x; qs[q][doff + 1] = v0.y + b0.y;
    qs[q][doff + 2] = v0.z + b0.z; qs[q][doff + 3] = v0.w + b0.w;
    qs[q][doff + 4] = v1.x + b1.x; qs[q][doff + 5] = v1.y + b1.y;
    qs[q][doff + 6] = v1.z + b1.z; qs[q][doff + 7] = v1.w + b1.w;
  }
  __syncthreads();
  int c = ct * 256 + t;
  float w[DH];
  const float* wr = Wk + (size_t)c * HDIM + h * DH;
#pragma unroll
  for (int d = 0; d < DH; d += 4) {
    float4 v = *(const float4*)(wr + d);
    w[d] = v.x; w[d + 1] = v.y; w[d + 2] = v.z; w[d + 3] = v.w;
  }
  u16* outp = Ab + ((size_t)b * HDIM + s2 * 512 + h * QN) * HDIM + c;
  for (int q = 0; q < QN; ++q) {
    float acc = 0.f;
#pragma unroll
    for (int d = 0; d < DH; ++d) acc += qs[q][d] * w[d];
    outp[(size_t)q * HDIM] = f2bf(acc * 0.125f);
  }
}

// ---------------- score bias sbias[b][n] = (1/8) (qh+bq) . bk ----------------
__global__ __launch_bounds__(256) void k_sbias(const float* __restrict__ qh, const float* __restrict__ bk_g,
                                               const float* __restrict__ bk_l, const float* __restrict__ bq_g,
                                               const float* __restrict__ bq_l, float* __restrict__ sbias) {
  int i = blockIdx.x * 256 + threadIdx.x;   // 0..4095
  int b = i >> 10, n = i & (HDIM - 1);
  int s2 = n >> 9, hq = n & 511, h = hq >> 5, q = hq & 31;
  const float* qr = qh + ((size_t)(s2 * 4 + b) * QN + q) * HDIM + h * DH;
  const float* bk = (s2 ? bk_l : bk_g) + h * DH;
  const float* bq = (s2 ? bq_l : bq_g) + h * DH;
  float acc = 0.f;
#pragma unroll
  for (int d = 0; d < DH; ++d) acc += (qr[d] + bq[d]) * bk[d];
  sbias[i] = acc * 0.125f;
}

// ---------------- THE big fused kernel: S = ctx_bf16 @ A^T, column-wise (max,sumexp) per chunk ----
// 256x256 tile, BK=64, 8 waves (2M x 4N), 512 thr, dbuf 128KB, counted vmcnt(8) pipeline.
// Per wave: 128 rows (= one full chunk) x 64 cols -> epilogue is shuffle-only (no LDS reduce).
// LDS XOR swizzle both-sides (rule #21): phys slot = logical ^ (row&7); global src pre-swizzled
// with gslot = (l&7)^(l>>3) so linear DMA writes == swizzled layout. ds_read 2-way (free).
// mglob/zglob written TRANSPOSED: [b][n(512)][jc(64)] for contiguous k_hq reads.
__global__ __launch_bounds__(512, 2) void k_scores(const u16* __restrict__ ctxb, const u16* __restrict__ Ab,
                                                   const float* __restrict__ sbias,
                                                   float* __restrict__ mglob, float* __restrict__ zglob,
                                                   float* __restrict__ locinv) {
  __shared__ u16 lds[65536];      // A0 | B0 | A1 | B1, 16384 u16 (32KB) each
  u16* A0 = lds;           u16* B0 = lds + 16384;
  u16* A1 = lds + 32768;   u16* B1 = lds + 49152;
  // XCD-bijective remap: 512 blocks, XCD x owns works [x*64, x*64+64)
  int bid = blockIdx.x;
  int work = (bid & 7) * 64 + (bid >> 3);
  int b = work >> 7, rem = work & 127, rt = rem >> 2, nt = rem & 3;
  int t = threadIdx.x, wid = t >> 6, lane = t & 63;
  int wm = wid >> 2, wn = wid & 3;
  int lrow = lane & 15, lkg = lane >> 4;

  const u16* ctx0 = ctxb + ((size_t)b * KN + rt * 256) * HDIM;
  const u16* Afp  = Ab + ((size_t)b * HDIM + nt * 256) * HDIM;

  // ---- staging geometry (per llds16: 8 waves x 8 rows = 64 rows; 4 insts per matrix) ----
  int grow = wid * 8 + (lane >> 3);          // row within a 64-row group
  int gslot = (lane & 7) ^ (lane >> 3);      // pre-swizzled global 16B-slot
  const u16* gA[4]; const u16* gB[4]; int dof[4];
#pragma unroll
  for (int s = 0; s < 4; ++s) {
    gA[s] = ctx0 + (size_t)(s * 64 + grow) * HDIM + gslot * 8;
    gB[s] = Afp + (size_t)(s * 64 + grow) * HDIM + gslot * 8;
    dof[s] = s * 4096 + wid * 512;           // u16 idx, wave-uniform LDS dest
  }

  // ---- ds_read offsets (loop-invariant) ----
  int rowA = (wm * 128 + lrow) * 64;
  int rowB = (wn * 64 + lrow) * 64;
  int p8[2];
#pragma unroll
  for (int ks = 0; ks < 2; ++ks) p8[ks] = ((ks * 4 + lkg) ^ (lane & 7)) * 8;

  f32x4 acc[8][4];
#pragma unroll
  for (int mi = 0; mi < 8; ++mi)
#pragma unroll
    for (int ni = 0; ni < 4; ++ni) acc[mi][ni] = 0.f;

#define STAGE(AT, BT, KT) { \
  _Pragma("unroll") for (int s = 0; s < 4; ++s) { \
    llds16(gA[s] + (KT) * 64, (AT) + dof[s]); \
    llds16(gB[s] + (KT) * 64, (BT) + dof[s]); } }

#define COMPUTE(AT, BT) { \
  _Pragma("unroll") for (int ks = 0; ks < 2; ++ks) { \
    const u16* pA = (AT) + rowA + p8[ks]; \
    const u16* pB = (BT) + rowB + p8[ks]; \
    s16x8 av[8], bv[4]; \
    _Pragma("unroll") for (int mi = 0; mi < 8; ++mi) av[mi] = *(const s16x8*)(pA + mi * 1024); \
    _Pragma("unroll") for (int ni = 0; ni < 4; ++ni) bv[ni] = *(const s16x8*)(pB + ni * 1024); \
    _Pragma("unroll") for (int mi = 0; mi < 8; ++mi) \
    _Pragma("unroll") for (int ni = 0; ni < 4; ++ni) \
      acc[mi][ni] = __builtin_amdgcn_mfma_f32_16x16x32_bf16(av[mi], bv[ni], acc[mi][ni], 0, 0, 0); } }

#define SYNCN(N) { asm volatile("s_waitcnt vmcnt(" #N ")" ::: "memory"); \
                   __builtin_amdgcn_s_barrier(); \
                   __builtin_amdgcn_sched_barrier(0); }

#define SUB(KT, CA, CB, SA, SB, FULL) { \
  if (FULL) { STAGE(SA, SB, (KT) + 1); } \
  if (FULL) { SYNCN(8) } else { SYNCN(0) } \
  __builtin_amdgcn_s_setprio(1); \
  COMPUTE(CA, CB); \
  __builtin_amdgcn_s_setprio(0); \
  __builtin_amdgcn_s_barrier(); }

  STAGE(A0, B0, 0);
  SUB(0,  A0, B0, A1, B1, 1)
  SUB(1,  A1, B1, A0, B0, 1)
  SUB(2,  A0, B0, A1, B1, 1)
  SUB(3,  A1, B1, A0, B0, 1)
  SUB(4,  A0, B0, A1, B1, 1)
  SUB(5,  A1, B1, A0, B0, 1)
  SUB(6,  A0, B0, A1, B1, 1)
  SUB(7,  A1, B1, A0, B0, 1)
  SUB(8,  A0, B0, A1, B1, 1)
  SUB(9,  A1, B1, A0, B0, 1)
  SUB(10, A0, B0, A1, B1, 1)
  SUB(11, A1, B1, A0, B0, 1)
  SUB(12, A0, B0, A1, B1, 1)
  SUB(13, A1, B1, A0, B0, 1)
  SUB(14, A0, B0, A1, B1, 1)
  SUB(15, A1, B1, A0, B0, 0)
#undef STAGE
#undef COMPUTE
#undef SYNCN
#undef SUB

  // ---- epilogue: per column, (max, sumexp) over this wave's 128 rows (= one chunk) ----
  // D mapping (m89-verified): col = lane&15, row = mi*16 + (lane>>4)*4 + reg
  int jc = rt * 2 + wm;
  float sb[4];
#pragma unroll
  for (int ni = 0; ni < 4; ++ni)
    sb[ni] = sbias[b * HDIM + nt * 256 + wn * 64 + ni * 16 + lrow];
#pragma unroll
  for (int ni = 0; ni < 4; ++ni) {
    float m = -1e30f;
#pragma unroll
    for (int mi = 0; mi < 8; ++mi)
#pragma unroll
      for (int r = 0; r < 4; ++r) m = fmaxf(m, acc[mi][ni][r]);
    m += sb[ni];
    m = fmaxf(m, __shfl_xor(m, 16, 64));
    m = fmaxf(m, __shfl_xor(m, 32, 64));
    float z = 0.f;
#pragma unroll
    for (int mi = 0; mi < 8; ++mi)
#pragma unroll
      for (int r = 0; r < 4; ++r) z += __expf(acc[mi][ni][r] + sb[ni] - m);
    z += __shfl_xor(z, 16, 64);
    z += __shfl_xor(z, 32, 64);
    if (lane < 16) {
      int n = nt * 256 + wn * 64 + ni * 16 + lane;
      if (n < 512) {
        size_t o = ((size_t)b * 512 + n) * JCH + jc;
        mglob[o] = m; zglob[o] = z;
      } else {
        locinv[((size_t)b * JCH + jc) * 512 + (n - 512)] = 1.0f / z;
      }
    }
  }
}

// ---------------- LN(mean over Q) of question -> qvec[b][1024] ----------------
__global__ __launch_bounds__(256) void k_qvec(const float* __restrict__ q, const float* __restrict__ g,
                                              const float* __restrict__ lb, float* __restrict__ qvec) {
  int b = blockIdx.x, t = threadIdx.x;
  const float* p = q + (size_t)b * QN * HDIM + t * 4;
  float a0 = 0, a1 = 0, a2 = 0, a3 = 0;
  for (int r = 0; r < QN; ++r) {
    float4 v = *(const float4*)(p + (size_t)r * HDIM);
    a0 += v.x; a1 += v.y; a2 += v.z; a3 += v.w;
  }
  const float sc = 1.0f / QN;
  a0 *= sc; a1 *= sc; a2 *= sc; a3 *= sc;
  float s = a0 + a1 + a2 + a3;
  float ss = a0 * a0 + a1 * a1 + a2 * a2 + a3 * a3;
#pragma unroll
  for (int o = 1; o < 64; o <<= 1) { s += __shfl_xor(s, o, 64); ss += __shfl_xor(ss, o, 64); }
  __shared__ float sm[4], sq[4];
  int wid = t >> 6, lane = t & 63;
  if (lane == 0) { sm[wid] = s; sq[wid] = ss; }
  __syncthreads();
  float S = sm[0] + sm[1] + sm[2] + sm[3], SS = sq[0] + sq[1] + sq[2] + sq[3];
  float mu = S / HDIM;
  float inv = rsqrtf(SS / HDIM - mu * mu + 1e-5f);
  int c = t * 4;
  float4 o;
  o.x = (a0 - mu) * inv * g[c + 0] + lb[c + 0];
  o.y = (a1 - mu) * inv * g[c + 1] + lb[c + 1];
  o.z = (a2 - mu) * inv * g[c + 2] + lb[c + 2];
  o.w = (a3 - mu) * inv * g[c + 3] + lb[c + 3];
  *(float4*)&qvec[(size_t)b * HDIM + c] = o;
}

// ---------------- LN(mean over L) of context chunks (bf16 src) -> cvec[b*64+j][1024] ----------------
__global__ __launch_bounds__(256) void k_cvec(const u16* __restrict__ ctxb, const float* __restrict__ g,
                                              const float* __restrict__ lb, float* __restrict__ cvec) {
  int bj = blockIdx.x, t = threadIdx.x;
  int b = bj >> 6, jc = bj & 63;
  const u16* p = ctxb + ((size_t)b * KN + jc * LCH) * HDIM + t * 4;
  float a0 = 0, a1 = 0, a2 = 0, a3 = 0;
  for (int r = 0; r < LCH; ++r) {
    ushort4 v = *(const ushort4*)(p + (size_t)r * HDIM);
    a0 += bf2f(v.x); a1 += bf2f(v.y); a2 += bf2f(v.z); a3 += bf2f(v.w);
  }
  const float sc = 1.0f / LCH;
  a0 *= sc; a1 *= sc; a2 *= sc; a3 *= sc;
  float s = a0 + a1 + a2 + a3;
  float ss = a0 * a0 + a1 * a1 + a2 * a2 + a3 * a3;
#pragma unroll
  for (int o = 1; o < 64; o <<= 1) { s += __shfl_xor(s, o, 64); ss += __shfl_xor(ss, o, 64); }
  __shared__ float sm[4], sq[4];
  int wid = t >> 6, lane = t & 63;
  if (lane == 0) { sm[wid] = s; sq[wid] = ss; }
  __syncthreads();
  float S = sm[0] + sm[1] + sm[2] + sm[3], SS = sq[0] + sq[1] + sq[2] + sq[3];
  float mu = S / HDIM;
  float inv = rsqrtf(SS / HDIM - mu * mu + 1e-5f);
  int c = t * 4;
  float4 o;
  o.x = (a0 - mu) * inv * g[c + 0] + lb[c + 0];
  o.y = (a1 - mu) * inv * g[c + 1] + lb[c + 1];
  o.z = (a2 - mu) * inv * g[c + 2] + lb[c + 2];
  o.w = (a3 - mu) * inv * g[c + 3] + lb[c + 3];
  *(float4*)&cvec[(size_t)bj * HDIM + c] = o;
}

// ---------------- qpart[b][n] += qvec[b][c-slice] . W1[c-slice, n]  (split-K, 256 blocks) ------
__global__ __launch_bounds__(256) void k_qpart(const float* __restrict__ qvec, const float* __restrict__ W1,
                                               float* __restrict__ qpart) {
  int nt = blockIdx.x, b = blockIdx.y, ks = blockIdx.z;
  int n = nt * 256 + threadIdx.x;
  const float* qv = qvec + (size_t)b * HDIM + ks * 64;
  const float* wp = W1 + (size_t)ks * 64 * HDIM + n;
  float acc = 0.f;
#pragma unroll 8
  for (int c = 0; c < 64; ++c) acc += qv[c] * wp[(size_t)c * HDIM];
  atomicAdd(&qpart[(size_t)b * HDIM + n], acc);
}

// ---------------- per-(b,hq) global max/denominator over chunks (contiguous reads) ----------------
__global__ __launch_bounds__(64) void k_hq(const float* __restrict__ mglob, const float* __restrict__ zglob,
                                           float* __restrict__ Mh, float* __restrict__ Zr) {
  int id = blockIdx.x * 64 + threadIdx.x;   // grid 32 -> 0..2047
  int b = id >> 9, hq = id & 511;
  const float* mg = mglob + ((size_t)b * 512 + hq) * JCH;
  const float* zg = zglob + ((size_t)b * 512 + hq) * JCH;
  float m = -1e30f;
  for (int j = 0; j < JCH; ++j) m = fmaxf(m, mg[j]);
  float z = 0.f;
  for (int j = 0; j < JCH; ++j) z += zg[j] * __expf(mg[j] - m);
  Mh[id] = m;
  Zr[id] = 1.0f / z;
}

// ---------------- per-(b,j) pooled scalars: att, loc, gate-dot (gelu fused) ----------------
__global__ __launch_bounds__(256) void k_chunk(const float* __restrict__ mglob, const float* __restrict__ zglob,
                                               const float* __restrict__ locinv,
                                               const float* __restrict__ Mh, const float* __restrict__ Zr,
                                               const float* __restrict__ h1, const float* __restrict__ qpart,
                                               const float* __restrict__ b1, const float* __restrict__ W2,
                                               float* __restrict__ abuf, float* __restrict__ lbuf,
                                               float* __restrict__ gbuf) {
  int bj = blockIdx.x, t = threadIdx.x;
  int b = bj >> 6, j = bj & 63;
  const float* mg = mglob + (size_t)b * 512 * JCH + j;   // stride JCH over hq
  const float* zg = zglob + (size_t)b * 512 * JCH + j;
  const float* lp = locinv + (size_t)bj * 512;
  const float* Mb = Mh + (size_t)b * 512;
  const float* Zb = Zr + (size_t)b * 512;
  float a = 0.f, l = 0.f, gsum = 0.f;
  for (int hq = t; hq < 512; hq += 256) {
    a += zg[(size_t)hq * JCH] * __expf(mg[(size_t)hq * JCH] - Mb[hq]) * Zb[hq];
    l += lp[hq];
  }
  const float* hp = h1 + (size_t)bj * HDIM;
  const float* qp = qpart + (size_t)b * HDIM;
  for (int n = t; n < HDIM; n += 256) {
    float x = hp[n] + qp[n] + b1[n];
    x = x * 0.5f * (1.0f + erff(x * 0.70710678118654752f));
    gsum += x * W2[n];
  }
#pragma unroll
  for (int o = 1; o < 64; o <<= 1) {
    a += __shfl_xor(a, o, 64); l += __shfl_xor(l, o, 64); gsum += __shfl_xor(gsum, o, 64);
  }
  __shared__ float ra[4], rl[4], rg[4];
  int wid = t >> 6, lane = t & 63;
  if (lane == 0) { ra[wid] = a; rl[wid] = l; rg[wid] = gsum; }
  __syncthreads();
  if (t == 0) {
    abuf[bj] = (ra[0] + ra[1] + ra[2] + ra[3]) * (1.0f / 65536.0f);
    lbuf[bj] = (rl[0] + rl[1] + rl[2] + rl[3]) * (1.0f / 512.0f);
    gbuf[bj] = rg[0] + rg[1] + rg[2] + rg[3];
  }
}

// ---------------- final: softmaxes over J, fuse, outputs ----------------
__global__ __launch_bounds__(64) void k_final(const float* __restrict__ abuf, const float* __restrict__ lbuf,
                                              const float* __restrict__ gbuf, const float* __restrict__ b2,
                                              float* __restrict__ out) {
  int b = blockIdx.x, t = threadIdx.x;   // 64 threads
  float a = abuf[b * 64 + t];
  float l = lbuf[b * 64 + t];
  float gt = gbuf[b * 64 + t] + b2[0];
  gt = 1.0f / (1.0f + __expf(-gt));
  float am = a, lm = l;
#pragma unroll
  for (int o = 1; o < 64; o <<= 1) { am = fmaxf(am, __shfl_xor(am, o, 64)); lm = fmaxf(lm, __shfl_xor(lm, o, 64)); }
  float ae = __expf(a - am), le = __expf(l - lm);
  float as_ = ae, ls_ = le;
#pragma unroll
  for (int o = 1; o < 64; o <<= 1) { as_ += __shfl_xor(as_, o, 64); ls_ += __shfl_xor(ls_, o, 64); }
  float gs = ae / as_, ls = le / ls_;
  float fu = gt * ls + (1.0f - gt) * gs;
  float fm = fu;
#pragma unroll
  for (int o = 1; o < 64; o <<= 1) fm = fmaxf(fm, __shfl_xor(fm, o, 64));
  float fe = __expf(fu - fm);
  float fs_ = fe;
#pragma unroll
  for (int o = 1; o < 64; o <<= 1) fs_ += __shfl_xor(fs_, o, 64);
  float fv = fe / fs_;
  out[b * 64 + t] = fv;
  out[256 + b * 64 + t] = ls;
  out[512 + b * 64 + t] = gs;
  float tot = fv;
#pragma unroll
  for (int o = 1; o < 64; o <<= 1) tot += __shfl_xor(tot, o, 64);
  if (t == 0) out[768 + b] = tot * (1.0f / 64.0f);
}

// ---------------- launcher ----------------
extern "C" void kernel_launch(void* const* d_in, const int* in_sizes, int n_in,
                              void* d_out, int out_size, void* d_ws, size_t ws_size,
                              hipStream_t stream) {
  const float* question = (const float*)d_in[0];
  const float* context  = (const float*)d_in[1];
  const float* Wq_l = (const float*)d_in[2];
  const float* bq_l = (const float*)d_in[3];
  const float* Wk_l = (const float*)d_in[4];
  const float* bk_l = (const float*)d_in[5];
  const float* Wq_g = (const float*)d_in[6];
  const float* bq_g = (const float*)d_in[7];
  const float* Wk_g = (const float*)d_in[8];
  const float* bk_g = (const float*)d_in[9];
  const float* ln_g = (const float*)d_in[10];
  const float* ln_b = (const float*)d_in[11];
  const float* W1   = (const float*)d_in[12];
  const float* b1   = (const float*)d_in[13];
  const float* W2   = (const float*)d_in[14];
  const float* b2   = (const float*)d_in[15];

  char* ws = (char*)d_ws;
  u16*   ctxb   = (u16*)(ws + 0);            // 67108864 B
  u16*   Ab     = (u16*)(ws + 67108864);     //  8388608 B
  float* qh     = (float*)(ws + 75497472);   //  1048576 B  [2][4][32][1024]
  float* sbias  = (float*)(ws + 76546048);   //    16384 B
  float* mglob  = (float*)(ws + 76562432);   //   524288 B  [4][512][64]  (transposed)
  float* zglob  = (float*)(ws + 77086720);   //   524288 B
  float* locinv = (float*)(ws + 77611008);   //   524288 B  [4][64][512]
  float* qvec   = (float*)(ws + 78135296);   //    16384 B
  float* cvec   = (float*)(ws + 78151680);   //  1048576 B  [256][1024]
  float* qpart  = (float*)(ws + 79200256);   //    16384 B
  float* h1     = (float*)(ws + 79216640);   //  1048576 B  [256][1024]
  float* Mh     = (float*)(ws + 80265216);   //     8192 B  [4][512]
  float* Zr     = (float*)(ws + 80273408);   //     8192 B
  float* abuf   = (float*)(ws + 80281600);   //     1024 B  [4][64]
  float* lbuf   = (float*)(ws + 80282624);   //     1024 B
  float* gbuf   = (float*)(ws + 80283648);   //     1024 B

  hipMemsetAsync(qh, 0, 1048576, stream);
  hipMemsetAsync(h1, 0, 1048576, stream);
  hipMemsetAsync(qpart, 0, 16384, stream);

  hipLaunchKernelGGL(k_ctx2bf16, dim3(2048), dim3(256), 0, stream, context, ctxb);
  // qh_g / qh_l : question[128x1024] @ Wq[1024x1024], both scorers in one launch
  hipLaunchKernelGGL(k_gemm_qh, dim3(2, 32, 8), dim3(256), 0, stream, question, Wq_g, Wq_l, qh);
  hipLaunchKernelGGL(k_afold, dim3(4, 32, 4), dim3(256), 0, stream, qh, Wk_g, Wk_l, bq_g, bq_l, Ab);
  hipLaunchKernelGGL(k_sbias, dim3(16), dim3(256), 0, stream, qh, bk_g, bk_l, bq_g, bq_l, sbias);
  hipLaunchKernelGGL(k_scores, dim3(512), dim3(512), 0, stream, ctxb, Ab, sbias, mglob, zglob, locinv);
  hipLaunchKernelGGL(k_qvec, dim3(4), dim3(256), 0, stream, question, ln_g, ln_b, qvec);
  hipLaunchKernelGGL(k_cvec, dim3(256), dim3(256), 0, stream, ctxb, ln_g, ln_b, cvec);
  hipLaunchKernelGGL(k_qpart, dim3(4, 4, 16), dim3(256), 0, stream, qvec, W1, qpart);
  // h1pre += cvec[256x1024] @ W1[1024:2048, :]
  hipLaunchKernelGGL(k_gemm_f32, dim3(4, 16, 8), dim3(256), 0, stream, cvec, HDIM, W1 + 1048576, HDIM, h1, HDIM, 128);
  hipLaunchKernelGGL(k_hq, dim3(32), dim3(64), 0, stream, mglob, zglob, Mh, Zr);
  hipLaunchKernelGGL(k_chunk, dim3(256), dim3(256), 0, stream, mglob, zglob, locinv, Mh, Zr, h1, qpart, b1, W2, abuf, lbuf, gbuf);
  hipLaunchKernelGGL(k_final, dim3(4), dim3(64), 0, stream, abuf, lbuf, gbuf, b2, (float*)d_out);
}

// Round 7
// 232.199 us; speedup vs baseline: 1.8693x; 1.0731x over previous
//
#include <hip/hip_runtime.h>
#include <math.h>

// ---------------- problem constants (fixed by setup_inputs) ----------------
#define B_    4
#define QN    32
#define KN    8192
#define HDIM  1024
#define NHD   16
#define DH    64
#define LCH   128
#define JCH   64

typedef float f32x4 __attribute__((ext_vector_type(4)));
typedef short s16x8 __attribute__((ext_vector_type(8)));
typedef unsigned short u16;

__device__ __forceinline__ u16 f2bf(float f) {          // round-to-nearest-even f32->bf16
  unsigned u = __float_as_uint(f);
  u += 0x7fffu + ((u >> 16) & 1u);
  return (u16)(u >> 16);
}

__device__ __forceinline__ float bf2f(u16 v) {
  return __uint_as_float(((unsigned)v) << 16);
}

__device__ __forceinline__ void llds16(const void* g, void* l) {   // 16B global->LDS DMA
  __builtin_amdgcn_global_load_lds((const __attribute__((address_space(1))) unsigned int*)g,
                                   (__attribute__((address_space(3))) unsigned int*)l,
                                   16, 0, 0);
}

// ---------------- zero-init for atomic accumulators (replaces 3 slow rocclr fills) ----------------
__global__ __launch_bounds__(256) void k_zero(float* __restrict__ qh, float* __restrict__ h1,
                                              float* __restrict__ qpart) {
  int i = blockIdx.x * 256 + threadIdx.x;   // grid 516 -> 132096 float4 slots
  float4 z = make_float4(0.f, 0.f, 0.f, 0.f);
  if (i < 65536)        ((float4*)qh)[i] = z;
  else if (i < 131072)  ((float4*)h1)[i - 65536] = z;
  else if (i < 132096)  ((float4*)qpart)[i - 131072] = z;
}

// ---------------- fused: context fp32 -> bf16 copy  +  per-chunk mean -> LN -> cvec ----------------
// grid 256 (= b*64+jc), 256 thr. Thread t owns cols [4t,4t+4) over the chunk's 128 rows.
__global__ __launch_bounds__(256) void k_ctxcv(const float* __restrict__ ctx, u16* __restrict__ ctxb,
                                               const float* __restrict__ g, const float* __restrict__ lb,
                                               float* __restrict__ cvec) {
  int bj = blockIdx.x, t = threadIdx.x;
  const float* p = ctx + (size_t)bj * LCH * HDIM + t * 4;
  u16* op = ctxb + (size_t)bj * LCH * HDIM + t * 4;
  float a0 = 0, a1 = 0, a2 = 0, a3 = 0;
  for (int r = 0; r < LCH; ++r) {
    float4 v = *(const float4*)(p + (size_t)r * HDIM);
    ushort4 o;
    o.x = f2bf(v.x); o.y = f2bf(v.y); o.z = f2bf(v.z); o.w = f2bf(v.w);
    *(ushort4*)(op + (size_t)r * HDIM) = o;
    a0 += v.x; a1 += v.y; a2 += v.z; a3 += v.w;
  }
  const float sc = 1.0f / LCH;
  a0 *= sc; a1 *= sc; a2 *= sc; a3 *= sc;
  float s = a0 + a1 + a2 + a3;
  float ss = a0 * a0 + a1 * a1 + a2 * a2 + a3 * a3;
#pragma unroll
  for (int o = 1; o < 64; o <<= 1) { s += __shfl_xor(s, o, 64); ss += __shfl_xor(ss, o, 64); }
  __shared__ float sm[4], sq[4];
  int wid = t >> 6, lane = t & 63;
  if (lane == 0) { sm[wid] = s; sq[wid] = ss; }
  __syncthreads();
  float S = sm[0] + sm[1] + sm[2] + sm[3], SS = sq[0] + sq[1] + sq[2] + sq[3];
  float mu = S / HDIM;
  float inv = rsqrtf(SS / HDIM - mu * mu + 1e-5f);
  int c = t * 4;
  float4 o;
  o.x = (a0 - mu) * inv * g[c + 0] + lb[c + 0];
  o.y = (a1 - mu) * inv * g[c + 1] + lb[c + 1];
  o.z = (a2 - mu) * inv * g[c + 2] + lb[c + 2];
  o.w = (a3 - mu) * inv * g[c + 3] + lb[c + 3];
  *(float4*)&cvec[(size_t)bj * HDIM + c] = o;
}

// ---------------- generic fp32 tiled GEMM, C += A*B over one K-slice (atomic) ----------------
__global__ __launch_bounds__(256) void k_gemm_f32(const float* __restrict__ A, int lda,
                                                  const float* __restrict__ Bm, int ldb,
                                                  float* __restrict__ C, int ldc, int kchunk) {
  __shared__ float As[64][17];
  __shared__ float Bs[16][64];
  int t = threadIdx.x;
  int m0 = blockIdx.x * 64, n0 = blockIdx.y * 64, k0 = blockIdx.z * kchunk;
  int tm = t >> 4, tn = t & 15;
  float c[4][4];
#pragma unroll
  for (int i = 0; i < 4; ++i)
#pragma unroll
    for (int j = 0; j < 4; ++j) c[i][j] = 0.f;
  int ra = t >> 2, ka = (t & 3) * 4;
  int kb = t >> 4, nb = (t & 15) * 4;
  for (int kk = 0; kk < kchunk; kk += 16) {
    float4 va = *(const float4*)(A + (size_t)(m0 + ra) * lda + k0 + kk + ka);
    float4 vb = *(const float4*)(Bm + (size_t)(k0 + kk + kb) * ldb + n0 + nb);
    As[ra][ka] = va.x; As[ra][ka + 1] = va.y; As[ra][ka + 2] = va.z; As[ra][ka + 3] = va.w;
    *(float4*)&Bs[kb][nb] = vb;
    __syncthreads();
#pragma unroll
    for (int kq = 0; kq < 16; ++kq) {
      float a0 = As[tm * 4 + 0][kq], a1 = As[tm * 4 + 1][kq];
      float a2 = As[tm * 4 + 2][kq], a3 = As[tm * 4 + 3][kq];
      float b0 = Bs[kq][tn * 4 + 0], b1 = Bs[kq][tn * 4 + 1];
      float b2 = Bs[kq][tn * 4 + 2], b3 = Bs[kq][tn * 4 + 3];
      c[0][0] += a0 * b0; c[0][1] += a0 * b1; c[0][2] += a0 * b2; c[0][3] += a0 * b3;
      c[1][0] += a1 * b0; c[1][1] += a1 * b1; c[1][2] += a1 * b2; c[1][3] += a1 * b3;
      c[2][0] += a2 * b0; c[2][1] += a2 * b1; c[2][2] += a2 * b2; c[2][3] += a2 * b3;
      c[3][0] += a3 * b0; c[3][1] += a3 * b1; c[3][2] += a3 * b2; c[3][3] += a3 * b3;
    }
    __syncthreads();
  }
#pragma unroll
  for (int i = 0; i < 4; ++i)
#pragma unroll
    for (int j = 0; j < 4; ++j)
      atomicAdd(&C[(size_t)(m0 + tm * 4 + i) * ldc + n0 + tn * 4 + j], c[i][j]);
}

// ---------------- merged qh GEMM: both Wq_g and Wq_l in one launch ----------------
__global__ __launch_bounds__(256) void k_gemm_qh(const float* __restrict__ A,
                                                 const float* __restrict__ Bg, const float* __restrict__ Bl,
                                                 float* __restrict__ C) {
  __shared__ float As[64][17];
  __shared__ float Bs[16][64];
  int t = threadIdx.x;
  int ny = blockIdx.y;
  const float* Bm = (ny < 16) ? Bg : Bl;
  float* Cp = (ny < 16) ? C : (C + 131072);
  int m0 = blockIdx.x * 64, n0 = (ny & 15) * 64, k0 = blockIdx.z * 128;
  int tm = t >> 4, tn = t & 15;
  float c[4][4];
#pragma unroll
  for (int i = 0; i < 4; ++i)
#pragma unroll
    for (int j = 0; j < 4; ++j) c[i][j] = 0.f;
  int ra = t >> 2, ka = (t & 3) * 4;
  int kb = t >> 4, nb = (t & 15) * 4;
  for (int kk = 0; kk < 128; kk += 16) {
    float4 va = *(const float4*)(A + (size_t)(m0 + ra) * HDIM + k0 + kk + ka);
    float4 vb = *(const float4*)(Bm + (size_t)(k0 + kk + kb) * HDIM + n0 + nb);
    As[ra][ka] = va.x; As[ra][ka + 1] = va.y; As[ra][ka + 2] = va.z; As[ra][ka + 3] = va.w;
    *(float4*)&Bs[kb][nb] = vb;
    __syncthreads();
#pragma unroll
    for (int kq = 0; kq < 16; ++kq) {
      float a0 = As[tm * 4 + 0][kq], a1 = As[tm * 4 + 1][kq];
      float a2 = As[tm * 4 + 2][kq], a3 = As[tm * 4 + 3][kq];
      float b0 = Bs[kq][tn * 4 + 0], b1 = Bs[kq][tn * 4 + 1];
      float b2 = Bs[kq][tn * 4 + 2], b3 = Bs[kq][tn * 4 + 3];
      c[0][0] += a0 * b0; c[0][1] += a0 * b1; c[0][2] += a0 * b2; c[0][3] += a0 * b3;
      c[1][0] += a1 * b0; c[1][1] += a1 * b1; c[1][2] += a1 * b2; c[1][3] += a1 * b3;
      c[2][0] += a2 * b0; c[2][1] += a2 * b1; c[2][2] += a2 * b2; c[2][3] += a2 * b3;
      c[3][0] += a3 * b0; c[3][1] += a3 * b1; c[3][2] += a3 * b2; c[3][3] += a3 * b3;
    }
    __syncthreads();
  }
#pragma unroll
  for (int i = 0; i < 4; ++i)
#pragma unroll
    for (int j = 0; j < 4; ++j)
      atomicAdd(&Cp[(size_t)(m0 + tm * 4 + i) * HDIM + n0 + tn * 4 + j], c[i][j]);
}

// ---------------- folded score matrix A[b][n][c] (bf16, scale 1/8, bq folded in) ----------------
__global__ __launch_bounds__(256) void k_afold(const float* __restrict__ qh, const float* __restrict__ Wk_g,
                                               const float* __restrict__ Wk_l, const float* __restrict__ bq_g,
                                               const float* __restrict__ bq_l, u16* __restrict__ Ab) {
  int ct = blockIdx.x;          // 0..3  (c tile of 256)
  int slot = blockIdx.y;        // 0..31 (s2*16 + h)
  int b = blockIdx.z;
  int s2 = slot >> 4, h = slot & 15;
  const float* qhp = qh + (size_t)(s2 * 4 + b) * QN * HDIM;
  const float* Wk = s2 ? Wk_l : Wk_g;
  const float* bq = s2 ? bq_l : bq_g;
  __shared__ float qs[QN][DH];
  int t = threadIdx.x;
  {
    int q = t >> 3, doff = (t & 7) * 8;
    const float4* src = (const float4*)(qhp + (size_t)q * HDIM + h * DH + doff);
    float4 b0 = *(const float4*)(bq + h * DH + doff);
    float4 b1 = *(const float4*)(bq + h * DH + doff + 4);
    float4 v0 = src[0], v1 = src[1];
    qs[q][doff + 0] = v0.x + b0.x; qs[q][doff + 1] = v0.y + b0.y;
    qs[q][doff + 2] = v0.z + b0.z; qs[q][doff + 3] = v0.w + b0.w;
    qs[q][doff + 4] = v1.x + b1.x; qs[q][doff + 5] = v1.y + b1.y;
    qs[q][doff + 6] = v1.z + b1.z; qs[q][doff + 7] = v1.w + b1.w;
  }
  __syncthreads();
  int c = ct * 256 + t;
  float w[DH];
  const float* wr = Wk + (size_t)c * HDIM + h * DH;
#pragma unroll
  for (int d = 0; d < DH; d += 4) {
    float4 v = *(const float4*)(wr + d);
    w[d] = v.x; w[d + 1] = v.y; w[d + 2] = v.z; w[d + 3] = v.w;
  }
  u16* outp = Ab + ((size_t)b * HDIM + s2 * 512 + h * QN) * HDIM + c;
  for (int q = 0; q < QN; ++q) {
    float acc = 0.f;
#pragma unroll
    for (int d = 0; d < DH; ++d) acc += qs[q][d] * w[d];
    outp[(size_t)q * HDIM] = f2bf(acc * 0.125f);
  }
}

// ---------------- score bias sbias[b][n] = (1/8) (qh+bq) . bk ----------------
__global__ __launch_bounds__(256) void k_sbias(const float* __restrict__ qh, const float* __restrict__ bk_g,
                                               const float* __restrict__ bk_l, const float* __restrict__ bq_g,
                                               const float* __restrict__ bq_l, float* __restrict__ sbias) {
  int i = blockIdx.x * 256 + threadIdx.x;   // 0..4095
  int b = i >> 10, n = i & (HDIM - 1);
  int s2 = n >> 9, hq = n & 511, h = hq >> 5, q = hq & 31;
  const float* qr = qh + ((size_t)(s2 * 4 + b) * QN + q) * HDIM + h * DH;
  const float* bk = (s2 ? bk_l : bk_g) + h * DH;
  const float* bq = (s2 ? bq_l : bq_g) + h * DH;
  float acc = 0.f;
#pragma unroll
  for (int d = 0; d < DH; ++d) acc += (qr[d] + bq[d]) * bk[d];
  sbias[i] = acc * 0.125f;
}

// ---------------- THE big fused kernel: S = ctx_bf16 @ A^T, column-wise (max,sumexp) per chunk ----
// 256x256 tile, BK=64, 8 waves (2M x 4N), 512 thr, dbuf 128KB, counted vmcnt(8) pipeline.
__global__ __launch_bounds__(512, 2) void k_scores(const u16* __restrict__ ctxb, const u16* __restrict__ Ab,
                                                   const float* __restrict__ sbias,
                                                   float* __restrict__ mglob, float* __restrict__ zglob,
                                                   float* __restrict__ locinv) {
  __shared__ u16 lds[65536];      // A0 | B0 | A1 | B1, 16384 u16 (32KB) each
  u16* A0 = lds;           u16* B0 = lds + 16384;
  u16* A1 = lds + 32768;   u16* B1 = lds + 49152;
  // XCD-bijective remap: 512 blocks, XCD x owns works [x*64, x*64+64)
  int bid = blockIdx.x;
  int work = (bid & 7) * 64 + (bid >> 3);
  int b = work >> 7, rem = work & 127, rt = rem >> 2, nt = rem & 3;
  int t = threadIdx.x, wid = t >> 6, lane = t & 63;
  int wm = wid >> 2, wn = wid & 3;
  int lrow = lane & 15, lkg = lane >> 4;

  const u16* ctx0 = ctxb + ((size_t)b * KN + rt * 256) * HDIM;
  const u16* Afp  = Ab + ((size_t)b * HDIM + nt * 256) * HDIM;

  // ---- staging geometry (per llds16: 8 waves x 8 rows = 64 rows; 4 insts per matrix) ----
  int grow = wid * 8 + (lane >> 3);          // row within a 64-row group
  int gslot = (lane & 7) ^ (lane >> 3);      // pre-swizzled global 16B-slot
  const u16* gA[4]; const u16* gB[4]; int dof[4];
#pragma unroll
  for (int s = 0; s < 4; ++s) {
    gA[s] = ctx0 + (size_t)(s * 64 + grow) * HDIM + gslot * 8;
    gB[s] = Afp + (size_t)(s * 64 + grow) * HDIM + gslot * 8;
    dof[s] = s * 4096 + wid * 512;           // u16 idx, wave-uniform LDS dest
  }

  // ---- ds_read offsets (loop-invariant) ----
  int rowA = (wm * 128 + lrow) * 64;
  int rowB = (wn * 64 + lrow) * 64;
  int p8[2];
#pragma unroll
  for (int ks = 0; ks < 2; ++ks) p8[ks] = ((ks * 4 + lkg) ^ (lane & 7)) * 8;

  f32x4 acc[8][4];
#pragma unroll
  for (int mi = 0; mi < 8; ++mi)
#pragma unroll
    for (int ni = 0; ni < 4; ++ni) acc[mi][ni] = 0.f;

#define STAGE(AT, BT, KT) { \
  _Pragma("unroll") for (int s = 0; s < 4; ++s) { \
    llds16(gA[s] + (KT) * 64, (AT) + dof[s]); \
    llds16(gB[s] + (KT) * 64, (BT) + dof[s]); } }

#define COMPUTE(AT, BT) { \
  _Pragma("unroll") for (int ks = 0; ks < 2; ++ks) { \
    const u16* pA = (AT) + rowA + p8[ks]; \
    const u16* pB = (BT) + rowB + p8[ks]; \
    s16x8 av[8], bv[4]; \
    _Pragma("unroll") for (int mi = 0; mi < 8; ++mi) av[mi] = *(const s16x8*)(pA + mi * 1024); \
    _Pragma("unroll") for (int ni = 0; ni < 4; ++ni) bv[ni] = *(const s16x8*)(pB + ni * 1024); \
    _Pragma("unroll") for (int mi = 0; mi < 8; ++mi) \
    _Pragma("unroll") for (int ni = 0; ni < 4; ++ni) \
      acc[mi][ni] = __builtin_amdgcn_mfma_f32_16x16x32_bf16(av[mi], bv[ni], acc[mi][ni], 0, 0, 0); } }

#define SYNCN(N) { asm volatile("s_waitcnt vmcnt(" #N ")" ::: "memory"); \
                   __builtin_amdgcn_s_barrier(); \
                   __builtin_amdgcn_sched_barrier(0); }

#define SUB(KT, CA, CB, SA, SB, FULL) { \
  if (FULL) { STAGE(SA, SB, (KT) + 1); } \
  if (FULL) { SYNCN(8) } else { SYNCN(0) } \
  __builtin_amdgcn_s_setprio(1); \
  COMPUTE(CA, CB); \
  __builtin_amdgcn_s_setprio(0); \
  __builtin_amdgcn_s_barrier(); }

  STAGE(A0, B0, 0);
  SUB(0,  A0, B0, A1, B1, 1)
  SUB(1,  A1, B1, A0, B0, 1)
  SUB(2,  A0, B0, A1, B1, 1)
  SUB(3,  A1, B1, A0, B0, 1)
  SUB(4,  A0, B0, A1, B1, 1)
  SUB(5,  A1, B1, A0, B0, 1)
  SUB(6,  A0, B0, A1, B1, 1)
  SUB(7,  A1, B1, A0, B0, 1)
  SUB(8,  A0, B0, A1, B1, 1)
  SUB(9,  A1, B1, A0, B0, 1)
  SUB(10, A0, B0, A1, B1, 1)
  SUB(11, A1, B1, A0, B0, 1)
  SUB(12, A0, B0, A1, B1, 1)
  SUB(13, A1, B1, A0, B0, 1)
  SUB(14, A0, B0, A1, B1, 1)
  SUB(15, A1, B1, A0, B0, 0)
#undef STAGE
#undef COMPUTE
#undef SYNCN
#undef SUB

  // ---- epilogue: per column, (max, sumexp) over this wave's 128 rows (= one chunk) ----
  int jc = rt * 2 + wm;
  float sb[4];
#pragma unroll
  for (int ni = 0; ni < 4; ++ni)
    sb[ni] = sbias[b * HDIM + nt * 256 + wn * 64 + ni * 16 + lrow];
#pragma unroll
  for (int ni = 0; ni < 4; ++ni) {
    float m = -1e30f;
#pragma unroll
    for (int mi = 0; mi < 8; ++mi)
#pragma unroll
      for (int r = 0; r < 4; ++r) m = fmaxf(m, acc[mi][ni][r]);
    m += sb[ni];
    m = fmaxf(m, __shfl_xor(m, 16, 64));
    m = fmaxf(m, __shfl_xor(m, 32, 64));
    float z = 0.f;
#pragma unroll
    for (int mi = 0; mi < 8; ++mi)
#pragma unroll
      for (int r = 0; r < 4; ++r) z += __expf(acc[mi][ni][r] + sb[ni] - m);
    z += __shfl_xor(z, 16, 64);
    z += __shfl_xor(z, 32, 64);
    if (lane < 16) {
      int n = nt * 256 + wn * 64 + ni * 16 + lane;
      if (n < 512) {
        size_t o = ((size_t)b * 512 + n) * JCH + jc;
        mglob[o] = m; zglob[o] = z;
      } else {
        locinv[((size_t)b * JCH + jc) * 512 + (n - 512)] = 1.0f / z;
      }
    }
  }
}

// ---------------- LN(mean over Q) of question -> qvec[b][1024] ----------------
__global__ __launch_bounds__(256) void k_qvec(const float* __restrict__ q, const float* __restrict__ g,
                                              const float* __restrict__ lb, float* __restrict__ qvec) {
  int b = blockIdx.x, t = threadIdx.x;
  const float* p = q + (size_t)b * QN * HDIM + t * 4;
  float a0 = 0, a1 = 0, a2 = 0, a3 = 0;
  for (int r = 0; r < QN; ++r) {
    float4 v = *(const float4*)(p + (size_t)r * HDIM);
    a0 += v.x; a1 += v.y; a2 += v.z; a3 += v.w;
  }
  const float sc = 1.0f / QN;
  a0 *= sc; a1 *= sc; a2 *= sc; a3 *= sc;
  float s = a0 + a1 + a2 + a3;
  float ss = a0 * a0 + a1 * a1 + a2 * a2 + a3 * a3;
#pragma unroll
  for (int o = 1; o < 64; o <<= 1) { s += __shfl_xor(s, o, 64); ss += __shfl_xor(ss, o, 64); }
  __shared__ float sm[4], sq[4];
  int wid = t >> 6, lane = t & 63;
  if (lane == 0) { sm[wid] = s; sq[wid] = ss; }
  __syncthreads();
  float S = sm[0] + sm[1] + sm[2] + sm[3], SS = sq[0] + sq[1] + sq[2] + sq[3];
  float mu = S / HDIM;
  float inv = rsqrtf(SS / HDIM - mu * mu + 1e-5f);
  int c = t * 4;
  float4 o;
  o.x = (a0 - mu) * inv * g[c + 0] + lb[c + 0];
  o.y = (a1 - mu) * inv * g[c + 1] + lb[c + 1];
  o.z = (a2 - mu) * inv * g[c + 2] + lb[c + 2];
  o.w = (a3 - mu) * inv * g[c + 3] + lb[c + 3];
  *(float4*)&qvec[(size_t)b * HDIM + c] = o;
}

// ---------------- qpart[b][n] += qvec[b][c-slice] . W1[c-slice, n]  (split-K, 256 blocks) ------
__global__ __launch_bounds__(256) void k_qpart(const float* __restrict__ qvec, const float* __restrict__ W1,
                                               float* __restrict__ qpart) {
  int nt = blockIdx.x, b = blockIdx.y, ks = blockIdx.z;
  int n = nt * 256 + threadIdx.x;
  const float* qv = qvec + (size_t)b * HDIM + ks * 64;
  const float* wp = W1 + (size_t)ks * 64 * HDIM + n;
  float acc = 0.f;
#pragma unroll 8
  for (int c = 0; c < 64; ++c) acc += qv[c] * wp[(size_t)c * HDIM];
  atomicAdd(&qpart[(size_t)b * HDIM + n], acc);
}

// ---------------- per-(b,hq) global max/denominator over chunks (contiguous reads) ----------------
__global__ __launch_bounds__(64) void k_hq(const float* __restrict__ mglob, const float* __restrict__ zglob,
                                           float* __restrict__ Mh, float* __restrict__ Zr) {
  int id = blockIdx.x * 64 + threadIdx.x;   // grid 32 -> 0..2047
  int b = id >> 9, hq = id & 511;
  const float* mg = mglob + ((size_t)b * 512 + hq) * JCH;
  const float* zg = zglob + ((size_t)b * 512 + hq) * JCH;
  float m = -1e30f;
  for (int j = 0; j < JCH; ++j) m = fmaxf(m, mg[j]);
  float z = 0.f;
  for (int j = 0; j < JCH; ++j) z += zg[j] * __expf(mg[j] - m);
  Mh[id] = m;
  Zr[id] = 1.0f / z;
}

// ---------------- per-(b,j) pooled scalars: att, loc, gate-dot (gelu fused) ----------------
__global__ __launch_bounds__(256) void k_chunk(const float* __restrict__ mglob, const float* __restrict__ zglob,
                                               const float* __restrict__ locinv,
                                               const float* __restrict__ Mh, const float* __restrict__ Zr,
                                               const float* __restrict__ h1, const float* __restrict__ qpart,
                                               const float* __restrict__ b1, const float* __restrict__ W2,
                                               float* __restrict__ abuf, float* __restrict__ lbuf,
                                               float* __restrict__ gbuf) {
  int bj = blockIdx.x, t = threadIdx.x;
  int b = bj >> 6, j = bj & 63;
  const float* mg = mglob + (size_t)b * 512 * JCH + j;   // stride JCH over hq
  const float* zg = zglob + (size_t)b * 512 * JCH + j;
  const float* lp = locinv + (size_t)bj * 512;
  const float* Mb = Mh + (size_t)b * 512;
  const float* Zb = Zr + (size_t)b * 512;
  float a = 0.f, l = 0.f, gsum = 0.f;
  for (int hq = t; hq < 512; hq += 256) {
    a += zg[(size_t)hq * JCH] * __expf(mg[(size_t)hq * JCH] - Mb[hq]) * Zb[hq];
    l += lp[hq];
  }
  const float* hp = h1 + (size_t)bj * HDIM;
  const float* qp = qpart + (size_t)b * HDIM;
  for (int n = t; n < HDIM; n += 256) {
    float x = hp[n] + qp[n] + b1[n];
    x = x * 0.5f * (1.0f + erff(x * 0.70710678118654752f));
    gsum += x * W2[n];
  }
#pragma unroll
  for (int o = 1; o < 64; o <<= 1) {
    a += __shfl_xor(a, o, 64); l += __shfl_xor(l, o, 64); gsum += __shfl_xor(gsum, o, 64);
  }
  __shared__ float ra[4], rl[4], rg[4];
  int wid = t >> 6, lane = t & 63;
  if (lane == 0) { ra[wid] = a; rl[wid] = l; rg[wid] = gsum; }
  __syncthreads();
  if (t == 0) {
    abuf[bj] = (ra[0] + ra[1] + ra[2] + ra[3]) * (1.0f / 65536.0f);
    lbuf[bj] = (rl[0] + rl[1] + rl[2] + rl[3]) * (1.0f / 512.0f);
    gbuf[bj] = rg[0] + rg[1] + rg[2] + rg[3];
  }
}

// ---------------- final: softmaxes over J, fuse, outputs ----------------
__global__ __launch_bounds__(64) void k_final(const float* __restrict__ abuf, const float* __restrict__ lbuf,
                                              const float* __restrict__ gbuf, const float* __restrict__ b2,
                                              float* __restrict__ out) {
  int b = blockIdx.x, t = threadIdx.x;   // 64 threads
  float a = abuf[b * 64 + t];
  float l = lbuf[b * 64 + t];
  float gt = gbuf[b * 64 + t] + b2[0];
  gt = 1.0f / (1.0f + __expf(-gt));
  float am = a, lm = l;
#pragma unroll
  for (int o = 1; o < 64; o <<= 1) { am = fmaxf(am, __shfl_xor(am, o, 64)); lm = fmaxf(lm, __shfl_xor(lm, o, 64)); }
  float ae = __expf(a - am), le = __expf(l - lm);
  float as_ = ae, ls_ = le;
#pragma unroll
  for (int o = 1; o < 64; o <<= 1) { as_ += __shfl_xor(as_, o, 64); ls_ += __shfl_xor(ls_, o, 64); }
  float gs = ae / as_, ls = le / ls_;
  float fu = gt * ls + (1.0f - gt) * gs;
  float fm = fu;
#pragma unroll
  for (int o = 1; o < 64; o <<= 1) fm = fmaxf(fm, __shfl_xor(fm, o, 64));
  float fe = __expf(fu - fm);
  float fs_ = fe;
#pragma unroll
  for (int o = 1; o < 64; o <<= 1) fs_ += __shfl_xor(fs_, o, 64);
  float fv = fe / fs_;
  out[b * 64 + t] = fv;
  out[256 + b * 64 + t] = ls;
  out[512 + b * 64 + t] = gs;
  float tot = fv;
#pragma unroll
  for (int o = 1; o < 64; o <<= 1) tot += __shfl_xor(tot, o, 64);
  if (t == 0) out[768 + b] = tot * (1.0f / 64.0f);
}

// ---------------- launcher ----------------
extern "C" void kernel_launch(void* const* d_in, const int* in_sizes, int n_in,
                              void* d_out, int out_size, void* d_ws, size_t ws_size,
                              hipStream_t stream) {
  const float* question = (const float*)d_in[0];
  const float* context  = (const float*)d_in[1];
  const float* Wq_l = (const float*)d_in[2];
  const float* bq_l = (const float*)d_in[3];
  const float* Wk_l = (const float*)d_in[4];
  const float* bk_l = (const float*)d_in[5];
  const float* Wq_g = (const float*)d_in[6];
  const float* bq_g = (const float*)d_in[7];
  const float* Wk_g = (const float*)d_in[8];
  const float* bk_g = (const float*)d_in[9];
  const float* ln_g = (const float*)d_in[10];
  const float* ln_b = (const float*)d_in[11];
  const float* W1   = (const float*)d_in[12];
  const float* b1   = (const float*)d_in[13];
  const float* W2   = (const float*)d_in[14];
  const float* b2   = (const float*)d_in[15];

  char* ws = (char*)d_ws;
  u16*   ctxb   = (u16*)(ws + 0);            // 67108864 B
  u16*   Ab     = (u16*)(ws + 67108864);     //  8388608 B
  float* qh     = (float*)(ws + 75497472);   //  1048576 B  [2][4][32][1024]
  float* sbias  = (float*)(ws + 76546048);   //    16384 B
  float* mglob  = (float*)(ws + 76562432);   //   524288 B  [4][512][64]  (transposed)
  float* zglob  = (float*)(ws + 77086720);   //   524288 B
  float* locinv = (float*)(ws + 77611008);   //   524288 B  [4][64][512]
  float* qvec   = (float*)(ws + 78135296);   //    16384 B
  float* cvec   = (float*)(ws + 78151680);   //  1048576 B  [256][1024]
  float* qpart  = (float*)(ws + 79200256);   //    16384 B
  float* h1     = (float*)(ws + 79216640);   //  1048576 B  [256][1024]
  float* Mh     = (float*)(ws + 80265216);   //     8192 B  [4][512]
  float* Zr     = (float*)(ws + 80273408);   //     8192 B
  float* abuf   = (float*)(ws + 80281600);   //     1024 B  [4][64]
  float* lbuf   = (float*)(ws + 80282624);   //     1024 B
  float* gbuf   = (float*)(ws + 80283648);   //     1024 B

  hipLaunchKernelGGL(k_zero, dim3(516), dim3(256), 0, stream, qh, h1, qpart);
  hipLaunchKernelGGL(k_ctxcv, dim3(256), dim3(256), 0, stream, context, ctxb, ln_g, ln_b, cvec);
  hipLaunchKernelGGL(k_gemm_qh, dim3(2, 32, 8), dim3(256), 0, stream, question, Wq_g, Wq_l, qh);
  hipLaunchKernelGGL(k_afold, dim3(4, 32, 4), dim3(256), 0, stream, qh, Wk_g, Wk_l, bq_g, bq_l, Ab);
  hipLaunchKernelGGL(k_sbias, dim3(16), dim3(256), 0, stream, qh, bk_g, bk_l, bq_g, bq_l, sbias);
  hipLaunchKernelGGL(k_scores, dim3(512), dim3(512), 0, stream, ctxb, Ab, sbias, mglob, zglob, locinv);
  hipLaunchKernelGGL(k_qvec, dim3(4), dim3(256), 0, stream, question, ln_g, ln_b, qvec);
  hipLaunchKernelGGL(k_qpart, dim3(4, 4, 16), dim3(256), 0, stream, qvec, W1, qpart);
  // h1pre += cvec[256x1024] @ W1[1024:2048, :]
  hipLaunchKernelGGL(k_gemm_f32, dim3(4, 16, 8), dim3(256), 0, stream, cvec, HDIM, W1 + 1048576, HDIM, h1, HDIM, 128);
  hipLaunchKernelGGL(k_hq, dim3(32), dim3(64), 0, stream, mglob, zglob, Mh, Zr);
  hipLaunchKernelGGL(k_chunk, dim3(256), dim3(256), 0, stream, mglob, zglob, locinv, Mh, Zr, h1, qpart, b1, W2, abuf, lbuf, gbuf);
  hipLaunchKernelGGL(k_final, dim3(4), dim3(64), 0, stream, abuf, lbuf, gbuf, b2, (float*)d_out);
}

// Round 8
// 230.418 us; speedup vs baseline: 1.8838x; 1.0077x over previous
//
#include <hip/hip_runtime.h>
#include <math.h>

// ---------------- problem constants (fixed by setup_inputs) ----------------
#define B_    4
#define QN    32
#define KN    8192
#define HDIM  1024
#define NHD   16
#define DH    64
#define LCH   128
#define JCH   64

typedef float f32x4 __attribute__((ext_vector_type(4)));
typedef short s16x8 __attribute__((ext_vector_type(8)));
typedef unsigned short u16;

__device__ __forceinline__ u16 f2bf(float f) {          // round-to-nearest-even f32->bf16
  unsigned u = __float_as_uint(f);
  u += 0x7fffu + ((u >> 16) & 1u);
  return (u16)(u >> 16);
}

__device__ __forceinline__ void llds16(const void* g, void* l) {   // 16B global->LDS DMA
  __builtin_amdgcn_global_load_lds((const __attribute__((address_space(1))) unsigned int*)g,
                                   (__attribute__((address_space(3))) unsigned int*)l,
                                   16, 0, 0);
}

// ---------------- direct-write 64x64-tile GEMM over full K=1024 (no atomics, no zero-init) ----
__device__ __forceinline__ void gemm64_direct(const float* __restrict__ A, const float* __restrict__ Bm,
                                              float* __restrict__ C, int m0, int n0, char* smem) {
  float (*As)[17] = (float(*)[17])smem;              // 64x17 = 4352 B
  float (*Bs)[64] = (float(*)[64])(smem + 4352);     // 16x64 = 4096 B
  int t = threadIdx.x;
  int tm = t >> 4, tn = t & 15;
  int ra = t >> 2, ka = (t & 3) * 4;
  int kb = t >> 4, nb = (t & 15) * 4;
  float c[4][4];
#pragma unroll
  for (int i = 0; i < 4; ++i)
#pragma unroll
    for (int j = 0; j < 4; ++j) c[i][j] = 0.f;
  for (int kk = 0; kk < HDIM; kk += 16) {
    float4 va = *(const float4*)(A + (size_t)(m0 + ra) * HDIM + kk + ka);
    float4 vb = *(const float4*)(Bm + (size_t)(kk + kb) * HDIM + n0 + nb);
    As[ra][ka] = va.x; As[ra][ka + 1] = va.y; As[ra][ka + 2] = va.z; As[ra][ka + 3] = va.w;
    *(float4*)&Bs[kb][nb] = vb;
    __syncthreads();
#pragma unroll
    for (int kq = 0; kq < 16; ++kq) {
      float a0 = As[tm * 4 + 0][kq], a1 = As[tm * 4 + 1][kq];
      float a2 = As[tm * 4 + 2][kq], a3 = As[tm * 4 + 3][kq];
      float b0 = Bs[kq][tn * 4 + 0], b1 = Bs[kq][tn * 4 + 1];
      float b2 = Bs[kq][tn * 4 + 2], b3 = Bs[kq][tn * 4 + 3];
      c[0][0] += a0 * b0; c[0][1] += a0 * b1; c[0][2] += a0 * b2; c[0][3] += a0 * b3;
      c[1][0] += a1 * b0; c[1][1] += a1 * b1; c[1][2] += a1 * b2; c[1][3] += a1 * b3;
      c[2][0] += a2 * b0; c[2][1] += a2 * b1; c[2][2] += a2 * b2; c[2][3] += a2 * b3;
      c[3][0] += a3 * b0; c[3][1] += a3 * b1; c[3][2] += a3 * b2; c[3][3] += a3 * b3;
    }
    __syncthreads();
  }
#pragma unroll
  for (int i = 0; i < 4; ++i)
#pragma unroll
    for (int j = 0; j < 4; ++j)
      C[(size_t)(m0 + tm * 4 + i) * HDIM + n0 + tn * 4 + j] = c[i][j];
}

// ---------------- phase A (fat): ctx->bf16+cvec | qh GEMM | qvec LN | zero qpart ----------------
__global__ __launch_bounds__(256) void k_phaseA(const float* __restrict__ ctx, u16* __restrict__ ctxb,
                                                const float* __restrict__ g, const float* __restrict__ lb,
                                                float* __restrict__ cvec,
                                                const float* __restrict__ question,
                                                const float* __restrict__ Wq_g, const float* __restrict__ Wq_l,
                                                float* __restrict__ qh, float* __restrict__ qvec,
                                                float* __restrict__ qpart) {
  __shared__ __align__(16) char smem[8448];
  int blk = blockIdx.x, t = threadIdx.x;
  if (blk < 256) {
    // ---- ctxcv: bf16 convert + chunk mean -> LN ----
    int bj = blk;
    const float* p = ctx + (size_t)bj * LCH * HDIM + t * 4;
    u16* op = ctxb + (size_t)bj * LCH * HDIM + t * 4;
    float a0 = 0, a1 = 0, a2 = 0, a3 = 0;
    for (int r = 0; r < LCH; ++r) {
      float4 v = *(const float4*)(p + (size_t)r * HDIM);
      ushort4 o;
      o.x = f2bf(v.x); o.y = f2bf(v.y); o.z = f2bf(v.z); o.w = f2bf(v.w);
      *(ushort4*)(op + (size_t)r * HDIM) = o;
      a0 += v.x; a1 += v.y; a2 += v.z; a3 += v.w;
    }
    const float sc = 1.0f / LCH;
    a0 *= sc; a1 *= sc; a2 *= sc; a3 *= sc;
    float s = a0 + a1 + a2 + a3;
    float ss = a0 * a0 + a1 * a1 + a2 * a2 + a3 * a3;
#pragma unroll
    for (int o = 1; o < 64; o <<= 1) { s += __shfl_xor(s, o, 64); ss += __shfl_xor(ss, o, 64); }
    float* sm = (float*)smem; float* sq = sm + 4;
    int wid = t >> 6, lane = t & 63;
    if (lane == 0) { sm[wid] = s; sq[wid] = ss; }
    __syncthreads();
    float S = sm[0] + sm[1] + sm[2] + sm[3], SS = sq[0] + sq[1] + sq[2] + sq[3];
    float mu = S / HDIM;
    float inv = rsqrtf(SS / HDIM - mu * mu + 1e-5f);
    int c = t * 4;
    float4 o;
    o.x = (a0 - mu) * inv * g[c + 0] + lb[c + 0];
    o.y = (a1 - mu) * inv * g[c + 1] + lb[c + 1];
    o.z = (a2 - mu) * inv * g[c + 2] + lb[c + 2];
    o.w = (a3 - mu) * inv * g[c + 3] + lb[c + 3];
    *(float4*)&cvec[(size_t)bj * HDIM + c] = o;
  } else if (blk < 320) {
    // ---- qh = question @ Wq  (direct write, both scorers) ----
    int id = blk - 256;               // 0..63
    int s2 = id >> 5, mt = (id >> 4) & 1, ntile = id & 15;
    gemm64_direct(question, s2 ? Wq_l : Wq_g, qh + (size_t)s2 * 131072, mt * 64, ntile * 64, smem);
  } else if (blk < 324) {
    // ---- qvec: LN(mean over Q) ----
    int b = blk - 320;
    const float* p = question + (size_t)b * QN * HDIM + t * 4;
    float a0 = 0, a1 = 0, a2 = 0, a3 = 0;
    for (int r = 0; r < QN; ++r) {
      float4 v = *(const float4*)(p + (size_t)r * HDIM);
      a0 += v.x; a1 += v.y; a2 += v.z; a3 += v.w;
    }
    const float sc = 1.0f / QN;
    a0 *= sc; a1 *= sc; a2 *= sc; a3 *= sc;
    float s = a0 + a1 + a2 + a3;
    float ss = a0 * a0 + a1 * a1 + a2 * a2 + a3 * a3;
#pragma unroll
    for (int o = 1; o < 64; o <<= 1) { s += __shfl_xor(s, o, 64); ss += __shfl_xor(ss, o, 64); }
    float* sm = (float*)smem; float* sq = sm + 4;
    int wid = t >> 6, lane = t & 63;
    if (lane == 0) { sm[wid] = s; sq[wid] = ss; }
    __syncthreads();
    float S = sm[0] + sm[1] + sm[2] + sm[3], SS = sq[0] + sq[1] + sq[2] + sq[3];
    float mu = S / HDIM;
    float inv = rsqrtf(SS / HDIM - mu * mu + 1e-5f);
    int c = t * 4;
    float4 o;
    o.x = (a0 - mu) * inv * g[c + 0] + lb[c + 0];
    o.y = (a1 - mu) * inv * g[c + 1] + lb[c + 1];
    o.z = (a2 - mu) * inv * g[c + 2] + lb[c + 2];
    o.w = (a3 - mu) * inv * g[c + 3] + lb[c + 3];
    *(float4*)&qvec[(size_t)b * HDIM + c] = o;
  } else {
    // ---- zero qpart (4096 floats) ----
    float4 z = make_float4(0.f, 0.f, 0.f, 0.f);
#pragma unroll
    for (int i = 0; i < 4; ++i) ((float4*)qpart)[t * 4 + i] = z;
  }
}

// ---------------- phase B (fat): afold | sbias | qpart split-K | h1 GEMM ----------------
__global__ __launch_bounds__(256) void k_phaseB(const float* __restrict__ qh,
                                                const float* __restrict__ Wk_g, const float* __restrict__ Wk_l,
                                                const float* __restrict__ bq_g, const float* __restrict__ bq_l,
                                                u16* __restrict__ Ab,
                                                const float* __restrict__ bk_g, const float* __restrict__ bk_l,
                                                float* __restrict__ sbias,
                                                const float* __restrict__ qvec, const float* __restrict__ W1,
                                                float* __restrict__ qpart,
                                                const float* __restrict__ cvec, float* __restrict__ h1) {
  __shared__ __align__(16) char smem[8448];
  int blk = blockIdx.x, t = threadIdx.x;
  if (blk < 512) {
    // ---- afold: A[b][n][c] = (1/8)(qh+bq) . Wk  (bf16) ----
    int ct = blk & 3, slot = (blk >> 2) & 31, b = blk >> 7;
    int s2 = slot >> 4, h = slot & 15;
    const float* qhp = qh + (size_t)(s2 * 4 + b) * QN * HDIM;
    const float* Wk = s2 ? Wk_l : Wk_g;
    const float* bq = s2 ? bq_l : bq_g;
    float (*qs)[DH] = (float(*)[DH])smem;   // 32x64x4 = 8192 B
    {
      int q = t >> 3, doff = (t & 7) * 8;
      const float4* src = (const float4*)(qhp + (size_t)q * HDIM + h * DH + doff);
      float4 b0 = *(const float4*)(bq + h * DH + doff);
      float4 b1 = *(const float4*)(bq + h * DH + doff + 4);
      float4 v0 = src[0], v1 = src[1];
      qs[q][doff + 0] = v0.x + b0.x; qs[q][doff + 1] = v0.y + b0.y;
      qs[q][doff + 2] = v0.z + b0.z; qs[q][doff + 3] = v0.w + b0.w;
      qs[q][doff + 4] = v1.x + b1.x; qs[q][doff + 5] = v1.y + b1.y;
      qs[q][doff + 6] = v1.z + b1.z; qs[q][doff + 7] = v1.w + b1.w;
    }
    __syncthreads();
    int c = ct * 256 + t;
    float w[DH];
    const float* wr = Wk + (size_t)c * HDIM + h * DH;
#pragma unroll
    for (int d = 0; d < DH; d += 4) {
      float4 v = *(const float4*)(wr + d);
      w[d] = v.x; w[d + 1] = v.y; w[d + 2] = v.z; w[d + 3] = v.w;
    }
    u16* outp = Ab + ((size_t)b * HDIM + s2 * 512 + h * QN) * HDIM + c;
    for (int q = 0; q < QN; ++q) {
      float acc = 0.f;
#pragma unroll
      for (int d = 0; d < DH; ++d) acc += qs[q][d] * w[d];
      outp[(size_t)q * HDIM] = f2bf(acc * 0.125f);
    }
  } else if (blk < 528) {
    // ---- sbias ----
    int i = (blk - 512) * 256 + t;   // 0..4095
    int b = i >> 10, n = i & (HDIM - 1);
    int s2 = n >> 9, hq = n & 511, h = hq >> 5, q = hq & 31;
    const float* qr = qh + ((size_t)(s2 * 4 + b) * QN + q) * HDIM + h * DH;
    const float* bk = (s2 ? bk_l : bk_g) + h * DH;
    const float* bq = (s2 ? bq_l : bq_g) + h * DH;
    float acc = 0.f;
#pragma unroll
    for (int d = 0; d < DH; ++d) acc += (qr[d] + bq[d]) * bk[d];
    sbias[i] = acc * 0.125f;
  } else if (blk < 784) {
    // ---- qpart split-K atomic ----
    int id = blk - 528;              // 0..255
    int nt = id & 3, b = (id >> 2) & 3, ks = id >> 4;
    int n = nt * 256 + t;
    const float* qv = qvec + (size_t)b * HDIM + ks * 64;
    const float* wp = W1 + (size_t)ks * 64 * HDIM + n;
    float acc = 0.f;
#pragma unroll 8
    for (int c = 0; c < 64; ++c) acc += qv[c] * wp[(size_t)c * HDIM];
    atomicAdd(&qpart[(size_t)b * HDIM + n], acc);
  } else {
    // ---- h1 = cvec @ W1[1024:2048,:]  (direct write) ----
    int id = blk - 784;              // 0..63
    int mt = id >> 4, ntile = id & 15;
    gemm64_direct(cvec, W1 + 1048576, h1, mt * 64, ntile * 64, smem);
  }
}

// ---------------- THE big fused kernel: S = ctx_bf16 @ A^T, column-wise (max,sumexp) per chunk ----
// 256x256 tile, BK=64, 8 waves (2M x 4N), 512 thr, dbuf 128KB, counted vmcnt(8) pipeline.
__global__ __launch_bounds__(512, 2) void k_scores(const u16* __restrict__ ctxb, const u16* __restrict__ Ab,
                                                   const float* __restrict__ sbias,
                                                   float* __restrict__ mglob, float* __restrict__ zglob,
                                                   float* __restrict__ locinv) {
  __shared__ u16 lds[65536];      // A0 | B0 | A1 | B1, 16384 u16 (32KB) each
  u16* A0 = lds;           u16* B0 = lds + 16384;
  u16* A1 = lds + 32768;   u16* B1 = lds + 49152;
  // XCD-bijective remap: 512 blocks, XCD x owns works [x*64, x*64+64)
  int bid = blockIdx.x;
  int work = (bid & 7) * 64 + (bid >> 3);
  int b = work >> 7, rem = work & 127, rt = rem >> 2, nt = rem & 3;
  int t = threadIdx.x, wid = t >> 6, lane = t & 63;
  int wm = wid >> 2, wn = wid & 3;
  int lrow = lane & 15, lkg = lane >> 4;

  const u16* ctx0 = ctxb + ((size_t)b * KN + rt * 256) * HDIM;
  const u16* Afp  = Ab + ((size_t)b * HDIM + nt * 256) * HDIM;

  int grow = wid * 8 + (lane >> 3);
  int gslot = (lane & 7) ^ (lane >> 3);
  const u16* gA[4]; const u16* gB[4]; int dof[4];
#pragma unroll
  for (int s = 0; s < 4; ++s) {
    gA[s] = ctx0 + (size_t)(s * 64 + grow) * HDIM + gslot * 8;
    gB[s] = Afp + (size_t)(s * 64 + grow) * HDIM + gslot * 8;
    dof[s] = s * 4096 + wid * 512;
  }

  int rowA = (wm * 128 + lrow) * 64;
  int rowB = (wn * 64 + lrow) * 64;
  int p8[2];
#pragma unroll
  for (int ks = 0; ks < 2; ++ks) p8[ks] = ((ks * 4 + lkg) ^ (lane & 7)) * 8;

  f32x4 acc[8][4];
#pragma unroll
  for (int mi = 0; mi < 8; ++mi)
#pragma unroll
    for (int ni = 0; ni < 4; ++ni) acc[mi][ni] = 0.f;

#define STAGE(AT, BT, KT) { \
  _Pragma("unroll") for (int s = 0; s < 4; ++s) { \
    llds16(gA[s] + (KT) * 64, (AT) + dof[s]); \
    llds16(gB[s] + (KT) * 64, (BT) + dof[s]); } }

#define COMPUTE(AT, BT) { \
  _Pragma("unroll") for (int ks = 0; ks < 2; ++ks) { \
    const u16* pA = (AT) + rowA + p8[ks]; \
    const u16* pB = (BT) + rowB + p8[ks]; \
    s16x8 av[8], bv[4]; \
    _Pragma("unroll") for (int mi = 0; mi < 8; ++mi) av[mi] = *(const s16x8*)(pA + mi * 1024); \
    _Pragma("unroll") for (int ni = 0; ni < 4; ++ni) bv[ni] = *(const s16x8*)(pB + ni * 1024); \
    _Pragma("unroll") for (int mi = 0; mi < 8; ++mi) \
    _Pragma("unroll") for (int ni = 0; ni < 4; ++ni) \
      acc[mi][ni] = __builtin_amdgcn_mfma_f32_16x16x32_bf16(av[mi], bv[ni], acc[mi][ni], 0, 0, 0); } }

#define SYNCN(N) { asm volatile("s_waitcnt vmcnt(" #N ")" ::: "memory"); \
                   __builtin_amdgcn_s_barrier(); \
                   __builtin_amdgcn_sched_barrier(0); }

#define SUB(KT, CA, CB, SA, SB, FULL) { \
  if (FULL) { STAGE(SA, SB, (KT) + 1); } \
  if (FULL) { SYNCN(8) } else { SYNCN(0) } \
  __builtin_amdgcn_s_setprio(1); \
  COMPUTE(CA, CB); \
  __builtin_amdgcn_s_setprio(0); \
  __builtin_amdgcn_s_barrier(); }

  STAGE(A0, B0, 0);
  SUB(0,  A0, B0, A1, B1, 1)
  SUB(1,  A1, B1, A0, B0, 1)
  SUB(2,  A0, B0, A1, B1, 1)
  SUB(3,  A1, B1, A0, B0, 1)
  SUB(4,  A0, B0, A1, B1, 1)
  SUB(5,  A1, B1, A0, B0, 1)
  SUB(6,  A0, B0, A1, B1, 1)
  SUB(7,  A1, B1, A0, B0, 1)
  SUB(8,  A0, B0, A1, B1, 1)
  SUB(9,  A1, B1, A0, B0, 1)
  SUB(10, A0, B0, A1, B1, 1)
  SUB(11, A1, B1, A0, B0, 1)
  SUB(12, A0, B0, A1, B1, 1)
  SUB(13, A1, B1, A0, B0, 1)
  SUB(14, A0, B0, A1, B1, 1)
  SUB(15, A1, B1, A0, B0, 0)
#undef STAGE
#undef COMPUTE
#undef SYNCN
#undef SUB

  // ---- epilogue: per column, (max, sumexp) over this wave's 128 rows (= one chunk) ----
  int jc = rt * 2 + wm;
  float sb[4];
#pragma unroll
  for (int ni = 0; ni < 4; ++ni)
    sb[ni] = sbias[b * HDIM + nt * 256 + wn * 64 + ni * 16 + lrow];
#pragma unroll
  for (int ni = 0; ni < 4; ++ni) {
    float m = -1e30f;
#pragma unroll
    for (int mi = 0; mi < 8; ++mi)
#pragma unroll
      for (int r = 0; r < 4; ++r) m = fmaxf(m, acc[mi][ni][r]);
    m += sb[ni];
    m = fmaxf(m, __shfl_xor(m, 16, 64));
    m = fmaxf(m, __shfl_xor(m, 32, 64));
    float z = 0.f;
#pragma unroll
    for (int mi = 0; mi < 8; ++mi)
#pragma unroll
      for (int r = 0; r < 4; ++r) z += __expf(acc[mi][ni][r] + sb[ni] - m);
    z += __shfl_xor(z, 16, 64);
    z += __shfl_xor(z, 32, 64);
    if (lane < 16) {
      int n = nt * 256 + wn * 64 + ni * 16 + lane;
      if (n < 512) {
        size_t o = ((size_t)b * 512 + n) * JCH + jc;
        mglob[o] = m; zglob[o] = z;
      } else {
        locinv[((size_t)b * JCH + jc) * 512 + (n - 512)] = 1.0f / z;
      }
    }
  }
}

// ---------------- per-(b,hq) global max/denominator over chunks (contiguous reads) ----------------
__global__ __launch_bounds__(256) void k_hq(const float* __restrict__ mglob, const float* __restrict__ zglob,
                                            float* __restrict__ Mh, float* __restrict__ Zr) {
  int id = blockIdx.x * 256 + threadIdx.x;   // grid 8 -> 0..2047
  int b = id >> 9, hq = id & 511;
  const float* mg = mglob + ((size_t)b * 512 + hq) * JCH;
  const float* zg = zglob + ((size_t)b * 512 + hq) * JCH;
  float m = -1e30f;
  for (int j = 0; j < JCH; ++j) m = fmaxf(m, mg[j]);
  float z = 0.f;
  for (int j = 0; j < JCH; ++j) z += zg[j] * __expf(mg[j] - m);
  Mh[id] = m;
  Zr[id] = 1.0f / z;
}

// ---------------- per-(b,j) pooled scalars: att, loc, gate-dot (gelu fused) ----------------
__global__ __launch_bounds__(256) void k_chunk(const float* __restrict__ mglob, const float* __restrict__ zglob,
                                               const float* __restrict__ locinv,
                                               const float* __restrict__ Mh, const float* __restrict__ Zr,
                                               const float* __restrict__ h1, const float* __restrict__ qpart,
                                               const float* __restrict__ b1, const float* __restrict__ W2,
                                               float* __restrict__ abuf, float* __restrict__ lbuf,
                                               float* __restrict__ gbuf) {
  int bj = blockIdx.x, t = threadIdx.x;
  int b = bj >> 6, j = bj & 63;
  const float* mg = mglob + (size_t)b * 512 * JCH + j;   // stride JCH over hq
  const float* zg = zglob + (size_t)b * 512 * JCH + j;
  const float* lp = locinv + (size_t)bj * 512;
  const float* Mb = Mh + (size_t)b * 512;
  const float* Zb = Zr + (size_t)b * 512;
  float a = 0.f, l = 0.f, gsum = 0.f;
  for (int hq = t; hq < 512; hq += 256) {
    a += zg[(size_t)hq * JCH] * __expf(mg[(size_t)hq * JCH] - Mb[hq]) * Zb[hq];
    l += lp[hq];
  }
  const float* hp = h1 + (size_t)bj * HDIM;
  const float* qp = qpart + (size_t)b * HDIM;
  for (int n = t; n < HDIM; n += 256) {
    float x = hp[n] + qp[n] + b1[n];
    x = x * 0.5f * (1.0f + erff(x * 0.70710678118654752f));
    gsum += x * W2[n];
  }
#pragma unroll
  for (int o = 1; o < 64; o <<= 1) {
    a += __shfl_xor(a, o, 64); l += __shfl_xor(l, o, 64); gsum += __shfl_xor(gsum, o, 64);
  }
  __shared__ float ra[4], rl[4], rg[4];
  int wid = t >> 6, lane = t & 63;
  if (lane == 0) { ra[wid] = a; rl[wid] = l; rg[wid] = gsum; }
  __syncthreads();
  if (t == 0) {
    abuf[bj] = (ra[0] + ra[1] + ra[2] + ra[3]) * (1.0f / 65536.0f);
    lbuf[bj] = (rl[0] + rl[1] + rl[2] + rl[3]) * (1.0f / 512.0f);
    gbuf[bj] = rg[0] + rg[1] + rg[2] + rg[3];
  }
}

// ---------------- final: softmaxes over J, fuse, outputs ----------------
__global__ __launch_bounds__(64) void k_final(const float* __restrict__ abuf, const float* __restrict__ lbuf,
                                              const float* __restrict__ gbuf, const float* __restrict__ b2,
                                              float* __restrict__ out) {
  int b = blockIdx.x, t = threadIdx.x;   // 64 threads
  float a = abuf[b * 64 + t];
  float l = lbuf[b * 64 + t];
  float gt = gbuf[b * 64 + t] + b2[0];
  gt = 1.0f / (1.0f + __expf(-gt));
  float am = a, lm = l;
#pragma unroll
  for (int o = 1; o < 64; o <<= 1) { am = fmaxf(am, __shfl_xor(am, o, 64)); lm = fmaxf(lm, __shfl_xor(lm, o, 64)); }
  float ae = __expf(a - am), le = __expf(l - lm);
  float as_ = ae, ls_ = le;
#pragma unroll
  for (int o = 1; o < 64; o <<= 1) { as_ += __shfl_xor(as_, o, 64); ls_ += __shfl_xor(ls_, o, 64); }
  float gs = ae / as_, ls = le / ls_;
  float fu = gt * ls + (1.0f - gt) * gs;
  float fm = fu;
#pragma unroll
  for (int o = 1; o < 64; o <<= 1) fm = fmaxf(fm, __shfl_xor(fm, o, 64));
  float fe = __expf(fu - fm);
  float fs_ = fe;
#pragma unroll
  for (int o = 1; o < 64; o <<= 1) fs_ += __shfl_xor(fs_, o, 64);
  float fv = fe / fs_;
  out[b * 64 + t] = fv;
  out[256 + b * 64 + t] = ls;
  out[512 + b * 64 + t] = gs;
  float tot = fv;
#pragma unroll
  for (int o = 1; o < 64; o <<= 1) tot += __shfl_xor(tot, o, 64);
  if (t == 0) out[768 + b] = tot * (1.0f / 64.0f);
}

// ---------------- launcher ----------------
extern "C" void kernel_launch(void* const* d_in, const int* in_sizes, int n_in,
                              void* d_out, int out_size, void* d_ws, size_t ws_size,
                              hipStream_t stream) {
  const float* question = (const float*)d_in[0];
  const float* context  = (const float*)d_in[1];
  const float* Wq_l = (const float*)d_in[2];
  const float* bq_l = (const float*)d_in[3];
  const float* Wk_l = (const float*)d_in[4];
  const float* bk_l = (const float*)d_in[5];
  const float* Wq_g = (const float*)d_in[6];
  const float* bq_g = (const float*)d_in[7];
  const float* Wk_g = (const float*)d_in[8];
  const float* bk_g = (const float*)d_in[9];
  const float* ln_g = (const float*)d_in[10];
  const float* ln_b = (const float*)d_in[11];
  const float* W1   = (const float*)d_in[12];
  const float* b1   = (const float*)d_in[13];
  const float* W2   = (const float*)d_in[14];
  const float* b2   = (const float*)d_in[15];

  char* ws = (char*)d_ws;
  u16*   ctxb   = (u16*)(ws + 0);            // 67108864 B
  u16*   Ab     = (u16*)(ws + 67108864);     //  8388608 B
  float* qh     = (float*)(ws + 75497472);   //  1048576 B  [2][4][32][1024]
  float* sbias  = (float*)(ws + 76546048);   //    16384 B
  float* mglob  = (float*)(ws + 76562432);   //   524288 B  [4][512][64]  (transposed)
  float* zglob  = (float*)(ws + 77086720);   //   524288 B
  float* locinv = (float*)(ws + 77611008);   //   524288 B  [4][64][512]
  float* qvec   = (float*)(ws + 78135296);   //    16384 B
  float* cvec   = (float*)(ws + 78151680);   //  1048576 B  [256][1024]
  float* qpart  = (float*)(ws + 79200256);   //    16384 B
  float* h1     = (float*)(ws + 79216640);   //  1048576 B  [256][1024]
  float* Mh     = (float*)(ws + 80265216);   //     8192 B  [4][512]
  float* Zr     = (float*)(ws + 80273408);   //     8192 B
  float* abuf   = (float*)(ws + 80281600);   //     1024 B  [4][64]
  float* lbuf   = (float*)(ws + 80282624);   //     1024 B
  float* gbuf   = (float*)(ws + 80283648);   //     1024 B

  hipLaunchKernelGGL(k_phaseA, dim3(325), dim3(256), 0, stream,
                     context, ctxb, ln_g, ln_b, cvec, question, Wq_g, Wq_l, qh, qvec, qpart);
  hipLaunchKernelGGL(k_phaseB, dim3(848), dim3(256), 0, stream,
                     qh, Wk_g, Wk_l, bq_g, bq_l, Ab, bk_g, bk_l, sbias, qvec, W1, qpart, cvec, h1);
  hipLaunchKernelGGL(k_scores, dim3(512), dim3(512), 0, stream, ctxb, Ab, sbias, mglob, zglob, locinv);
  hipLaunchKernelGGL(k_hq, dim3(8), dim3(256), 0, stream, mglob, zglob, Mh, Zr);
  hipLaunchKernelGGL(k_chunk, dim3(256), dim3(256), 0, stream, mglob, zglob, locinv, Mh, Zr, h1, qpart, b1, W2, abuf, lbuf, gbuf);
  hipLaunchKernelGGL(k_final, dim3(4), dim3(64), 0, stream, abuf, lbuf, gbuf, b2, (float*)d_out);
}